// Round 4
// baseline (1658.559 us; speedup 1.0000x reference)
//
#include <hip/hip_runtime.h>
#include <math.h>

#define NN 100000
#define EE 500000
// D=H=128, ED=64, T=2, L=4

typedef __attribute__((ext_vector_type(8))) short bf16x8;
typedef __attribute__((ext_vector_type(4))) float f32x4;
#define MFMA __builtin_amdgcn_mfma_f32_16x16x32_bf16

__device__ inline short f2bf(float x) {
    union { float f; unsigned u; } v; v.f = x;
    unsigned r = v.u + 0x7FFF + ((v.u >> 16) & 1);
    return (short)(r >> 16);
}
__device__ inline float bf2f(unsigned short h) {
    union { unsigned u; float f; } v; v.u = ((unsigned)h) << 16; return v.f;
}

__device__ inline bf16x8 mk_hi(const float* p) {
    float4 a = *(const float4*)p, b = *(const float4*)(p + 4);
    float v[8] = {a.x, a.y, a.z, a.w, b.x, b.y, b.z, b.w};
    bf16x8 h;
#pragma unroll
    for (int i = 0; i < 8; i++) h[i] = f2bf(v[i]);
    return h;
}
__device__ inline void mk_split(const float* p, bf16x8& hi, bf16x8& lo) {
    float4 a = *(const float4*)p, b = *(const float4*)(p + 4);
    float v[8] = {a.x, a.y, a.z, a.w, b.x, b.y, b.z, b.w};
#pragma unroll
    for (int i = 0; i < 8; i++) {
        short h = f2bf(v[i]);
        hi[i] = h;
        lo[i] = f2bf(v[i] - bf2f((unsigned short)h));
    }
}

// ---------------- zero fill ----------------
__global__ void k_zero(float* __restrict__ p, size_t n) {
    size_t i = (size_t)blockIdx.x * blockDim.x + threadIdx.x;
    size_t stride = (size_t)gridDim.x * blockDim.x;
    for (; i < n; i += stride) p[i] = 0.0f;
}

// ---------------- prep head: WhT, WUT, WVT, WET (bf16 transposed), beff ----------------
__global__ void k_prep_head(const float* __restrict__ Wn, const float* __restrict__ bn,
                            const float* __restrict__ W1, const float* __restrict__ b1,
                            const float* __restrict__ We, const float* __restrict__ be,
                            unsigned short* __restrict__ WhT, unsigned short* __restrict__ WUT,
                            unsigned short* __restrict__ WVT, unsigned short* __restrict__ WET,
                            float* __restrict__ beff) {
    __shared__ float red[2];
    int j = blockIdx.x, k = threadIdx.x;  // 128 blocks x 128 threads
    WhT[j * 128 + k] = (unsigned short)f2bf(Wn[k * 128 + j]);
    float su = 0.0f, sv = 0.0f;
    for (int m = 0; m < 128; m++) {
        float wkm = Wn[k * 128 + m];
        su = fmaf(wkm, W1[m * 128 + j], su);
        sv = fmaf(wkm, W1[(128 + m) * 128 + j], sv);
    }
    WUT[j * 128 + k] = (unsigned short)f2bf(su);
    WVT[j * 128 + k] = (unsigned short)f2bf(sv);
    if (k < 64) {
        float se = 0.0f;
        for (int m = 0; m < 128; m++) se = fmaf(We[k * 128 + m], W1[(256 + m) * 128 + j], se);
        WET[j * 64 + k] = (unsigned short)f2bf(se);
    }
    float tk = bn[k] * (W1[k * 128 + j] + W1[(128 + k) * 128 + j]) + be[k] * W1[(256 + k) * 128 + j];
#pragma unroll
    for (int o = 32; o > 0; o >>= 1) tk += __shfl_down(tk, o);
    if ((k & 63) == 0) red[k >> 6] = tk;
    __syncthreads();
    if (k == 0) beff[j] = b1[j] + red[0] + red[1];
}

// ---------------- prep tail: split-bf16 transposed weights (6 mats) ----------------
struct WSrc { const float* s[6]; };
__global__ void k_prep_tail(WSrc ps, unsigned short* __restrict__ hi,
                            unsigned short* __restrict__ lo) {
    int m = blockIdx.x >> 6, blk = blockIdx.x & 63;
    const float* src = ps.s[m];
    unsigned short* h = hi + (size_t)m * 16384;
    unsigned short* l = lo + (size_t)m * 16384;
    int idx = blk * 256 + threadIdx.x;  // 0..16383
    int k = idx >> 7, j = idx & 127;
    float v = src[idx];
    short hh = f2bf(v);
    h[j * 128 + k] = (unsigned short)hh;
    l[j * 128 + k] = (unsigned short)f2bf(v - bf2f((unsigned short)hh));
}

// ---------------- prep Q: QW[l] = hpW[l] @ hW1a (transposed split bf16), qb[l] = hpb[l]@hW1a --
__global__ void k_prep_q(const float* __restrict__ hpW, const float* __restrict__ hpb,
                         const float* __restrict__ hW1a,
                         unsigned short* __restrict__ QWhi, unsigned short* __restrict__ QWlo,
                         float* __restrict__ qb) {
    int gidx = blockIdx.x * 256 + threadIdx.x;
    if (gidx < 4 * 16384) {
        int l = gidx >> 14, rem = gidx & 16383;
        int k = rem >> 7, j = rem & 127;
        const float* wr = hpW + (size_t)l * 16384 + (size_t)k * 128;
        float v = 0.0f;
        for (int m = 0; m < 128; m++) v = fmaf(wr[m], hW1a[m * 128 + j], v);
        short hh = f2bf(v);
        QWhi[(size_t)l * 16384 + j * 128 + k] = (unsigned short)hh;
        QWlo[(size_t)l * 16384 + j * 128 + k] = (unsigned short)f2bf(v - bf2f((unsigned short)hh));
    } else {
        int e = gidx - 4 * 16384;
        if (e < 512) {
            int l = e >> 7, j = e & 127;
            float v = 0.0f;
            for (int m = 0; m < 128; m++) v = fmaf(hpb[l * 128 + m], hW1a[m * 128 + j], v);
            qb[l * 128 + j] = v;
        }
    }
}

// ---------------- HEAD: hbf = bf16(nf@Wn+bn), U = bf16(nf@WU), V = bf16(nf@WV) ----------------
__global__ __launch_bounds__(256) void k_head(const float* __restrict__ nf,
                                              const unsigned short* __restrict__ WhT,
                                              const unsigned short* __restrict__ WUT,
                                              const unsigned short* __restrict__ WVT,
                                              const float* __restrict__ bn,
                                              unsigned short* __restrict__ hbf,
                                              unsigned short* __restrict__ U,
                                              unsigned short* __restrict__ V) {
    __shared__ __align__(16) float T[16][132];
    int tid = threadIdx.x;
    long row0 = (long)blockIdx.x * 16;
#pragma unroll
    for (int i = 0; i < 8; i++) {
        int idx = tid + i * 256;
        int r = idx >> 7, c = idx & 127;
        T[r][c] = nf[(row0 + r) * 128 + c];
    }
    __syncthreads();
    int w = tid >> 6, lane = tid & 63, lr = lane & 15, lg = lane >> 4;
    bf16x8 A[4];
#pragma unroll
    for (int k = 0; k < 4; k++) A[k] = mk_hi(&T[lr][k * 32 + lg * 8]);
    int col0 = w * 32 + lr, col1 = col0 + 16;
#pragma unroll
    for (int o = 0; o < 3; o++) {
        const unsigned short* wb = (o == 0) ? WhT : (o == 1) ? WUT : WVT;
        unsigned short* ob = (o == 0) ? hbf : (o == 1) ? U : V;
        const unsigned short* w0 = wb + (size_t)col0 * 128 + lg * 8;
        const unsigned short* w1 = wb + (size_t)col1 * 128 + lg * 8;
        f32x4 a0 = {0.f, 0.f, 0.f, 0.f}, a1 = {0.f, 0.f, 0.f, 0.f};
#pragma unroll
        for (int k = 0; k < 4; k++) {
            a0 = MFMA(A[k], *(const bf16x8*)(w0 + k * 32), a0, 0, 0, 0);
            a1 = MFMA(A[k], *(const bf16x8*)(w1 + k * 32), a1, 0, 0, 0);
        }
        float bb0 = (o == 0) ? bn[col0] : 0.0f;
        float bb1 = (o == 0) ? bn[col1] : 0.0f;
        unsigned short* op = ob + (size_t)row0 * 128;
#pragma unroll
        for (int i = 0; i < 4; i++) {
            int r = lg * 4 + i;
            op[(size_t)r * 128 + col0] = (unsigned short)f2bf(a0[i] + bb0);
            op[(size_t)r * 128 + col1] = (unsigned short)f2bf(a1[i] + bb1);
        }
    }
}

// ---------------- EDGE: pre = U[s]+V[d]+ef@WE+beff; score=tanh(pre)@W2+b2; e=exp ----------------
__global__ __launch_bounds__(256) void k_edge2(const float* __restrict__ ef,
                                               const int* __restrict__ eis,
                                               const int* __restrict__ eid,
                                               const unsigned short* __restrict__ WET,
                                               const unsigned short* __restrict__ U,
                                               const unsigned short* __restrict__ V,
                                               const float* __restrict__ beff,
                                               const float* __restrict__ W2,
                                               const float* __restrict__ b2p,
                                               float* __restrict__ ebuf,
                                               float* __restrict__ z) {
    __shared__ float part[4][64];
    int tid = threadIdx.x, w = tid >> 6, lane = tid & 63, lr = lane & 15, lg = lane >> 4;
    long e0 = (long)blockIdx.x * 64;
    long rem = ((long)EE - e0) / 16;
    int n16 = rem < 4 ? (int)rem : 4;
    int col0 = w * 32 + lr, col1 = col0 + 16;
    bf16x8 B0[2], B1[2];
#pragma unroll
    for (int kk = 0; kk < 2; kk++) {
        B0[kk] = *(const bf16x8*)(WET + (size_t)col0 * 64 + kk * 32 + lg * 8);
        B1[kk] = *(const bf16x8*)(WET + (size_t)col1 * 64 + kk * 32 + lg * 8);
    }
    float be0 = beff[col0], be1 = beff[col1], w20 = W2[col0], w21 = W2[col1];
    for (int i16 = 0; i16 < n16; i16++) {
        long eg0 = e0 + i16 * 16;
        const float* ep = ef + (size_t)(eg0 + lr) * 64;
        f32x4 a0 = {0.f, 0.f, 0.f, 0.f}, a1 = {0.f, 0.f, 0.f, 0.f};
#pragma unroll
        for (int kk = 0; kk < 2; kk++) {
            bf16x8 a = mk_hi(ep + kk * 32 + lg * 8);
            a0 = MFMA(a, B0[kk], a0, 0, 0, 0);
            a1 = MFMA(a, B1[kk], a1, 0, 0, 0);
        }
        int4 s4 = *(const int4*)(eis + eg0 + lg * 4);
        int4 d4 = *(const int4*)(eid + eg0 + lg * 4);
        int ss[4] = {s4.x, s4.y, s4.z, s4.w};
        int dd[4] = {d4.x, d4.y, d4.z, d4.w};
#pragma unroll
        for (int i = 0; i < 4; i++) {
            float u0 = bf2f(U[(size_t)ss[i] * 128 + col0]) + bf2f(V[(size_t)dd[i] * 128 + col0]);
            float u1 = bf2f(U[(size_t)ss[i] * 128 + col1]) + bf2f(V[(size_t)dd[i] * 128 + col1]);
            float v = tanhf(a0[i] + u0 + be0) * w20 + tanhf(a1[i] + u1 + be1) * w21;
            v += __shfl_xor(v, 1);
            v += __shfl_xor(v, 2);
            v += __shfl_xor(v, 4);
            v += __shfl_xor(v, 8);
            if (lr == 0) part[w][i16 * 16 + lg * 4 + i] = v;
        }
    }
    __syncthreads();
    if (tid < n16 * 16) {
        long e = e0 + tid;
        float a = part[0][tid] + part[1][tid] + part[2][tid] + part[3][tid] + b2p[0];
        float ev = expf(a);
        ebuf[e] = ev;
        atomicAdd(&z[eis[e]], ev);
    }
}

// ---------------- AGG: agg[s] += e * h[d]  (unnormalized; /z deferred) ----------------
__global__ __launch_bounds__(256) void k_agg2(const unsigned short* __restrict__ hbf,
                                              const float* __restrict__ ebuf,
                                              const int* __restrict__ eis,
                                              const int* __restrict__ eid,
                                              float* __restrict__ agg) {
    int tid = threadIdx.x;
    long e = (long)blockIdx.x * 2 + (tid >> 7);
    int j = tid & 127;
    int s = eis[e], d = eid[e];
    float wv = ebuf[e];
    atomicAdd(&agg[(size_t)s * 128 + j], wv * bf2f(hbf[(size_t)d * 128 + j]));
}

// ---------------- TAIL-A: emb = relu(LN((agg/z)@oW+ob)); score = tanh(emb@eW1+eb1)@eW2+eb2 ----
__global__ __launch_bounds__(256) void k_tailA(const float* __restrict__ agg,
                                               const float* __restrict__ z,
                                               const unsigned short* __restrict__ Whi,
                                               const unsigned short* __restrict__ Wlo,
                                               const float* __restrict__ ob,
                                               const float* __restrict__ g,
                                               const float* __restrict__ bln,
                                               const unsigned short* __restrict__ Shi,
                                               const unsigned short* __restrict__ Slo,
                                               const float* __restrict__ sb1,
                                               const float* __restrict__ sW2,
                                               const float* __restrict__ sb2,
                                               float* __restrict__ emb,
                                               float* __restrict__ scores, int t) {
    __shared__ __align__(16) float T[16][132];
    __shared__ __align__(16) float T2[16][132];
    __shared__ float mu16[16], rs16[16], zs[16], part[4][16];
    int tid = threadIdx.x;
    long row0 = (long)blockIdx.x * 16;
    if (tid < 16) zs[tid] = 1.0f / (z[row0 + tid] + 1e-16f);
    __syncthreads();
#pragma unroll
    for (int i = 0; i < 8; i++) {
        int idx = tid + i * 256;
        int r = idx >> 7, c = idx & 127;
        T[r][c] = agg[(row0 + r) * 128 + c] * zs[r];
    }
    __syncthreads();
    int w = tid >> 6, lane = tid & 63, lr = lane & 15, lg = lane >> 4;
    int col0 = w * 32 + lr, col1 = col0 + 16;
    int j = tid & 127, half = tid >> 7;
    {
        bf16x8 ahi[4], alo[4];
#pragma unroll
        for (int k = 0; k < 4; k++) mk_split(&T[lr][k * 32 + lg * 8], ahi[k], alo[k]);
        const unsigned short* wh0 = Whi + (size_t)col0 * 128 + lg * 8;
        const unsigned short* wl0 = Wlo + (size_t)col0 * 128 + lg * 8;
        const unsigned short* wh1 = Whi + (size_t)col1 * 128 + lg * 8;
        const unsigned short* wl1 = Wlo + (size_t)col1 * 128 + lg * 8;
        f32x4 a0 = {0.f, 0.f, 0.f, 0.f}, a1 = {0.f, 0.f, 0.f, 0.f};
#pragma unroll
        for (int k = 0; k < 4; k++) {
            bf16x8 bh = *(const bf16x8*)(wh0 + k * 32), bl = *(const bf16x8*)(wl0 + k * 32);
            a0 = MFMA(ahi[k], bh, a0, 0, 0, 0);
            a0 = MFMA(alo[k], bh, a0, 0, 0, 0);
            a0 = MFMA(ahi[k], bl, a0, 0, 0, 0);
            bh = *(const bf16x8*)(wh1 + k * 32); bl = *(const bf16x8*)(wl1 + k * 32);
            a1 = MFMA(ahi[k], bh, a1, 0, 0, 0);
            a1 = MFMA(alo[k], bh, a1, 0, 0, 0);
            a1 = MFMA(ahi[k], bl, a1, 0, 0, 0);
        }
#pragma unroll
        for (int i = 0; i < 4; i++) {
            int r = lg * 4 + i;
            T2[r][col0] = a0[i] + ob[col0];
            T2[r][col1] = a1[i] + ob[col1];
        }
    }
    __syncthreads();
    {
        int gr = tid >> 4, l16 = tid & 15;
        float sm = 0.0f, sq = 0.0f;
#pragma unroll
        for (int i = 0; i < 8; i++) {
            float v = T2[gr][l16 + 16 * i];
            sm += v; sq += v * v;
        }
#pragma unroll
        for (int m = 1; m < 16; m <<= 1) { sm += __shfl_xor(sm, m); sq += __shfl_xor(sq, m); }
        if (l16 == 0) {
            float mean = sm * (1.0f / 128.0f);
            float var = sq * (1.0f / 128.0f) - mean * mean;
            mu16[gr] = mean;
            rs16[gr] = rsqrtf(var + 1e-5f);
        }
    }
    __syncthreads();
    {
        float gj = g[j], bb = bln[j];
#pragma unroll
        for (int r = 0; r < 8; r++) {
            int rr = half * 8 + r;
            float v = fmaxf((T2[rr][j] - mu16[rr]) * rs16[rr] * gj + bb, 0.0f);
            emb[(row0 + rr) * 128 + j] = v;
            T2[rr][j] = v;
        }
    }
    __syncthreads();
    {
        bf16x8 ahi[4], alo[4];
#pragma unroll
        for (int k = 0; k < 4; k++) mk_split(&T2[lr][k * 32 + lg * 8], ahi[k], alo[k]);
        const unsigned short* wh0 = Shi + (size_t)col0 * 128 + lg * 8;
        const unsigned short* wl0 = Slo + (size_t)col0 * 128 + lg * 8;
        const unsigned short* wh1 = Shi + (size_t)col1 * 128 + lg * 8;
        const unsigned short* wl1 = Slo + (size_t)col1 * 128 + lg * 8;
        f32x4 a0 = {0.f, 0.f, 0.f, 0.f}, a1 = {0.f, 0.f, 0.f, 0.f};
#pragma unroll
        for (int k = 0; k < 4; k++) {
            bf16x8 bh = *(const bf16x8*)(wh0 + k * 32), bl = *(const bf16x8*)(wl0 + k * 32);
            a0 = MFMA(ahi[k], bh, a0, 0, 0, 0);
            a0 = MFMA(alo[k], bh, a0, 0, 0, 0);
            a0 = MFMA(ahi[k], bl, a0, 0, 0, 0);
            bh = *(const bf16x8*)(wh1 + k * 32); bl = *(const bf16x8*)(wl1 + k * 32);
            a1 = MFMA(ahi[k], bh, a1, 0, 0, 0);
            a1 = MFMA(alo[k], bh, a1, 0, 0, 0);
            a1 = MFMA(ahi[k], bl, a1, 0, 0, 0);
        }
        float b0 = sb1[col0], b1v = sb1[col1], w20 = sW2[col0], w21 = sW2[col1];
#pragma unroll
        for (int i = 0; i < 4; i++) {
            int r = lg * 4 + i;
            float v = tanhf(a0[i] + b0) * w20 + tanhf(a1[i] + b1v) * w21;
            v += __shfl_xor(v, 1);
            v += __shfl_xor(v, 2);
            v += __shfl_xor(v, 4);
            v += __shfl_xor(v, 8);
            if (lr == 0) part[w][r] = v;
        }
    }
    __syncthreads();
    if (tid < 16)
        scores[(row0 + tid) * 2 + t] = part[0][tid] + part[1][tid] + part[2][tid] + part[3][tid] + sb2[0];
}

// ---------------- TAIL-B1: fused2 = relu(LN((w0*emb0+w1*emb1)@eoW + eob)) ----------------
__global__ __launch_bounds__(256) void k_tailB1(const float* __restrict__ emb0,
                                                const float* __restrict__ emb1,
                                                const float* __restrict__ scores,
                                                const unsigned short* __restrict__ Fhi,
                                                const unsigned short* __restrict__ Flo,
                                                const float* __restrict__ eob,
                                                const float* __restrict__ elg,
                                                const float* __restrict__ elb,
                                                float* __restrict__ fused2) {
    __shared__ __align__(16) float T[16][132];
    __shared__ __align__(16) float T2[16][132];
    __shared__ float mu16[16], rs16[16], w0s[16], w1s[16];
    int tid = threadIdx.x;
    long row0 = (long)blockIdx.x * 16;
    if (tid < 16) {
        long r = row0 + tid;
        float s0 = scores[r * 2], s1 = scores[r * 2 + 1];
        float mx = fmaxf(s0, s1);
        float e0 = expf(s0 - mx), e1 = expf(s1 - mx);
        float inv = 1.0f / (e0 + e1);
        w0s[tid] = e0 * inv;
        w1s[tid] = e1 * inv;
    }
    __syncthreads();
#pragma unroll
    for (int i = 0; i < 8; i++) {
        int idx = tid + i * 256;
        int r = idx >> 7, c = idx & 127;
        T[r][c] = w0s[r] * emb0[(row0 + r) * 128 + c] + w1s[r] * emb1[(row0 + r) * 128 + c];
    }
    __syncthreads();
    int w = tid >> 6, lane = tid & 63, lr = lane & 15, lg = lane >> 4;
    int col0 = w * 32 + lr, col1 = col0 + 16;
    int j = tid & 127, half = tid >> 7;
    {
        bf16x8 ahi[4], alo[4];
#pragma unroll
        for (int k = 0; k < 4; k++) mk_split(&T[lr][k * 32 + lg * 8], ahi[k], alo[k]);
        const unsigned short* wh0 = Fhi + (size_t)col0 * 128 + lg * 8;
        const unsigned short* wl0 = Flo + (size_t)col0 * 128 + lg * 8;
        const unsigned short* wh1 = Fhi + (size_t)col1 * 128 + lg * 8;
        const unsigned short* wl1 = Flo + (size_t)col1 * 128 + lg * 8;
        f32x4 a0 = {0.f, 0.f, 0.f, 0.f}, a1 = {0.f, 0.f, 0.f, 0.f};
#pragma unroll
        for (int k = 0; k < 4; k++) {
            bf16x8 bh = *(const bf16x8*)(wh0 + k * 32), bl = *(const bf16x8*)(wl0 + k * 32);
            a0 = MFMA(ahi[k], bh, a0, 0, 0, 0);
            a0 = MFMA(alo[k], bh, a0, 0, 0, 0);
            a0 = MFMA(ahi[k], bl, a0, 0, 0, 0);
            bh = *(const bf16x8*)(wh1 + k * 32); bl = *(const bf16x8*)(wl1 + k * 32);
            a1 = MFMA(ahi[k], bh, a1, 0, 0, 0);
            a1 = MFMA(alo[k], bh, a1, 0, 0, 0);
            a1 = MFMA(ahi[k], bl, a1, 0, 0, 0);
        }
#pragma unroll
        for (int i = 0; i < 4; i++) {
            int r = lg * 4 + i;
            T2[r][col0] = a0[i] + eob[col0];
            T2[r][col1] = a1[i] + eob[col1];
        }
    }
    __syncthreads();
    {
        int gr = tid >> 4, l16 = tid & 15;
        float sm = 0.0f, sq = 0.0f;
#pragma unroll
        for (int i = 0; i < 8; i++) {
            float v = T2[gr][l16 + 16 * i];
            sm += v; sq += v * v;
        }
#pragma unroll
        for (int m = 1; m < 16; m <<= 1) { sm += __shfl_xor(sm, m); sq += __shfl_xor(sq, m); }
        if (l16 == 0) {
            float mean = sm * (1.0f / 128.0f);
            float var = sq * (1.0f / 128.0f) - mean * mean;
            mu16[gr] = mean;
            rs16[gr] = rsqrtf(var + 1e-5f);
        }
    }
    __syncthreads();
    {
        float gj = elg[j], bb = elb[j];
#pragma unroll
        for (int r = 0; r < 8; r++) {
            int rr = half * 8 + r;
            float v = fmaxf((T2[rr][j] - mu16[rr]) * rs16[rr] * gj + bb, 0.0f);
            fused2[(row0 + rr) * 128 + j] = v;
        }
    }
}

// ---------------- FSUM: fsum[l] = sum_{lev=l} fused2, cnt[l] ----------------
__global__ __launch_bounds__(256) void k_fsum(const float* __restrict__ fused2,
                                              const int* __restrict__ lev,
                                              float* __restrict__ fsumg,
                                              float* __restrict__ cntg) {
    __shared__ float ls[2][4][128];
    __shared__ float lc[2][4];
    int tid = threadIdx.x, half = tid >> 7, j = tid & 127;
#pragma unroll
    for (int l = 0; l < 4; l++) ls[half][l][j] = 0.0f;
    if (j < 4) lc[half][j] = 0.0f;
    __syncthreads();
    for (long row = (long)blockIdx.x * 2 + half; row < NN; row += (long)gridDim.x * 2) {
        int l = lev[row];
        ls[half][l][j] += fused2[row * 128 + j];
        if (j == 0) lc[half][l] += 1.0f;
    }
    __syncthreads();
    if (half == 0) {
#pragma unroll
        for (int l = 0; l < 4; l++) atomicAdd(&fsumg[l * 128 + j], ls[0][l][j] + ls[1][l][j]);
        if (j < 4) atomicAdd(&cntg[j], lc[0][j] + lc[1][j]);
    }
}

// ---------------- FIN2: lmean[l] = (fsum[l]@hpW[l]+cnt*hpb[l])/cnt; lmw[l]=lmean[l]@W1b+hb1 --
__global__ void k_fin2(const float* __restrict__ fsum, const float* __restrict__ cnt,
                       const float* __restrict__ hpW, const float* __restrict__ hpb,
                       const float* __restrict__ W1b, const float* __restrict__ b1,
                       float* __restrict__ lmean, float* __restrict__ lmw) {
    __shared__ float fs[128];
    __shared__ float lml[128];
    int l = blockIdx.x, j = threadIdx.x;
    fs[j] = fsum[l * 128 + j];
    __syncthreads();
    float c = cnt[l];
    float a = c * hpb[l * 128 + j];
    const float* wp = hpW + (size_t)l * 16384;
    for (int k = 0; k < 128; k++) a = fmaf(fs[k], wp[k * 128 + j], a);
    float cm = c < 1.0f ? 1.0f : c;
    float v = a / cm;
    lmean[l * 128 + j] = v;
    lml[j] = v;
    __syncthreads();
    float b = b1[j];
    for (int k = 0; k < 128; k++) b = fmaf(lml[k], W1b[k * 128 + j], b);
    lmw[l * 128 + j] = b;
}

// ---------------- TAIL-CD: hfa (level-select QW GEMM) + hier attn + final GEMM + LN -> out ----
__global__ __launch_bounds__(256) void k_tailCD(const float* __restrict__ fused2,
                                                const int* __restrict__ lev,
                                                const unsigned short* __restrict__ QWhi,
                                                const unsigned short* __restrict__ QWlo,
                                                const float* __restrict__ qb,
                                                const float* __restrict__ lmw,
                                                const float* __restrict__ lmean,
                                                const float* __restrict__ hW2,
                                                const float* __restrict__ hb2,
                                                const unsigned short* __restrict__ Ohi,
                                                const unsigned short* __restrict__ Olo,
                                                const float* __restrict__ hob,
                                                const float* __restrict__ hlg,
                                                const float* __restrict__ hlb,
                                                float* __restrict__ out) {
    __shared__ __align__(16) float T[16][132];
    __shared__ __align__(16) float T2[16][132];
    __shared__ float lm[4][128];
    __shared__ float part[4][8][4];
    __shared__ float aw[16][4];
    __shared__ float mu16[16], rs16[16];
    __shared__ int lv[16];
    int tid = threadIdx.x;
    long row0 = (long)blockIdx.x * 16;
#pragma unroll
    for (int i = 0; i < 8; i++) {
        int idx = tid + i * 256;
        T[idx >> 7][idx & 127] = fused2[(row0 + (idx >> 7)) * 128 + (idx & 127)];
    }
    for (int idx = tid; idx < 512; idx += 256) lm[idx >> 7][idx & 127] = lmean[idx];
    if (tid < 16) lv[tid] = lev[row0 + tid];
    __syncthreads();
    int w = tid >> 6, lane = tid & 63, lr = lane & 15, lg = lane >> 4;
    int col0 = w * 32 + lr, col1 = col0 + 16;
    int j = tid & 127, half = tid >> 7;
    // hfa = fused2 @ QW[lev] + qb[lev]  (compute all 4, select)
    {
        bf16x8 ahi[4], alo[4];
#pragma unroll
        for (int k = 0; k < 4; k++) mk_split(&T[lr][k * 32 + lg * 8], ahi[k], alo[k]);
        float sel0[4] = {0.f, 0.f, 0.f, 0.f}, sel1[4] = {0.f, 0.f, 0.f, 0.f};
#pragma unroll
        for (int l = 0; l < 4; l++) {
            const unsigned short* wh0 = QWhi + (size_t)l * 16384 + (size_t)col0 * 128 + lg * 8;
            const unsigned short* wl0 = QWlo + (size_t)l * 16384 + (size_t)col0 * 128 + lg * 8;
            const unsigned short* wh1 = QWhi + (size_t)l * 16384 + (size_t)col1 * 128 + lg * 8;
            const unsigned short* wl1 = QWlo + (size_t)l * 16384 + (size_t)col1 * 128 + lg * 8;
            f32x4 a0 = {0.f, 0.f, 0.f, 0.f}, a1 = {0.f, 0.f, 0.f, 0.f};
#pragma unroll
            for (int k = 0; k < 4; k++) {
                bf16x8 bh = *(const bf16x8*)(wh0 + k * 32), bl = *(const bf16x8*)(wl0 + k * 32);
                a0 = MFMA(ahi[k], bh, a0, 0, 0, 0);
                a0 = MFMA(alo[k], bh, a0, 0, 0, 0);
                a0 = MFMA(ahi[k], bl, a0, 0, 0, 0);
                bh = *(const bf16x8*)(wh1 + k * 32); bl = *(const bf16x8*)(wl1 + k * 32);
                a1 = MFMA(ahi[k], bh, a1, 0, 0, 0);
                a1 = MFMA(alo[k], bh, a1, 0, 0, 0);
                a1 = MFMA(ahi[k], bl, a1, 0, 0, 0);
            }
#pragma unroll
            for (int i = 0; i < 4; i++) {
                int r = lg * 4 + i;
                bool m = (lv[r] == l);
                sel0[i] = m ? (a0[i] + qb[l * 128 + col0]) : sel0[i];
                sel1[i] = m ? (a1[i] + qb[l * 128 + col1]) : sel1[i];
            }
        }
#pragma unroll
        for (int i = 0; i < 4; i++) {
            int r = lg * 4 + i;
            T2[r][col0] = sel0[i];
            T2[r][col1] = sel1[i];
        }
    }
    __syncthreads();
    // hierarchical attention scores
    {
        float w2j = hW2[j];
        float lw[4];
#pragma unroll
        for (int l = 0; l < 4; l++) lw[l] = lmw[l * 128 + j];
#pragma unroll
        for (int r = 0; r < 8; r++) {
            int rr = half * 8 + r;
            float hv = T2[rr][j];
#pragma unroll
            for (int l = 0; l < 4; l++) {
                float v = tanhf(hv + lw[l]) * w2j;
#pragma unroll
                for (int o = 32; o > 0; o >>= 1) v += __shfl_down(v, o);
                if ((tid & 63) == 0) part[tid >> 6][r][l] = v;
            }
        }
    }
    __syncthreads();
    if (tid < 16) {
        int hh = tid >> 3, r = tid & 7;
        float b2 = hb2[0];
        float sc[4];
        float mx = -1e30f;
#pragma unroll
        for (int l = 0; l < 4; l++) {
            sc[l] = part[hh * 2][r][l] + part[hh * 2 + 1][r][l] + b2;
            mx = fmaxf(mx, sc[l]);
        }
        float s = 0.0f;
#pragma unroll
        for (int l = 0; l < 4; l++) { sc[l] = expf(sc[l] - mx); s += sc[l]; }
        float inv = 1.0f / s;
#pragma unroll
        for (int l = 0; l < 4; l++) aw[tid][l] = sc[l] * inv;
    }
    __syncthreads();
    // enhanced = aw @ lmean  (overwrite T)
#pragma unroll
    for (int r = 0; r < 8; r++) {
        int rr = half * 8 + r;
        float e = 0.0f;
#pragma unroll
        for (int l = 0; l < 4; l++) e = fmaf(aw[rr][l], lm[l][j], e);
        T[rr][j] = e;
    }
    __syncthreads();
    // out = relu(LN(enh @ hoW + hob))
    {
        bf16x8 ahi[4], alo[4];
#pragma unroll
        for (int k = 0; k < 4; k++) mk_split(&T[lr][k * 32 + lg * 8], ahi[k], alo[k]);
        const unsigned short* wh0 = Ohi + (size_t)col0 * 128 + lg * 8;
        const unsigned short* wl0 = Olo + (size_t)col0 * 128 + lg * 8;
        const unsigned short* wh1 = Ohi + (size_t)col1 * 128 + lg * 8;
        const unsigned short* wl1 = Olo + (size_t)col1 * 128 + lg * 8;
        f32x4 a0 = {0.f, 0.f, 0.f, 0.f}, a1 = {0.f, 0.f, 0.f, 0.f};
#pragma unroll
        for (int k = 0; k < 4; k++) {
            bf16x8 bh = *(const bf16x8*)(wh0 + k * 32), bl = *(const bf16x8*)(wl0 + k * 32);
            a0 = MFMA(ahi[k], bh, a0, 0, 0, 0);
            a0 = MFMA(alo[k], bh, a0, 0, 0, 0);
            a0 = MFMA(ahi[k], bl, a0, 0, 0, 0);
            bh = *(const bf16x8*)(wh1 + k * 32); bl = *(const bf16x8*)(wl1 + k * 32);
            a1 = MFMA(ahi[k], bh, a1, 0, 0, 0);
            a1 = MFMA(alo[k], bh, a1, 0, 0, 0);
            a1 = MFMA(ahi[k], bl, a1, 0, 0, 0);
        }
#pragma unroll
        for (int i = 0; i < 4; i++) {
            int r = lg * 4 + i;
            T2[r][col0] = a0[i] + hob[col0];
            T2[r][col1] = a1[i] + hob[col1];
        }
    }
    __syncthreads();
    {
        int gr = tid >> 4, l16 = tid & 15;
        float sm = 0.0f, sq = 0.0f;
#pragma unroll
        for (int i = 0; i < 8; i++) {
            float v = T2[gr][l16 + 16 * i];
            sm += v; sq += v * v;
        }
#pragma unroll
        for (int m = 1; m < 16; m <<= 1) { sm += __shfl_xor(sm, m); sq += __shfl_xor(sq, m); }
        if (l16 == 0) {
            float mean = sm * (1.0f / 128.0f);
            float var = sq * (1.0f / 128.0f) - mean * mean;
            mu16[gr] = mean;
            rs16[gr] = rsqrtf(var + 1e-5f);
        }
    }
    __syncthreads();
    {
        float gj = hlg[j], bb = hlb[j];
#pragma unroll
        for (int r = 0; r < 8; r++) {
            int rr = half * 8 + r;
            float v = (T2[rr][j] - mu16[rr]) * rs16[rr] * gj + bb;
            out[(row0 + rr) * 128 + j] = fmaxf(v, 0.0f);
        }
    }
}

extern "C" void kernel_launch(void* const* d_in, const int* in_sizes, int n_in,
                              void* d_out, int out_size, void* d_ws, size_t ws_size,
                              hipStream_t stream) {
    const float* nf  = (const float*)d_in[0];
    const float* ef  = (const float*)d_in[1];
    const int*   lev = (const int*)d_in[2];
    const int*   ei  = (const int*)d_in[3];
    const float* nlW = (const float*)d_in[4];
    const float* nlb = (const float*)d_in[5];
    const float* neW = (const float*)d_in[6];
    const float* neb = (const float*)d_in[7];
    const float* aW1 = (const float*)d_in[8];
    const float* ab1 = (const float*)d_in[9];
    const float* aW2 = (const float*)d_in[10];
    const float* ab2 = (const float*)d_in[11];
    const float* oW  = (const float*)d_in[12];
    const float* ob  = (const float*)d_in[13];
    const float* lng = (const float*)d_in[14];
    const float* lnb = (const float*)d_in[15];
    const float* eW1 = (const float*)d_in[16];
    const float* eb1 = (const float*)d_in[17];
    const float* eW2 = (const float*)d_in[18];
    const float* eb2 = (const float*)d_in[19];
    const float* eoW = (const float*)d_in[20];
    const float* eob = (const float*)d_in[21];
    const float* elg = (const float*)d_in[22];
    const float* elb = (const float*)d_in[23];
    const float* hpW = (const float*)d_in[24];
    const float* hpb = (const float*)d_in[25];
    const float* hW1 = (const float*)d_in[26];
    const float* hb1 = (const float*)d_in[27];
    const float* hW2 = (const float*)d_in[28];
    const float* hb2 = (const float*)d_in[29];
    const float* hoW = (const float*)d_in[30];
    const float* hob = (const float*)d_in[31];
    const float* hlg = (const float*)d_in[32];
    const float* hlb = (const float*)d_in[33];

    float* ws = (float*)d_ws;
    size_t NH = (size_t)NN * 128;
    float* agg    = ws;              // NH (reused as fused2)
    float* emb0   = agg + NH;        // NH
    float* emb1   = emb0 + NH;       // NH (hbf aliased here)
    float* ebuf   = emb1 + NH;       // EE
    float* z      = ebuf + EE;       // NN
    float* scores = z + NN;          // 2*NN
    float* beff   = scores + (size_t)2 * NN;  // 128
    float* fsum   = beff + 128;      // 512
    float* cnt    = fsum + 512;      // 4
    float* lmean  = cnt + 4;         // 512
    float* lmw    = lmean + 512;     // 512
    float* qb     = lmw + 512;       // 512
    unsigned short* U    = (unsigned short*)(qb + 512);   // NH
    unsigned short* V    = U + NH;                        // NH
    unsigned short* WhT  = V + NH;                        // 16384
    unsigned short* WUT  = WhT + 16384;
    unsigned short* WVT  = WUT + 16384;
    unsigned short* WET  = WVT + 16384;                   // 8192
    unsigned short* twhi = WET + 8192;                    // 6*16384
    unsigned short* twlo = twhi + 6 * 16384;              // 6*16384
    unsigned short* QWhi = twlo + 6 * 16384;              // 4*16384
    unsigned short* QWlo = QWhi + 4 * 16384;              // 4*16384
    unsigned short* hbf  = (unsigned short*)emb1;
    float* fused2 = agg;
    float* out = (float*)d_out;

    WSrc ps;
    ps.s[0] = oW;               // oW t0
    ps.s[1] = oW + 16384;       // oW t1
    ps.s[2] = eW1;              // eW1 t0
    ps.s[3] = eW1 + 16384;      // eW1 t1
    ps.s[4] = eoW;
    ps.s[5] = hoW;

    k_prep_tail<<<6 * 64, 256, 0, stream>>>(ps, twhi, twlo);
    k_prep_q<<<258, 256, 0, stream>>>(hpW, hpb, hW1, QWhi, QWlo, qb);
    k_zero<<<2, 256, 0, stream>>>(fsum, (size_t)516);

    for (int t = 0; t < 2; t++) {
        k_prep_head<<<128, 128, 0, stream>>>(nlW + (size_t)t * 16384, nlb + t * 128,
                                             aW1 + (size_t)t * 384 * 128, ab1 + t * 128,
                                             neW + (size_t)t * 64 * 128, neb + t * 128,
                                             WhT, WUT, WVT, WET, beff);
        k_head<<<NN / 16, 256, 0, stream>>>(nf, WhT, WUT, WVT, nlb + t * 128, hbf, U, V);
        k_zero<<<256, 256, 0, stream>>>(z, (size_t)NN);
        const int* eis = ei + (size_t)t * 2 * EE;
        const int* eid = eis + EE;
        k_edge2<<<(EE + 63) / 64, 256, 0, stream>>>(ef + (size_t)t * EE * 64, eis, eid,
                                                    WET, U, V, beff, aW2 + t * 128,
                                                    ab2 + t, ebuf, z);
        k_zero<<<2048, 256, 0, stream>>>(agg, NH);
        k_agg2<<<EE / 2, 256, 0, stream>>>(hbf, ebuf, eis, eid, agg);
        float* embt = (t == 0) ? emb0 : emb1;
        k_tailA<<<NN / 16, 256, 0, stream>>>(agg, z,
                                             twhi + (size_t)t * 16384, twlo + (size_t)t * 16384,
                                             ob + t * 128, lng + t * 128, lnb + t * 128,
                                             twhi + (size_t)(2 + t) * 16384,
                                             twlo + (size_t)(2 + t) * 16384,
                                             eb1 + t * 128, eW2 + t * 128, eb2 + t,
                                             embt, scores, t);
    }
    k_tailB1<<<NN / 16, 256, 0, stream>>>(emb0, emb1, scores,
                                          twhi + (size_t)4 * 16384, twlo + (size_t)4 * 16384,
                                          eob, elg, elb, fused2);
    k_fsum<<<256, 256, 0, stream>>>(fused2, lev, fsum, cnt);
    k_fin2<<<4, 128, 0, stream>>>(fsum, cnt, hpW, hpb, hW1 + 16384, hb1, lmean, lmw);
    k_tailCD<<<NN / 16, 256, 0, stream>>>(fused2, lev, QWhi, QWlo, qb, lmw, lmean,
                                          hW2, hb2,
                                          twhi + (size_t)5 * 16384, twlo + (size_t)5 * 16384,
                                          hob, hlg, hlb, out);
}

// Round 5
// 1369.418 us; speedup vs baseline: 1.2111x; 1.2111x over previous
//
#include <hip/hip_runtime.h>
#include <math.h>

#define NN 100000
#define EE 500000
// D=H=128, ED=64, T=2, L=4

typedef __attribute__((ext_vector_type(8))) short bf16x8;
typedef __attribute__((ext_vector_type(4))) float f32x4;
#define MFMA __builtin_amdgcn_mfma_f32_16x16x32_bf16

__device__ inline short f2bf(float x) {
    union { float f; unsigned u; } v; v.f = x;
    unsigned r = v.u + 0x7FFF + ((v.u >> 16) & 1);
    return (short)(r >> 16);
}
__device__ inline float bf2f(unsigned short h) {
    union { unsigned u; float f; } v; v.u = ((unsigned)h) << 16; return v.f;
}
__device__ inline float tanhf_fast(float x) {
    float e = __expf(2.0f * x);
    return 1.0f - 2.0f * __builtin_amdgcn_rcpf(e + 1.0f);
}

__device__ inline bf16x8 mk_hi(const float* p) {
    float4 a = *(const float4*)p, b = *(const float4*)(p + 4);
    float v[8] = {a.x, a.y, a.z, a.w, b.x, b.y, b.z, b.w};
    bf16x8 h;
#pragma unroll
    for (int i = 0; i < 8; i++) h[i] = f2bf(v[i]);
    return h;
}
__device__ inline void mk_split(const float* p, bf16x8& hi, bf16x8& lo) {
    float4 a = *(const float4*)p, b = *(const float4*)(p + 4);
    float v[8] = {a.x, a.y, a.z, a.w, b.x, b.y, b.z, b.w};
#pragma unroll
    for (int i = 0; i < 8; i++) {
        short h = f2bf(v[i]);
        hi[i] = h;
        lo[i] = f2bf(v[i] - bf2f((unsigned short)h));
    }
}

// ---------------- zero fill ----------------
__global__ void k_zero(float* __restrict__ p, size_t n) {
    size_t i = (size_t)blockIdx.x * blockDim.x + threadIdx.x;
    size_t stride = (size_t)gridDim.x * blockDim.x;
    for (; i < n; i += stride) p[i] = 0.0f;
}

// ---------------- level bucketing ----------------
__global__ __launch_bounds__(256) void k_count(const int* __restrict__ lev, int* __restrict__ cnt4) {
    __shared__ int lc[4];
    int tid = threadIdx.x;
    if (tid < 4) lc[tid] = 0;
    __syncthreads();
    for (long n = (long)blockIdx.x * 256 + tid; n < NN; n += (long)gridDim.x * 256)
        atomicAdd(&lc[lev[n]], 1);
    __syncthreads();
    if (tid < 4 && lc[tid]) atomicAdd(&cnt4[tid], lc[tid]);
}

__global__ void k_scan(const int* __restrict__ cnt4, int* __restrict__ off4,
                       int* __restrict__ boff5, int* __restrict__ cursor) {
    int o = 0, b = 0;
    for (int l = 0; l < 4; l++) {
        off4[l] = o; cursor[l] = o; boff5[l] = b;
        o += cnt4[l];
        b += (cnt4[l] + 15) >> 4;
    }
    boff5[4] = b;
}

__global__ __launch_bounds__(256) void k_scatter(const int* __restrict__ lev,
                                                 int* __restrict__ cursor,
                                                 int* __restrict__ perm) {
    __shared__ int lc[4], lb[4], lc2[4];
    int tid = threadIdx.x;
    if (tid < 4) { lc[tid] = 0; lc2[tid] = 0; }
    __syncthreads();
    int start = blockIdx.x * 800, end = start + 800;
    if (end > NN) end = NN;
    for (int n = start + tid; n < end; n += 256) atomicAdd(&lc[lev[n]], 1);
    __syncthreads();
    if (tid < 4 && lc[tid]) lb[tid] = atomicAdd(&cursor[tid], lc[tid]);
    __syncthreads();
    for (int n = start + tid; n < end; n += 256) {
        int l = lev[n];
        int p = atomicAdd(&lc2[l], 1);
        perm[lb[l] + p] = n;
    }
}

// ---------------- prep head: WhT, WUT, WVT, WET (bf16 transposed), beff ----------------
__global__ void k_prep_head(const float* __restrict__ Wn, const float* __restrict__ bn,
                            const float* __restrict__ W1, const float* __restrict__ b1,
                            const float* __restrict__ We, const float* __restrict__ be,
                            unsigned short* __restrict__ WhT, unsigned short* __restrict__ WUT,
                            unsigned short* __restrict__ WVT, unsigned short* __restrict__ WET,
                            float* __restrict__ beff) {
    __shared__ float red[2];
    int j = blockIdx.x, k = threadIdx.x;  // 128 blocks x 128 threads
    WhT[j * 128 + k] = (unsigned short)f2bf(Wn[k * 128 + j]);
    float su = 0.0f, sv = 0.0f;
    for (int m = 0; m < 128; m++) {
        float wkm = Wn[k * 128 + m];
        su = fmaf(wkm, W1[m * 128 + j], su);
        sv = fmaf(wkm, W1[(128 + m) * 128 + j], sv);
    }
    WUT[j * 128 + k] = (unsigned short)f2bf(su);
    WVT[j * 128 + k] = (unsigned short)f2bf(sv);
    if (k < 64) {
        float se = 0.0f;
        for (int m = 0; m < 128; m++) se = fmaf(We[k * 128 + m], W1[(256 + m) * 128 + j], se);
        WET[j * 64 + k] = (unsigned short)f2bf(se);
    }
    float tk = bn[k] * (W1[k * 128 + j] + W1[(128 + k) * 128 + j]) + be[k] * W1[(256 + k) * 128 + j];
#pragma unroll
    for (int o = 32; o > 0; o >>= 1) tk += __shfl_down(tk, o);
    if ((k & 63) == 0) red[k >> 6] = tk;
    __syncthreads();
    if (k == 0) beff[j] = b1[j] + red[0] + red[1];
}

// ---------------- prep tail: split-bf16 transposed weights (6 mats) ----------------
struct WSrc { const float* s[6]; };
__global__ void k_prep_tail(WSrc ps, unsigned short* __restrict__ hi,
                            unsigned short* __restrict__ lo) {
    int m = blockIdx.x >> 6, blk = blockIdx.x & 63;
    const float* src = ps.s[m];
    unsigned short* h = hi + (size_t)m * 16384;
    unsigned short* l = lo + (size_t)m * 16384;
    int idx = blk * 256 + threadIdx.x;  // 0..16383
    int k = idx >> 7, j = idx & 127;
    float v = src[idx];
    short hh = f2bf(v);
    h[j * 128 + k] = (unsigned short)hh;
    l[j * 128 + k] = (unsigned short)f2bf(v - bf2f((unsigned short)hh));
}

// ---------------- prep Q: QW[l] = hpW[l] @ hW1a (transposed split bf16), qb[l] = hpb[l]@hW1a --
__global__ void k_prep_q(const float* __restrict__ hpW, const float* __restrict__ hpb,
                         const float* __restrict__ hW1a,
                         unsigned short* __restrict__ QWhi, unsigned short* __restrict__ QWlo,
                         float* __restrict__ qb) {
    int gidx = blockIdx.x * 256 + threadIdx.x;
    if (gidx < 4 * 16384) {
        int l = gidx >> 14, rem = gidx & 16383;
        int k = rem >> 7, j = rem & 127;
        const float* wr = hpW + (size_t)l * 16384 + (size_t)k * 128;
        float v = 0.0f;
        for (int m = 0; m < 128; m++) v = fmaf(wr[m], hW1a[m * 128 + j], v);
        short hh = f2bf(v);
        QWhi[(size_t)l * 16384 + j * 128 + k] = (unsigned short)hh;
        QWlo[(size_t)l * 16384 + j * 128 + k] = (unsigned short)f2bf(v - bf2f((unsigned short)hh));
    } else {
        int e = gidx - 4 * 16384;
        if (e < 512) {
            int l = e >> 7, j = e & 127;
            float v = 0.0f;
            for (int m = 0; m < 128; m++) v = fmaf(hpb[l * 128 + m], hW1a[m * 128 + j], v);
            qb[l * 128 + j] = v;
        }
    }
}

// ---------------- HEAD: hbf = bf16(nf@Wn+bn), U = bf16(nf@WU), V = bf16(nf@WV) ----------------
__global__ __launch_bounds__(256) void k_head(const float* __restrict__ nf,
                                              const unsigned short* __restrict__ WhT,
                                              const unsigned short* __restrict__ WUT,
                                              const unsigned short* __restrict__ WVT,
                                              const float* __restrict__ bn,
                                              unsigned short* __restrict__ hbf,
                                              unsigned short* __restrict__ U,
                                              unsigned short* __restrict__ V) {
    __shared__ __align__(16) float T[16][132];
    int tid = threadIdx.x;
    long row0 = (long)blockIdx.x * 16;
#pragma unroll
    for (int i = 0; i < 8; i++) {
        int idx = tid + i * 256;
        int r = idx >> 7, c = idx & 127;
        T[r][c] = nf[(row0 + r) * 128 + c];
    }
    __syncthreads();
    int w = tid >> 6, lane = tid & 63, lr = lane & 15, lg = lane >> 4;
    bf16x8 A[4];
#pragma unroll
    for (int k = 0; k < 4; k++) A[k] = mk_hi(&T[lr][k * 32 + lg * 8]);
    int col0 = w * 32 + lr, col1 = col0 + 16;
#pragma unroll
    for (int o = 0; o < 3; o++) {
        const unsigned short* wb = (o == 0) ? WhT : (o == 1) ? WUT : WVT;
        unsigned short* ob = (o == 0) ? hbf : (o == 1) ? U : V;
        const unsigned short* w0 = wb + (size_t)col0 * 128 + lg * 8;
        const unsigned short* w1 = wb + (size_t)col1 * 128 + lg * 8;
        f32x4 a0 = {0.f, 0.f, 0.f, 0.f}, a1 = {0.f, 0.f, 0.f, 0.f};
#pragma unroll
        for (int k = 0; k < 4; k++) {
            a0 = MFMA(A[k], *(const bf16x8*)(w0 + k * 32), a0, 0, 0, 0);
            a1 = MFMA(A[k], *(const bf16x8*)(w1 + k * 32), a1, 0, 0, 0);
        }
        float bb0 = (o == 0) ? bn[col0] : 0.0f;
        float bb1 = (o == 0) ? bn[col1] : 0.0f;
        unsigned short* op = ob + (size_t)row0 * 128;
#pragma unroll
        for (int i = 0; i < 4; i++) {
            int r = lg * 4 + i;
            op[(size_t)r * 128 + col0] = (unsigned short)f2bf(a0[i] + bb0);
            op[(size_t)r * 128 + col1] = (unsigned short)f2bf(a1[i] + bb1);
        }
    }
}

// ---------------- EDGE: pre = U[s]+V[d]+ef@WE+beff; score=tanh(pre)@W2+b2; e=exp ----------------
__global__ __launch_bounds__(256) void k_edge2(const float* __restrict__ ef,
                                               const int* __restrict__ eis,
                                               const int* __restrict__ eid,
                                               const unsigned short* __restrict__ WET,
                                               const unsigned short* __restrict__ U,
                                               const unsigned short* __restrict__ V,
                                               const float* __restrict__ beff,
                                               const float* __restrict__ W2,
                                               const float* __restrict__ b2p,
                                               float* __restrict__ ebuf,
                                               float* __restrict__ z) {
    __shared__ float part[4][64];
    int tid = threadIdx.x, w = tid >> 6, lane = tid & 63, lr = lane & 15, lg = lane >> 4;
    long e0 = (long)blockIdx.x * 64;
    long rem = ((long)EE - e0) / 16;
    int n16 = rem < 4 ? (int)rem : 4;
    int col0 = w * 32 + lr, col1 = col0 + 16;
    bf16x8 B0[2], B1[2];
#pragma unroll
    for (int kk = 0; kk < 2; kk++) {
        B0[kk] = *(const bf16x8*)(WET + (size_t)col0 * 64 + kk * 32 + lg * 8);
        B1[kk] = *(const bf16x8*)(WET + (size_t)col1 * 64 + kk * 32 + lg * 8);
    }
    float be0 = beff[col0], be1 = beff[col1], w20 = W2[col0], w21 = W2[col1];
    for (int i16 = 0; i16 < n16; i16++) {
        long eg0 = e0 + i16 * 16;
        const float* ep = ef + (size_t)(eg0 + lr) * 64;
        f32x4 a0 = {0.f, 0.f, 0.f, 0.f}, a1 = {0.f, 0.f, 0.f, 0.f};
#pragma unroll
        for (int kk = 0; kk < 2; kk++) {
            bf16x8 a = mk_hi(ep + kk * 32 + lg * 8);
            a0 = MFMA(a, B0[kk], a0, 0, 0, 0);
            a1 = MFMA(a, B1[kk], a1, 0, 0, 0);
        }
        int4 s4 = *(const int4*)(eis + eg0 + lg * 4);
        int4 d4 = *(const int4*)(eid + eg0 + lg * 4);
        int ss[4] = {s4.x, s4.y, s4.z, s4.w};
        int dd[4] = {d4.x, d4.y, d4.z, d4.w};
#pragma unroll
        for (int i = 0; i < 4; i++) {
            float u0 = bf2f(U[(size_t)ss[i] * 128 + col0]) + bf2f(V[(size_t)dd[i] * 128 + col0]);
            float u1 = bf2f(U[(size_t)ss[i] * 128 + col1]) + bf2f(V[(size_t)dd[i] * 128 + col1]);
            float v = tanhf_fast(a0[i] + u0 + be0) * w20 + tanhf_fast(a1[i] + u1 + be1) * w21;
            v += __shfl_xor(v, 1);
            v += __shfl_xor(v, 2);
            v += __shfl_xor(v, 4);
            v += __shfl_xor(v, 8);
            if (lr == 0) part[w][i16 * 16 + lg * 4 + i] = v;
        }
    }
    __syncthreads();
    if (tid < n16 * 16) {
        long e = e0 + tid;
        float a = part[0][tid] + part[1][tid] + part[2][tid] + part[3][tid] + b2p[0];
        float ev = __expf(a);
        ebuf[e] = ev;
        atomicAdd(&z[eis[e]], ev);
    }
}

// ---------------- AGG: agg[s] += e * h[d]  (unnormalized; /z deferred) ----------------
__global__ __launch_bounds__(256) void k_agg2(const unsigned short* __restrict__ hbf,
                                              const float* __restrict__ ebuf,
                                              const int* __restrict__ eis,
                                              const int* __restrict__ eid,
                                              float* __restrict__ agg) {
    int tid = threadIdx.x;
    long e = (long)blockIdx.x * 2 + (tid >> 7);
    int j = tid & 127;
    int s = eis[e], d = eid[e];
    float wv = ebuf[e];
    atomicAdd(&agg[(size_t)s * 128 + j], wv * bf2f(hbf[(size_t)d * 128 + j]));
}

// ---------------- TAIL-A: emb = relu(LN((agg/z)@oW+ob)); score = tanh(emb@eW1+eb1)@eW2+eb2 ----
__global__ __launch_bounds__(256) void k_tailA(const float* __restrict__ agg,
                                               const float* __restrict__ z,
                                               const unsigned short* __restrict__ Whi,
                                               const unsigned short* __restrict__ Wlo,
                                               const float* __restrict__ ob,
                                               const float* __restrict__ g,
                                               const float* __restrict__ bln,
                                               const unsigned short* __restrict__ Shi,
                                               const float* __restrict__ sb1,
                                               const float* __restrict__ sW2,
                                               const float* __restrict__ sb2,
                                               float* __restrict__ emb,
                                               float* __restrict__ scores, int t) {
    __shared__ __align__(16) float T[16][132];
    __shared__ __align__(16) float T2[16][132];
    __shared__ float mu16[16], rs16[16], zs[16], part[4][16];
    int tid = threadIdx.x;
    long row0 = (long)blockIdx.x * 16;
    if (tid < 16) zs[tid] = 1.0f / (z[row0 + tid] + 1e-16f);
    __syncthreads();
#pragma unroll
    for (int i = 0; i < 8; i++) {
        int idx = tid + i * 256;
        int r = idx >> 7, c = idx & 127;
        T[r][c] = agg[(row0 + r) * 128 + c] * zs[r];
    }
    __syncthreads();
    int w = tid >> 6, lane = tid & 63, lr = lane & 15, lg = lane >> 4;
    int col0 = w * 32 + lr, col1 = col0 + 16;
    int j = tid & 127, half = tid >> 7;
    {
        bf16x8 ahi[4], alo[4];
#pragma unroll
        for (int k = 0; k < 4; k++) mk_split(&T[lr][k * 32 + lg * 8], ahi[k], alo[k]);
        const unsigned short* wh0 = Whi + (size_t)col0 * 128 + lg * 8;
        const unsigned short* wl0 = Wlo + (size_t)col0 * 128 + lg * 8;
        const unsigned short* wh1 = Whi + (size_t)col1 * 128 + lg * 8;
        const unsigned short* wl1 = Wlo + (size_t)col1 * 128 + lg * 8;
        f32x4 a0 = {0.f, 0.f, 0.f, 0.f}, a1 = {0.f, 0.f, 0.f, 0.f};
#pragma unroll
        for (int k = 0; k < 4; k++) {
            bf16x8 bh = *(const bf16x8*)(wh0 + k * 32), bl = *(const bf16x8*)(wl0 + k * 32);
            a0 = MFMA(ahi[k], bh, a0, 0, 0, 0);
            a0 = MFMA(alo[k], bh, a0, 0, 0, 0);
            a0 = MFMA(ahi[k], bl, a0, 0, 0, 0);
            bh = *(const bf16x8*)(wh1 + k * 32); bl = *(const bf16x8*)(wl1 + k * 32);
            a1 = MFMA(ahi[k], bh, a1, 0, 0, 0);
            a1 = MFMA(alo[k], bh, a1, 0, 0, 0);
            a1 = MFMA(ahi[k], bl, a1, 0, 0, 0);
        }
#pragma unroll
        for (int i = 0; i < 4; i++) {
            int r = lg * 4 + i;
            T2[r][col0] = a0[i] + ob[col0];
            T2[r][col1] = a1[i] + ob[col1];
        }
    }
    __syncthreads();
    {
        int gr = tid >> 4, l16 = tid & 15;
        float sm = 0.0f, sq = 0.0f;
#pragma unroll
        for (int i = 0; i < 8; i++) {
            float v = T2[gr][l16 + 16 * i];
            sm += v; sq += v * v;
        }
#pragma unroll
        for (int m = 1; m < 16; m <<= 1) { sm += __shfl_xor(sm, m); sq += __shfl_xor(sq, m); }
        if (l16 == 0) {
            float mean = sm * (1.0f / 128.0f);
            float var = sq * (1.0f / 128.0f) - mean * mean;
            mu16[gr] = mean;
            rs16[gr] = rsqrtf(var + 1e-5f);
        }
    }
    __syncthreads();
    {
        float gj = g[j], bb = bln[j];
#pragma unroll
        for (int r = 0; r < 8; r++) {
            int rr = half * 8 + r;
            float v = fmaxf((T2[rr][j] - mu16[rr]) * rs16[rr] * gj + bb, 0.0f);
            emb[(row0 + rr) * 128 + j] = v;
            T2[rr][j] = v;
        }
    }
    __syncthreads();
    {
        bf16x8 ah[4];
#pragma unroll
        for (int k = 0; k < 4; k++) ah[k] = mk_hi(&T2[lr][k * 32 + lg * 8]);
        const unsigned short* wh0 = Shi + (size_t)col0 * 128 + lg * 8;
        const unsigned short* wh1 = Shi + (size_t)col1 * 128 + lg * 8;
        f32x4 a0 = {0.f, 0.f, 0.f, 0.f}, a1 = {0.f, 0.f, 0.f, 0.f};
#pragma unroll
        for (int k = 0; k < 4; k++) {
            a0 = MFMA(ah[k], *(const bf16x8*)(wh0 + k * 32), a0, 0, 0, 0);
            a1 = MFMA(ah[k], *(const bf16x8*)(wh1 + k * 32), a1, 0, 0, 0);
        }
        float b0 = sb1[col0], b1v = sb1[col1], w20 = sW2[col0], w21 = sW2[col1];
#pragma unroll
        for (int i = 0; i < 4; i++) {
            int r = lg * 4 + i;
            float v = tanhf_fast(a0[i] + b0) * w20 + tanhf_fast(a1[i] + b1v) * w21;
            v += __shfl_xor(v, 1);
            v += __shfl_xor(v, 2);
            v += __shfl_xor(v, 4);
            v += __shfl_xor(v, 8);
            if (lr == 0) part[w][r] = v;
        }
    }
    __syncthreads();
    if (tid < 16)
        scores[(row0 + tid) * 2 + t] = part[0][tid] + part[1][tid] + part[2][tid] + part[3][tid] + sb2[0];
}

// ---------------- TAIL-B1: fused2 = relu(LN((w0*emb0+w1*emb1)@eoW + eob)) ----------------
__global__ __launch_bounds__(256) void k_tailB1(const float* __restrict__ emb0,
                                                const float* __restrict__ emb1,
                                                const float* __restrict__ scores,
                                                const unsigned short* __restrict__ Fhi,
                                                const unsigned short* __restrict__ Flo,
                                                const float* __restrict__ eob,
                                                const float* __restrict__ elg,
                                                const float* __restrict__ elb,
                                                float* __restrict__ fused2) {
    __shared__ __align__(16) float T[16][132];
    __shared__ __align__(16) float T2[16][132];
    __shared__ float mu16[16], rs16[16], w0s[16], w1s[16];
    int tid = threadIdx.x;
    long row0 = (long)blockIdx.x * 16;
    if (tid < 16) {
        long r = row0 + tid;
        float s0 = scores[r * 2], s1 = scores[r * 2 + 1];
        float mx = fmaxf(s0, s1);
        float e0 = __expf(s0 - mx), e1 = __expf(s1 - mx);
        float inv = 1.0f / (e0 + e1);
        w0s[tid] = e0 * inv;
        w1s[tid] = e1 * inv;
    }
    __syncthreads();
#pragma unroll
    for (int i = 0; i < 8; i++) {
        int idx = tid + i * 256;
        int r = idx >> 7, c = idx & 127;
        T[r][c] = w0s[r] * emb0[(row0 + r) * 128 + c] + w1s[r] * emb1[(row0 + r) * 128 + c];
    }
    __syncthreads();
    int w = tid >> 6, lane = tid & 63, lr = lane & 15, lg = lane >> 4;
    int col0 = w * 32 + lr, col1 = col0 + 16;
    int j = tid & 127, half = tid >> 7;
    {
        bf16x8 ahi[4], alo[4];
#pragma unroll
        for (int k = 0; k < 4; k++) mk_split(&T[lr][k * 32 + lg * 8], ahi[k], alo[k]);
        const unsigned short* wh0 = Fhi + (size_t)col0 * 128 + lg * 8;
        const unsigned short* wl0 = Flo + (size_t)col0 * 128 + lg * 8;
        const unsigned short* wh1 = Fhi + (size_t)col1 * 128 + lg * 8;
        const unsigned short* wl1 = Flo + (size_t)col1 * 128 + lg * 8;
        f32x4 a0 = {0.f, 0.f, 0.f, 0.f}, a1 = {0.f, 0.f, 0.f, 0.f};
#pragma unroll
        for (int k = 0; k < 4; k++) {
            bf16x8 bh = *(const bf16x8*)(wh0 + k * 32), bl = *(const bf16x8*)(wl0 + k * 32);
            a0 = MFMA(ahi[k], bh, a0, 0, 0, 0);
            a0 = MFMA(alo[k], bh, a0, 0, 0, 0);
            a0 = MFMA(ahi[k], bl, a0, 0, 0, 0);
            bh = *(const bf16x8*)(wh1 + k * 32); bl = *(const bf16x8*)(wl1 + k * 32);
            a1 = MFMA(ahi[k], bh, a1, 0, 0, 0);
            a1 = MFMA(alo[k], bh, a1, 0, 0, 0);
            a1 = MFMA(ahi[k], bl, a1, 0, 0, 0);
        }
#pragma unroll
        for (int i = 0; i < 4; i++) {
            int r = lg * 4 + i;
            T2[r][col0] = a0[i] + eob[col0];
            T2[r][col1] = a1[i] + eob[col1];
        }
    }
    __syncthreads();
    {
        int gr = tid >> 4, l16 = tid & 15;
        float sm = 0.0f, sq = 0.0f;
#pragma unroll
        for (int i = 0; i < 8; i++) {
            float v = T2[gr][l16 + 16 * i];
            sm += v; sq += v * v;
        }
#pragma unroll
        for (int m = 1; m < 16; m <<= 1) { sm += __shfl_xor(sm, m); sq += __shfl_xor(sq, m); }
        if (l16 == 0) {
            float mean = sm * (1.0f / 128.0f);
            float var = sq * (1.0f / 128.0f) - mean * mean;
            mu16[gr] = mean;
            rs16[gr] = rsqrtf(var + 1e-5f);
        }
    }
    __syncthreads();
    {
        float gj = elg[j], bb = elb[j];
#pragma unroll
        for (int r = 0; r < 8; r++) {
            int rr = half * 8 + r;
            float v = fmaxf((T2[rr][j] - mu16[rr]) * rs16[rr] * gj + bb, 0.0f);
            fused2[(row0 + rr) * 128 + j] = v;
        }
    }
}

// ---------------- FSUM: fsum[l] = sum_{lev=l} fused2 ----------------
__global__ __launch_bounds__(256) void k_fsum(const float* __restrict__ fused2,
                                              const int* __restrict__ lev,
                                              float* __restrict__ fsumg) {
    __shared__ float ls[2][4][128];
    int tid = threadIdx.x, half = tid >> 7, j = tid & 127;
#pragma unroll
    for (int l = 0; l < 4; l++) ls[half][l][j] = 0.0f;
    __syncthreads();
    for (long row = (long)blockIdx.x * 2 + half; row < NN; row += (long)gridDim.x * 2) {
        int l = lev[row];
        ls[half][l][j] += fused2[row * 128 + j];
    }
    __syncthreads();
    if (half == 0) {
#pragma unroll
        for (int l = 0; l < 4; l++) atomicAdd(&fsumg[l * 128 + j], ls[0][l][j] + ls[1][l][j]);
    }
}

// ---------------- FIN2: lmean[l] = (fsum[l]@hpW[l]+cnt*hpb[l])/cnt; lmw[l]=lmean[l]@W1b+hb1 --
__global__ void k_fin2(const float* __restrict__ fsum, const int* __restrict__ cnt4,
                       const float* __restrict__ hpW, const float* __restrict__ hpb,
                       const float* __restrict__ W1b, const float* __restrict__ b1,
                       float* __restrict__ lmean, float* __restrict__ lmw) {
    __shared__ float fs[128];
    __shared__ float lml[128];
    int l = blockIdx.x, j = threadIdx.x;
    fs[j] = fsum[l * 128 + j];
    __syncthreads();
    float c = (float)cnt4[l];
    float a = c * hpb[l * 128 + j];
    const float* wp = hpW + (size_t)l * 16384;
    for (int k = 0; k < 128; k++) a = fmaf(fs[k], wp[k * 128 + j], a);
    float cm = c < 1.0f ? 1.0f : c;
    float v = a / cm;
    lmean[l * 128 + j] = v;
    lml[j] = v;
    __syncthreads();
    float b = b1[j];
    for (int k = 0; k < 128; k++) b = fmaf(lml[k], W1b[k * 128 + j], b);
    lmw[l * 128 + j] = b;
}

// ---------------- TAIL-CD2 (level-bucketed): QW[l] GEMM + hier attn + final GEMM + LN -> out --
__global__ __launch_bounds__(256) void k_tailCD2(const float* __restrict__ fused2,
                                                 const int* __restrict__ perm,
                                                 const int* __restrict__ cnt4,
                                                 const int* __restrict__ off4,
                                                 const int* __restrict__ boff5,
                                                 const unsigned short* __restrict__ QWhi,
                                                 const unsigned short* __restrict__ QWlo,
                                                 const float* __restrict__ qb,
                                                 const float* __restrict__ lmw,
                                                 const float* __restrict__ lmean,
                                                 const float* __restrict__ hW2,
                                                 const unsigned short* __restrict__ Ohi,
                                                 const unsigned short* __restrict__ Olo,
                                                 const float* __restrict__ hob,
                                                 const float* __restrict__ hlg,
                                                 const float* __restrict__ hlb,
                                                 float* __restrict__ out) {
    __shared__ __align__(16) float T[16][132];
    __shared__ __align__(16) float T2[16][132];
    __shared__ float lm[4][128];
    __shared__ float lmwS[4][128];
    __shared__ float w2S[128];
    __shared__ float scS[16][4];
    __shared__ float aw[16][4];
    __shared__ float mu16[16], rs16[16];
    __shared__ int idx16[16];
    int tid = threadIdx.x;
    int b = blockIdx.x;
    if (b >= boff5[4]) return;
    int l = (b >= boff5[3]) ? 3 : (b >= boff5[2]) ? 2 : (b >= boff5[1]) ? 1 : 0;
    int bi = b - boff5[l];
    int base = off4[l] + bi * 16;
    int last = off4[l] + cnt4[l] - 1;
    if (tid < 16) {
        int gp = base + tid;
        if (gp > last) gp = last;
        idx16[tid] = perm[gp];
    }
    for (int idx = tid; idx < 512; idx += 256) {
        lm[idx >> 7][idx & 127] = lmean[idx];
        lmwS[idx >> 7][idx & 127] = lmw[idx];
    }
    if (tid < 128) w2S[tid] = hW2[tid];
    __syncthreads();
#pragma unroll
    for (int i = 0; i < 8; i++) {
        int idx = tid + i * 256;
        int r = idx >> 7, c = idx & 127;
        T[r][c] = fused2[(size_t)idx16[r] * 128 + c];
    }
    __syncthreads();
    int w = tid >> 6, lane = tid & 63, lr = lane & 15, lg = lane >> 4;
    int col0 = w * 32 + lr, col1 = col0 + 16;
    int j = tid & 127, half = tid >> 7;
    // hfa = fused2 @ QW[l] + qb[l]
    {
        bf16x8 ahi[4], alo[4];
#pragma unroll
        for (int k = 0; k < 4; k++) mk_split(&T[lr][k * 32 + lg * 8], ahi[k], alo[k]);
        const unsigned short* wh0 = QWhi + (size_t)l * 16384 + (size_t)col0 * 128 + lg * 8;
        const unsigned short* wl0 = QWlo + (size_t)l * 16384 + (size_t)col0 * 128 + lg * 8;
        const unsigned short* wh1 = QWhi + (size_t)l * 16384 + (size_t)col1 * 128 + lg * 8;
        const unsigned short* wl1 = QWlo + (size_t)l * 16384 + (size_t)col1 * 128 + lg * 8;
        f32x4 a0 = {0.f, 0.f, 0.f, 0.f}, a1 = {0.f, 0.f, 0.f, 0.f};
#pragma unroll
        for (int k = 0; k < 4; k++) {
            bf16x8 bh = *(const bf16x8*)(wh0 + k * 32), bl = *(const bf16x8*)(wl0 + k * 32);
            a0 = MFMA(ahi[k], bh, a0, 0, 0, 0);
            a0 = MFMA(alo[k], bh, a0, 0, 0, 0);
            a0 = MFMA(ahi[k], bl, a0, 0, 0, 0);
            bh = *(const bf16x8*)(wh1 + k * 32); bl = *(const bf16x8*)(wl1 + k * 32);
            a1 = MFMA(ahi[k], bh, a1, 0, 0, 0);
            a1 = MFMA(alo[k], bh, a1, 0, 0, 0);
            a1 = MFMA(ahi[k], bl, a1, 0, 0, 0);
        }
#pragma unroll
        for (int i = 0; i < 4; i++) {
            int r = lg * 4 + i;
            T2[r][col0] = a0[i] + qb[l * 128 + col0];
            T2[r][col1] = a1[i] + qb[l * 128 + col1];
        }
    }
    __syncthreads();
    // hier scores: 4 threads per (row, level') pair, stride-4 cols
    {
        int p = tid >> 2, sub = tid & 3;
        int pr = p & 15, pl = p >> 4;
        float s = 0.0f;
#pragma unroll
        for (int jj = 0; jj < 32; jj++) {
            int j2 = sub + 4 * jj;
            s += tanhf_fast(T2[pr][j2] + lmwS[pl][j2]) * w2S[j2];
        }
        s += __shfl_xor(s, 1);
        s += __shfl_xor(s, 2);
        if (sub == 0) scS[pr][pl] = s;
    }
    __syncthreads();
    if (tid < 16) {
        float sc[4];
        float mx = -1e30f;
#pragma unroll
        for (int ll = 0; ll < 4; ll++) {
            sc[ll] = scS[tid][ll];
            mx = fmaxf(mx, sc[ll]);
        }
        float s = 0.0f;
#pragma unroll
        for (int ll = 0; ll < 4; ll++) { sc[ll] = __expf(sc[ll] - mx); s += sc[ll]; }
        float inv = 1.0f / s;
#pragma unroll
        for (int ll = 0; ll < 4; ll++) aw[tid][ll] = sc[ll] * inv;
    }
    __syncthreads();
    // enhanced = aw @ lmean
#pragma unroll
    for (int r = 0; r < 8; r++) {
        int rr = half * 8 + r;
        float e = 0.0f;
#pragma unroll
        for (int ll = 0; ll < 4; ll++) e = fmaf(aw[rr][ll], lm[ll][j], e);
        T[rr][j] = e;
    }
    __syncthreads();
    // out = relu(LN(enh @ hoW + hob))
    {
        bf16x8 ahi[4], alo[4];
#pragma unroll
        for (int k = 0; k < 4; k++) mk_split(&T[lr][k * 32 + lg * 8], ahi[k], alo[k]);
        const unsigned short* wh0 = Ohi + (size_t)col0 * 128 + lg * 8;
        const unsigned short* wl0 = Olo + (size_t)col0 * 128 + lg * 8;
        const unsigned short* wh1 = Ohi + (size_t)col1 * 128 + lg * 8;
        const unsigned short* wl1 = Olo + (size_t)col1 * 128 + lg * 8;
        f32x4 a0 = {0.f, 0.f, 0.f, 0.f}, a1 = {0.f, 0.f, 0.f, 0.f};
#pragma unroll
        for (int k = 0; k < 4; k++) {
            bf16x8 bh = *(const bf16x8*)(wh0 + k * 32), bl = *(const bf16x8*)(wl0 + k * 32);
            a0 = MFMA(ahi[k], bh, a0, 0, 0, 0);
            a0 = MFMA(alo[k], bh, a0, 0, 0, 0);
            a0 = MFMA(ahi[k], bl, a0, 0, 0, 0);
            bh = *(const bf16x8*)(wh1 + k * 32); bl = *(const bf16x8*)(wl1 + k * 32);
            a1 = MFMA(ahi[k], bh, a1, 0, 0, 0);
            a1 = MFMA(alo[k], bh, a1, 0, 0, 0);
            a1 = MFMA(ahi[k], bl, a1, 0, 0, 0);
        }
#pragma unroll
        for (int i = 0; i < 4; i++) {
            int r = lg * 4 + i;
            T2[r][col0] = a0[i] + hob[col0];
            T2[r][col1] = a1[i] + hob[col1];
        }
    }
    __syncthreads();
    {
        int gr = tid >> 4, l16 = tid & 15;
        float sm = 0.0f, sq = 0.0f;
#pragma unroll
        for (int i = 0; i < 8; i++) {
            float v = T2[gr][l16 + 16 * i];
            sm += v; sq += v * v;
        }
#pragma unroll
        for (int m = 1; m < 16; m <<= 1) { sm += __shfl_xor(sm, m); sq += __shfl_xor(sq, m); }
        if (l16 == 0) {
            float mean = sm * (1.0f / 128.0f);
            float var = sq * (1.0f / 128.0f) - mean * mean;
            mu16[gr] = mean;
            rs16[gr] = rsqrtf(var + 1e-5f);
        }
    }
    __syncthreads();
    {
        float gj = hlg[j], bb = hlb[j];
#pragma unroll
        for (int r = 0; r < 8; r++) {
            int rr = half * 8 + r;
            float v = (T2[rr][j] - mu16[rr]) * rs16[rr] * gj + bb;
            out[(size_t)idx16[rr] * 128 + j] = fmaxf(v, 0.0f);
        }
    }
}

extern "C" void kernel_launch(void* const* d_in, const int* in_sizes, int n_in,
                              void* d_out, int out_size, void* d_ws, size_t ws_size,
                              hipStream_t stream) {
    const float* nf  = (const float*)d_in[0];
    const float* ef  = (const float*)d_in[1];
    const int*   lev = (const int*)d_in[2];
    const int*   ei  = (const int*)d_in[3];
    const float* nlW = (const float*)d_in[4];
    const float* nlb = (const float*)d_in[5];
    const float* neW = (const float*)d_in[6];
    const float* neb = (const float*)d_in[7];
    const float* aW1 = (const float*)d_in[8];
    const float* ab1 = (const float*)d_in[9];
    const float* aW2 = (const float*)d_in[10];
    const float* ab2 = (const float*)d_in[11];
    const float* oW  = (const float*)d_in[12];
    const float* ob  = (const float*)d_in[13];
    const float* lng = (const float*)d_in[14];
    const float* lnb = (const float*)d_in[15];
    const float* eW1 = (const float*)d_in[16];
    const float* eb1 = (const float*)d_in[17];
    const float* eW2 = (const float*)d_in[18];
    const float* eb2 = (const float*)d_in[19];
    const float* eoW = (const float*)d_in[20];
    const float* eob = (const float*)d_in[21];
    const float* elg = (const float*)d_in[22];
    const float* elb = (const float*)d_in[23];
    const float* hpW = (const float*)d_in[24];
    const float* hpb = (const float*)d_in[25];
    const float* hW1 = (const float*)d_in[26];
    const float* hb1 = (const float*)d_in[27];
    const float* hW2 = (const float*)d_in[28];
    const float* hb2 = (const float*)d_in[29];
    const float* hoW = (const float*)d_in[30];
    const float* hob = (const float*)d_in[31];
    const float* hlg = (const float*)d_in[32];
    const float* hlb = (const float*)d_in[33];

    float* ws = (float*)d_ws;
    size_t NH = (size_t)NN * 128;
    float* agg    = ws;              // NH (reused as fused2)
    float* emb0   = agg + NH;        // NH
    float* emb1   = emb0 + NH;       // NH (hbf aliased here)
    float* ebuf   = emb1 + NH;       // EE
    float* z      = ebuf + EE;       // NN
    float* scores = z + NN;          // 2*NN
    float* beff   = scores + (size_t)2 * NN;  // 128
    float* fsum   = beff + 128;      // 512
    float* lmean  = fsum + 512;      // 512
    float* lmw    = lmean + 512;     // 512
    float* qb     = lmw + 512;       // 512
    unsigned short* U    = (unsigned short*)(qb + 512);   // NH
    unsigned short* V    = U + NH;                        // NH
    unsigned short* WhT  = V + NH;                        // 16384
    unsigned short* WUT  = WhT + 16384;
    unsigned short* WVT  = WUT + 16384;
    unsigned short* WET  = WVT + 16384;                   // 8192
    unsigned short* twhi = WET + 8192;                    // 6*16384
    unsigned short* twlo = twhi + 6 * 16384;              // 6*16384
    unsigned short* QWhi = twlo + 6 * 16384;              // 4*16384
    unsigned short* QWlo = QWhi + 4 * 16384;              // 4*16384
    int* perm  = (int*)(QWlo + 4 * 16384);                // NN
    int* cnt4  = perm + NN;                               // 4
    int* off4  = cnt4 + 4;                                // 4
    int* boff5 = off4 + 4;                                // 5
    int* cursor = boff5 + 5;                              // 4
    unsigned short* hbf  = (unsigned short*)emb1;
    float* fused2 = agg;
    float* out = (float*)d_out;

    WSrc ps;
    ps.s[0] = oW;               // oW t0
    ps.s[1] = oW + 16384;       // oW t1
    ps.s[2] = eW1;              // eW1 t0
    ps.s[3] = eW1 + 16384;      // eW1 t1
    ps.s[4] = eoW;
    ps.s[5] = hoW;

    // level bucketing (independent of the main pipeline)
    k_zero<<<1, 4, 0, stream>>>((float*)cnt4, (size_t)4);
    k_count<<<128, 256, 0, stream>>>(lev, cnt4);
    k_scan<<<1, 1, 0, stream>>>(cnt4, off4, boff5, cursor);
    k_scatter<<<125, 256, 0, stream>>>(lev, cursor, perm);

    k_prep_tail<<<6 * 64, 256, 0, stream>>>(ps, twhi, twlo);
    k_prep_q<<<258, 256, 0, stream>>>(hpW, hpb, hW1, QWhi, QWlo, qb);
    k_zero<<<1, 512, 0, stream>>>(fsum, (size_t)512);

    for (int t = 0; t < 2; t++) {
        k_prep_head<<<128, 128, 0, stream>>>(nlW + (size_t)t * 16384, nlb + t * 128,
                                             aW1 + (size_t)t * 384 * 128, ab1 + t * 128,
                                             neW + (size_t)t * 64 * 128, neb + t * 128,
                                             WhT, WUT, WVT, WET, beff);
        k_head<<<NN / 16, 256, 0, stream>>>(nf, WhT, WUT, WVT, nlb + t * 128, hbf, U, V);
        k_zero<<<256, 256, 0, stream>>>(z, (size_t)NN);
        const int* eis = ei + (size_t)t * 2 * EE;
        const int* eid = eis + EE;
        k_edge2<<<(EE + 63) / 64, 256, 0, stream>>>(ef + (size_t)t * EE * 64, eis, eid,
                                                    WET, U, V, beff, aW2 + t * 128,
                                                    ab2 + t, ebuf, z);
        k_zero<<<2048, 256, 0, stream>>>(agg, NH);
        k_agg2<<<EE / 2, 256, 0, stream>>>(hbf, ebuf, eis, eid, agg);
        float* embt = (t == 0) ? emb0 : emb1;
        k_tailA<<<NN / 16, 256, 0, stream>>>(agg, z,
                                             twhi + (size_t)t * 16384, twlo + (size_t)t * 16384,
                                             ob + t * 128, lng + t * 128, lnb + t * 128,
                                             twhi + (size_t)(2 + t) * 16384,
                                             eb1 + t * 128, eW2 + t * 128, eb2 + t,
                                             embt, scores, t);
    }
    k_tailB1<<<NN / 16, 256, 0, stream>>>(emb0, emb1, scores,
                                          twhi + (size_t)4 * 16384, twlo + (size_t)4 * 16384,
                                          eob, elg, elb, fused2);
    k_fsum<<<256, 256, 0, stream>>>(fused2, lev, fsum);
    k_fin2<<<4, 128, 0, stream>>>(fsum, cnt4, hpW, hpb, hW1 + 16384, hb1, lmean, lmw);
    k_tailCD2<<<NN / 16 + 4, 256, 0, stream>>>(fused2, perm, cnt4, off4, boff5,
                                               QWhi, QWlo, qb, lmw, lmean, hW2,
                                               twhi + (size_t)5 * 16384, twlo + (size_t)5 * 16384,
                                               hob, hlg, hlb, out);
}

// Round 6
// 1185.386 us; speedup vs baseline: 1.3992x; 1.1553x over previous
//
#include <hip/hip_runtime.h>
#include <math.h>

#define NN 100000
#define EE 500000
// D=H=128, ED=64, T=2, L=4

typedef __attribute__((ext_vector_type(8))) short bf16x8;
typedef __attribute__((ext_vector_type(4))) float f32x4;
#define MFMA __builtin_amdgcn_mfma_f32_16x16x32_bf16

__device__ inline short f2bf(float x) {
    union { float f; unsigned u; } v; v.f = x;
    unsigned r = v.u + 0x7FFF + ((v.u >> 16) & 1);
    return (short)(r >> 16);
}
__device__ inline float bf2f(unsigned short h) {
    union { unsigned u; float f; } v; v.u = ((unsigned)h) << 16; return v.f;
}
__device__ inline float tanhf_fast(float x) {
    float e = __expf(2.0f * x);
    return 1.0f - 2.0f * __builtin_amdgcn_rcpf(e + 1.0f);
}

__device__ inline bf16x8 mk_hi(const float* p) {
    float4 a = *(const float4*)p, b = *(const float4*)(p + 4);
    float v[8] = {a.x, a.y, a.z, a.w, b.x, b.y, b.z, b.w};
    bf16x8 h;
#pragma unroll
    for (int i = 0; i < 8; i++) h[i] = f2bf(v[i]);
    return h;
}
__device__ inline void mk_split(const float* p, bf16x8& hi, bf16x8& lo) {
    float4 a = *(const float4*)p, b = *(const float4*)(p + 4);
    float v[8] = {a.x, a.y, a.z, a.w, b.x, b.y, b.z, b.w};
#pragma unroll
    for (int i = 0; i < 8; i++) {
        short h = f2bf(v[i]);
        hi[i] = h;
        lo[i] = f2bf(v[i] - bf2f((unsigned short)h));
    }
}

// ---------------- zero fill ----------------
__global__ void k_zero(float* __restrict__ p, size_t n) {
    size_t i = (size_t)blockIdx.x * blockDim.x + threadIdx.x;
    size_t stride = (size_t)gridDim.x * blockDim.x;
    for (; i < n; i += stride) p[i] = 0.0f;
}
__global__ void k_zeroi(int* __restrict__ p, int n) {
    int i = blockIdx.x * blockDim.x + threadIdx.x;
    if (i < n) p[i] = 0;
}

// ---------------- CSR build (by source) ----------------
__global__ __launch_bounds__(256) void k_hist(const int* __restrict__ eis, int* __restrict__ deg) {
    int e = blockIdx.x * 256 + threadIdx.x;
    if (e < EE) atomicAdd(&deg[eis[e]], 1);
}
__global__ __launch_bounds__(512) void k_scan1(const int* __restrict__ deg,
                                               int* __restrict__ tmp, int* __restrict__ bsum) {
    __shared__ int sh[2][512];
    int b = blockIdx.x, tid = threadIdx.x;
    int i = b * 512 + tid;
    int v = (i < NN) ? deg[i] : 0;
    int cur = 0;
    sh[0][tid] = v;
    __syncthreads();
    for (int off = 1; off < 512; off <<= 1) {
        int nxt = cur ^ 1;
        int a = sh[cur][tid];
        if (tid >= off) a += sh[cur][tid - off];
        sh[nxt][tid] = a;
        __syncthreads();
        cur = nxt;
    }
    int incl = sh[cur][tid];
    if (i < NN) tmp[i] = incl;
    if (tid == 511) bsum[b] = incl;
}
__global__ void k_scan2(const int* __restrict__ bsum, int* __restrict__ boff) {
    __shared__ int sh[2][256];
    int tid = threadIdx.x;
    int v = (tid < 196) ? bsum[tid] : 0;
    int cur = 0;
    sh[0][tid] = v;
    __syncthreads();
    for (int off = 1; off < 256; off <<= 1) {
        int nxt = cur ^ 1;
        int a = sh[cur][tid];
        if (tid >= off) a += sh[cur][tid - off];
        sh[nxt][tid] = a;
        __syncthreads();
        cur = nxt;
    }
    boff[tid] = sh[cur][tid] - v;
}
__global__ __launch_bounds__(512) void k_scan3(const int* __restrict__ deg,
                                               const int* __restrict__ tmp,
                                               const int* __restrict__ boff,
                                               int* __restrict__ rowptr, int* __restrict__ cursor) {
    int i = blockIdx.x * 512 + threadIdx.x;
    if (i < NN) {
        int r = tmp[i] - deg[i] + boff[blockIdx.x];
        rowptr[i] = r;
        cursor[i] = r;
    }
    if (i == 0) rowptr[NN] = EE;
}
__global__ __launch_bounds__(256) void k_csr_scatter(const int* __restrict__ eis,
                                                     const int* __restrict__ eid,
                                                     int* __restrict__ cursor,
                                                     int* __restrict__ ceid,
                                                     int* __restrict__ cdst) {
    int e = blockIdx.x * 256 + threadIdx.x;
    if (e < EE) {
        int s = eis[e];
        int p = atomicAdd(&cursor[s], 1);
        ceid[p] = e;
        cdst[p] = eid[e];
    }
}

// ---------------- level bucketing ----------------
__global__ __launch_bounds__(256) void k_count(const int* __restrict__ lev, int* __restrict__ cnt4) {
    __shared__ int lc[4];
    int tid = threadIdx.x;
    if (tid < 4) lc[tid] = 0;
    __syncthreads();
    for (long n = (long)blockIdx.x * 256 + tid; n < NN; n += (long)gridDim.x * 256)
        atomicAdd(&lc[lev[n]], 1);
    __syncthreads();
    if (tid < 4 && lc[tid]) atomicAdd(&cnt4[tid], lc[tid]);
}

__global__ void k_scan(const int* __restrict__ cnt4, int* __restrict__ off4,
                       int* __restrict__ boff5, int* __restrict__ cursor) {
    int o = 0, b = 0;
    for (int l = 0; l < 4; l++) {
        off4[l] = o; cursor[l] = o; boff5[l] = b;
        o += cnt4[l];
        b += (cnt4[l] + 15) >> 4;
    }
    boff5[4] = b;
}

__global__ __launch_bounds__(256) void k_scatter(const int* __restrict__ lev,
                                                 int* __restrict__ cursor,
                                                 int* __restrict__ perm) {
    __shared__ int lc[4], lb[4], lc2[4];
    int tid = threadIdx.x;
    if (tid < 4) { lc[tid] = 0; lc2[tid] = 0; }
    __syncthreads();
    int start = blockIdx.x * 800, end = start + 800;
    if (end > NN) end = NN;
    for (int n = start + tid; n < end; n += 256) atomicAdd(&lc[lev[n]], 1);
    __syncthreads();
    if (tid < 4 && lc[tid]) lb[tid] = atomicAdd(&cursor[tid], lc[tid]);
    __syncthreads();
    for (int n = start + tid; n < end; n += 256) {
        int l = lev[n];
        int p = atomicAdd(&lc2[l], 1);
        perm[lb[l] + p] = n;
    }
}

// ---------------- prep head: WhT, WUT, WVT, WET (bf16 transposed), beff ----------------
__global__ void k_prep_head(const float* __restrict__ Wn, const float* __restrict__ bn,
                            const float* __restrict__ W1, const float* __restrict__ b1,
                            const float* __restrict__ We, const float* __restrict__ be,
                            unsigned short* __restrict__ WhT, unsigned short* __restrict__ WUT,
                            unsigned short* __restrict__ WVT, unsigned short* __restrict__ WET,
                            float* __restrict__ beff) {
    __shared__ float red[2];
    int j = blockIdx.x, k = threadIdx.x;  // 128 blocks x 128 threads
    WhT[j * 128 + k] = (unsigned short)f2bf(Wn[k * 128 + j]);
    float su = 0.0f, sv = 0.0f;
    for (int m = 0; m < 128; m++) {
        float wkm = Wn[k * 128 + m];
        su = fmaf(wkm, W1[m * 128 + j], su);
        sv = fmaf(wkm, W1[(128 + m) * 128 + j], sv);
    }
    WUT[j * 128 + k] = (unsigned short)f2bf(su);
    WVT[j * 128 + k] = (unsigned short)f2bf(sv);
    if (k < 64) {
        float se = 0.0f;
        for (int m = 0; m < 128; m++) se = fmaf(We[k * 128 + m], W1[(256 + m) * 128 + j], se);
        WET[j * 64 + k] = (unsigned short)f2bf(se);
    }
    float tk = bn[k] * (W1[k * 128 + j] + W1[(128 + k) * 128 + j]) + be[k] * W1[(256 + k) * 128 + j];
#pragma unroll
    for (int o = 32; o > 0; o >>= 1) tk += __shfl_down(tk, o);
    if ((k & 63) == 0) red[k >> 6] = tk;
    __syncthreads();
    if (k == 0) beff[j] = b1[j] + red[0] + red[1];
}

// ---------------- prep tail: split-bf16 transposed weights (6 mats) ----------------
struct WSrc { const float* s[6]; };
__global__ void k_prep_tail(WSrc ps, unsigned short* __restrict__ hi,
                            unsigned short* __restrict__ lo) {
    int m = blockIdx.x >> 6, blk = blockIdx.x & 63;
    const float* src = ps.s[m];
    unsigned short* h = hi + (size_t)m * 16384;
    unsigned short* l = lo + (size_t)m * 16384;
    int idx = blk * 256 + threadIdx.x;  // 0..16383
    int k = idx >> 7, j = idx & 127;
    float v = src[idx];
    short hh = f2bf(v);
    h[j * 128 + k] = (unsigned short)hh;
    l[j * 128 + k] = (unsigned short)f2bf(v - bf2f((unsigned short)hh));
}

// ---------------- prep Q: QW[l] = hpW[l] @ hW1a (transposed split bf16), qb[l] = hpb[l]@hW1a --
__global__ void k_prep_q(const float* __restrict__ hpW, const float* __restrict__ hpb,
                         const float* __restrict__ hW1a,
                         unsigned short* __restrict__ QWhi, unsigned short* __restrict__ QWlo,
                         float* __restrict__ qb) {
    int gidx = blockIdx.x * 256 + threadIdx.x;
    if (gidx < 4 * 16384) {
        int l = gidx >> 14, rem = gidx & 16383;
        int k = rem >> 7, j = rem & 127;
        const float* wr = hpW + (size_t)l * 16384 + (size_t)k * 128;
        float v = 0.0f;
        for (int m = 0; m < 128; m++) v = fmaf(wr[m], hW1a[m * 128 + j], v);
        short hh = f2bf(v);
        QWhi[(size_t)l * 16384 + j * 128 + k] = (unsigned short)hh;
        QWlo[(size_t)l * 16384 + j * 128 + k] = (unsigned short)f2bf(v - bf2f((unsigned short)hh));
    } else {
        int e = gidx - 4 * 16384;
        if (e < 512) {
            int l = e >> 7, j = e & 127;
            float v = 0.0f;
            for (int m = 0; m < 128; m++) v = fmaf(hpb[l * 128 + m], hW1a[m * 128 + j], v);
            qb[l * 128 + j] = v;
        }
    }
}

// ---------------- HEAD: hbf = bf16(nf@Wn+bn), U = bf16(nf@WU), V = bf16(nf@WV) ----------------
__global__ __launch_bounds__(256) void k_head(const float* __restrict__ nf,
                                              const unsigned short* __restrict__ WhT,
                                              const unsigned short* __restrict__ WUT,
                                              const unsigned short* __restrict__ WVT,
                                              const float* __restrict__ bn,
                                              unsigned short* __restrict__ hbf,
                                              unsigned short* __restrict__ U,
                                              unsigned short* __restrict__ V) {
    __shared__ __align__(16) float T[16][132];
    int tid = threadIdx.x;
    long row0 = (long)blockIdx.x * 16;
#pragma unroll
    for (int i = 0; i < 8; i++) {
        int idx = tid + i * 256;
        int r = idx >> 7, c = idx & 127;
        T[r][c] = nf[(row0 + r) * 128 + c];
    }
    __syncthreads();
    int w = tid >> 6, lane = tid & 63, lr = lane & 15, lg = lane >> 4;
    bf16x8 A[4];
#pragma unroll
    for (int k = 0; k < 4; k++) A[k] = mk_hi(&T[lr][k * 32 + lg * 8]);
    int col0 = w * 32 + lr, col1 = col0 + 16;
#pragma unroll
    for (int o = 0; o < 3; o++) {
        const unsigned short* wb = (o == 0) ? WhT : (o == 1) ? WUT : WVT;
        unsigned short* ob = (o == 0) ? hbf : (o == 1) ? U : V;
        const unsigned short* w0 = wb + (size_t)col0 * 128 + lg * 8;
        const unsigned short* w1 = wb + (size_t)col1 * 128 + lg * 8;
        f32x4 a0 = {0.f, 0.f, 0.f, 0.f}, a1 = {0.f, 0.f, 0.f, 0.f};
#pragma unroll
        for (int k = 0; k < 4; k++) {
            a0 = MFMA(A[k], *(const bf16x8*)(w0 + k * 32), a0, 0, 0, 0);
            a1 = MFMA(A[k], *(const bf16x8*)(w1 + k * 32), a1, 0, 0, 0);
        }
        float bb0 = (o == 0) ? bn[col0] : 0.0f;
        float bb1 = (o == 0) ? bn[col1] : 0.0f;
        unsigned short* op = ob + (size_t)row0 * 128;
#pragma unroll
        for (int i = 0; i < 4; i++) {
            int r = lg * 4 + i;
            op[(size_t)r * 128 + col0] = (unsigned short)f2bf(a0[i] + bb0);
            op[(size_t)r * 128 + col1] = (unsigned short)f2bf(a1[i] + bb1);
        }
    }
}

// ---------------- EDGE: pre = U[s]+V[d]+ef@WE+beff; score=tanh(pre)@W2+b2; e=exp ----------------
__global__ __launch_bounds__(256) void k_edge2(const float* __restrict__ ef,
                                               const int* __restrict__ eis,
                                               const int* __restrict__ eid,
                                               const unsigned short* __restrict__ WET,
                                               const unsigned short* __restrict__ U,
                                               const unsigned short* __restrict__ V,
                                               const float* __restrict__ beff,
                                               const float* __restrict__ W2,
                                               const float* __restrict__ b2p,
                                               float* __restrict__ ebuf) {
    __shared__ float part[4][64];
    int tid = threadIdx.x, w = tid >> 6, lane = tid & 63, lr = lane & 15, lg = lane >> 4;
    long e0 = (long)blockIdx.x * 64;
    long rem = ((long)EE - e0) / 16;
    int n16 = rem < 4 ? (int)rem : 4;
    int col0 = w * 32 + lr, col1 = col0 + 16;
    bf16x8 B0[2], B1[2];
#pragma unroll
    for (int kk = 0; kk < 2; kk++) {
        B0[kk] = *(const bf16x8*)(WET + (size_t)col0 * 64 + kk * 32 + lg * 8);
        B1[kk] = *(const bf16x8*)(WET + (size_t)col1 * 64 + kk * 32 + lg * 8);
    }
    float be0 = beff[col0], be1 = beff[col1], w20 = W2[col0], w21 = W2[col1];
    for (int i16 = 0; i16 < n16; i16++) {
        long eg0 = e0 + i16 * 16;
        const float* ep = ef + (size_t)(eg0 + lr) * 64;
        f32x4 a0 = {0.f, 0.f, 0.f, 0.f}, a1 = {0.f, 0.f, 0.f, 0.f};
#pragma unroll
        for (int kk = 0; kk < 2; kk++) {
            bf16x8 a = mk_hi(ep + kk * 32 + lg * 8);
            a0 = MFMA(a, B0[kk], a0, 0, 0, 0);
            a1 = MFMA(a, B1[kk], a1, 0, 0, 0);
        }
        int4 s4 = *(const int4*)(eis + eg0 + lg * 4);
        int4 d4 = *(const int4*)(eid + eg0 + lg * 4);
        int ss[4] = {s4.x, s4.y, s4.z, s4.w};
        int dd[4] = {d4.x, d4.y, d4.z, d4.w};
#pragma unroll
        for (int i = 0; i < 4; i++) {
            float u0 = bf2f(U[(size_t)ss[i] * 128 + col0]) + bf2f(V[(size_t)dd[i] * 128 + col0]);
            float u1 = bf2f(U[(size_t)ss[i] * 128 + col1]) + bf2f(V[(size_t)dd[i] * 128 + col1]);
            float v = tanhf_fast(a0[i] + u0 + be0) * w20 + tanhf_fast(a1[i] + u1 + be1) * w21;
            v += __shfl_xor(v, 1);
            v += __shfl_xor(v, 2);
            v += __shfl_xor(v, 4);
            v += __shfl_xor(v, 8);
            if (lr == 0) part[w][i16 * 16 + lg * 4 + i] = v;
        }
    }
    __syncthreads();
    if (tid < n16 * 16) {
        long e = e0 + tid;
        float a = part[0][tid] + part[1][tid] + part[2][tid] + part[3][tid] + b2p[0];
        ebuf[e] = __expf(a);
    }
}

// ---------------- TAIL-A2: CSR gather-agg + oW GEMM + LN + relu + score MLP ----------------
__global__ __launch_bounds__(256) void k_tailA2(const int* __restrict__ rowptr,
                                                const int* __restrict__ ceid,
                                                const int* __restrict__ cdst,
                                                const float* __restrict__ ebuf,
                                                const unsigned short* __restrict__ hbf,
                                                const unsigned short* __restrict__ Whi,
                                                const unsigned short* __restrict__ Wlo,
                                                const float* __restrict__ ob,
                                                const float* __restrict__ g,
                                                const float* __restrict__ bln,
                                                const unsigned short* __restrict__ Shi,
                                                const float* __restrict__ sb1,
                                                const float* __restrict__ sW2,
                                                const float* __restrict__ sb2,
                                                float* __restrict__ emb,
                                                float* __restrict__ scores, int t) {
    __shared__ __align__(16) float T[16][132];
    __shared__ __align__(16) float T2[16][132];
    __shared__ float mu16[16], rs16[16], part[4][16];
    int tid = threadIdx.x;
    long row0 = (long)blockIdx.x * 16;
    int w = tid >> 6, lane = tid & 63, lr = lane & 15, lg = lane >> 4;
    int c0 = lane * 2;
    // CSR gather aggregation: agg[n] = sum ev*h[d] / sum ev
    for (int q = 0; q < 4; q++) {
        int rr = w * 4 + q;
        long n = row0 + rr;
        int p0 = rowptr[n], p1 = rowptr[n + 1];
        float a0 = 0.0f, a1 = 0.0f, sev = 0.0f;
        for (int p = p0; p < p1; p++) {
            float ev = ebuf[ceid[p]];
            int d = cdst[p];
            unsigned hv = *(const unsigned*)(hbf + (size_t)d * 128 + c0);
            a0 = fmaf(ev, bf2f((unsigned short)(hv & 0xffff)), a0);
            a1 = fmaf(ev, bf2f((unsigned short)(hv >> 16)), a1);
            sev += ev;
        }
        float inv = 1.0f / (sev + 1e-16f);
        T[rr][c0] = a0 * inv;
        T[rr][c0 + 1] = a1 * inv;
    }
    __syncthreads();
    int col0 = w * 32 + lr, col1 = col0 + 16;
    int j = tid & 127, half = tid >> 7;
    {
        bf16x8 ahi[4], alo[4];
#pragma unroll
        for (int k = 0; k < 4; k++) mk_split(&T[lr][k * 32 + lg * 8], ahi[k], alo[k]);
        const unsigned short* wh0 = Whi + (size_t)col0 * 128 + lg * 8;
        const unsigned short* wl0 = Wlo + (size_t)col0 * 128 + lg * 8;
        const unsigned short* wh1 = Whi + (size_t)col1 * 128 + lg * 8;
        const unsigned short* wl1 = Wlo + (size_t)col1 * 128 + lg * 8;
        f32x4 a0 = {0.f, 0.f, 0.f, 0.f}, a1 = {0.f, 0.f, 0.f, 0.f};
#pragma unroll
        for (int k = 0; k < 4; k++) {
            bf16x8 bh = *(const bf16x8*)(wh0 + k * 32), bl = *(const bf16x8*)(wl0 + k * 32);
            a0 = MFMA(ahi[k], bh, a0, 0, 0, 0);
            a0 = MFMA(alo[k], bh, a0, 0, 0, 0);
            a0 = MFMA(ahi[k], bl, a0, 0, 0, 0);
            bh = *(const bf16x8*)(wh1 + k * 32); bl = *(const bf16x8*)(wl1 + k * 32);
            a1 = MFMA(ahi[k], bh, a1, 0, 0, 0);
            a1 = MFMA(alo[k], bh, a1, 0, 0, 0);
            a1 = MFMA(ahi[k], bl, a1, 0, 0, 0);
        }
#pragma unroll
        for (int i = 0; i < 4; i++) {
            int r = lg * 4 + i;
            T2[r][col0] = a0[i] + ob[col0];
            T2[r][col1] = a1[i] + ob[col1];
        }
    }
    __syncthreads();
    {
        int gr = tid >> 4, l16 = tid & 15;
        float sm = 0.0f, sq = 0.0f;
#pragma unroll
        for (int i = 0; i < 8; i++) {
            float v = T2[gr][l16 + 16 * i];
            sm += v; sq += v * v;
        }
#pragma unroll
        for (int m = 1; m < 16; m <<= 1) { sm += __shfl_xor(sm, m); sq += __shfl_xor(sq, m); }
        if (l16 == 0) {
            float mean = sm * (1.0f / 128.0f);
            float var = sq * (1.0f / 128.0f) - mean * mean;
            mu16[gr] = mean;
            rs16[gr] = rsqrtf(var + 1e-5f);
        }
    }
    __syncthreads();
    {
        float gj = g[j], bb = bln[j];
#pragma unroll
        for (int r = 0; r < 8; r++) {
            int rr = half * 8 + r;
            float v = fmaxf((T2[rr][j] - mu16[rr]) * rs16[rr] * gj + bb, 0.0f);
            emb[(row0 + rr) * 128 + j] = v;
            T2[rr][j] = v;
        }
    }
    __syncthreads();
    {
        bf16x8 ah[4];
#pragma unroll
        for (int k = 0; k < 4; k++) ah[k] = mk_hi(&T2[lr][k * 32 + lg * 8]);
        const unsigned short* wh0 = Shi + (size_t)col0 * 128 + lg * 8;
        const unsigned short* wh1 = Shi + (size_t)col1 * 128 + lg * 8;
        f32x4 a0 = {0.f, 0.f, 0.f, 0.f}, a1 = {0.f, 0.f, 0.f, 0.f};
#pragma unroll
        for (int k = 0; k < 4; k++) {
            a0 = MFMA(ah[k], *(const bf16x8*)(wh0 + k * 32), a0, 0, 0, 0);
            a1 = MFMA(ah[k], *(const bf16x8*)(wh1 + k * 32), a1, 0, 0, 0);
        }
        float b0 = sb1[col0], b1v = sb1[col1], w20 = sW2[col0], w21 = sW2[col1];
#pragma unroll
        for (int i = 0; i < 4; i++) {
            int r = lg * 4 + i;
            float v = tanhf_fast(a0[i] + b0) * w20 + tanhf_fast(a1[i] + b1v) * w21;
            v += __shfl_xor(v, 1);
            v += __shfl_xor(v, 2);
            v += __shfl_xor(v, 4);
            v += __shfl_xor(v, 8);
            if (lr == 0) part[w][r] = v;
        }
    }
    __syncthreads();
    if (tid < 16)
        scores[(row0 + tid) * 2 + t] = part[0][tid] + part[1][tid] + part[2][tid] + part[3][tid] + sb2[0];
}

// ---------------- TAIL-B1: fused2 = relu(LN((w0*emb0+w1*emb1)@eoW + eob)) ----------------
__global__ __launch_bounds__(256) void k_tailB1(const float* __restrict__ emb0,
                                                const float* __restrict__ emb1,
                                                const float* __restrict__ scores,
                                                const unsigned short* __restrict__ Fhi,
                                                const unsigned short* __restrict__ Flo,
                                                const float* __restrict__ eob,
                                                const float* __restrict__ elg,
                                                const float* __restrict__ elb,
                                                float* __restrict__ fused2) {
    __shared__ __align__(16) float T[16][132];
    __shared__ __align__(16) float T2[16][132];
    __shared__ float mu16[16], rs16[16], w0s[16], w1s[16];
    int tid = threadIdx.x;
    long row0 = (long)blockIdx.x * 16;
    if (tid < 16) {
        long r = row0 + tid;
        float s0 = scores[r * 2], s1 = scores[r * 2 + 1];
        float mx = fmaxf(s0, s1);
        float e0 = __expf(s0 - mx), e1 = __expf(s1 - mx);
        float inv = 1.0f / (e0 + e1);
        w0s[tid] = e0 * inv;
        w1s[tid] = e1 * inv;
    }
    __syncthreads();
#pragma unroll
    for (int i = 0; i < 8; i++) {
        int idx = tid + i * 256;
        int r = idx >> 7, c = idx & 127;
        T[r][c] = w0s[r] * emb0[(row0 + r) * 128 + c] + w1s[r] * emb1[(row0 + r) * 128 + c];
    }
    __syncthreads();
    int w = tid >> 6, lane = tid & 63, lr = lane & 15, lg = lane >> 4;
    int col0 = w * 32 + lr, col1 = col0 + 16;
    int j = tid & 127, half = tid >> 7;
    {
        bf16x8 ahi[4], alo[4];
#pragma unroll
        for (int k = 0; k < 4; k++) mk_split(&T[lr][k * 32 + lg * 8], ahi[k], alo[k]);
        const unsigned short* wh0 = Fhi + (size_t)col0 * 128 + lg * 8;
        const unsigned short* wl0 = Flo + (size_t)col0 * 128 + lg * 8;
        const unsigned short* wh1 = Fhi + (size_t)col1 * 128 + lg * 8;
        const unsigned short* wl1 = Flo + (size_t)col1 * 128 + lg * 8;
        f32x4 a0 = {0.f, 0.f, 0.f, 0.f}, a1 = {0.f, 0.f, 0.f, 0.f};
#pragma unroll
        for (int k = 0; k < 4; k++) {
            bf16x8 bh = *(const bf16x8*)(wh0 + k * 32), bl = *(const bf16x8*)(wl0 + k * 32);
            a0 = MFMA(ahi[k], bh, a0, 0, 0, 0);
            a0 = MFMA(alo[k], bh, a0, 0, 0, 0);
            a0 = MFMA(ahi[k], bl, a0, 0, 0, 0);
            bh = *(const bf16x8*)(wh1 + k * 32); bl = *(const bf16x8*)(wl1 + k * 32);
            a1 = MFMA(ahi[k], bh, a1, 0, 0, 0);
            a1 = MFMA(alo[k], bh, a1, 0, 0, 0);
            a1 = MFMA(ahi[k], bl, a1, 0, 0, 0);
        }
#pragma unroll
        for (int i = 0; i < 4; i++) {
            int r = lg * 4 + i;
            T2[r][col0] = a0[i] + eob[col0];
            T2[r][col1] = a1[i] + eob[col1];
        }
    }
    __syncthreads();
    {
        int gr = tid >> 4, l16 = tid & 15;
        float sm = 0.0f, sq = 0.0f;
#pragma unroll
        for (int i = 0; i < 8; i++) {
            float v = T2[gr][l16 + 16 * i];
            sm += v; sq += v * v;
        }
#pragma unroll
        for (int m = 1; m < 16; m <<= 1) { sm += __shfl_xor(sm, m); sq += __shfl_xor(sq, m); }
        if (l16 == 0) {
            float mean = sm * (1.0f / 128.0f);
            float var = sq * (1.0f / 128.0f) - mean * mean;
            mu16[gr] = mean;
            rs16[gr] = rsqrtf(var + 1e-5f);
        }
    }
    __syncthreads();
    {
        float gj = elg[j], bb = elb[j];
#pragma unroll
        for (int r = 0; r < 8; r++) {
            int rr = half * 8 + r;
            float v = fmaxf((T2[rr][j] - mu16[rr]) * rs16[rr] * gj + bb, 0.0f);
            fused2[(row0 + rr) * 128 + j] = v;
        }
    }
}

// ---------------- FSUM: fsum[l] = sum_{lev=l} fused2 ----------------
__global__ __launch_bounds__(256) void k_fsum(const float* __restrict__ fused2,
                                              const int* __restrict__ lev,
                                              float* __restrict__ fsumg) {
    __shared__ float ls[2][4][128];
    int tid = threadIdx.x, half = tid >> 7, j = tid & 127;
#pragma unroll
    for (int l = 0; l < 4; l++) ls[half][l][j] = 0.0f;
    __syncthreads();
    for (long row = (long)blockIdx.x * 2 + half; row < NN; row += (long)gridDim.x * 2) {
        int l = lev[row];
        ls[half][l][j] += fused2[row * 128 + j];
    }
    __syncthreads();
    if (half == 0) {
#pragma unroll
        for (int l = 0; l < 4; l++) atomicAdd(&fsumg[l * 128 + j], ls[0][l][j] + ls[1][l][j]);
    }
}

// ---------------- FIN2: lmean[l] = (fsum[l]@hpW[l]+cnt*hpb[l])/cnt; lmw[l]=lmean[l]@W1b+hb1 --
__global__ void k_fin2(const float* __restrict__ fsum, const int* __restrict__ cnt4,
                       const float* __restrict__ hpW, const float* __restrict__ hpb,
                       const float* __restrict__ W1b, const float* __restrict__ b1,
                       float* __restrict__ lmean, float* __restrict__ lmw) {
    __shared__ float fs[128];
    __shared__ float lml[128];
    int l = blockIdx.x, j = threadIdx.x;
    fs[j] = fsum[l * 128 + j];
    __syncthreads();
    float c = (float)cnt4[l];
    float a = c * hpb[l * 128 + j];
    const float* wp = hpW + (size_t)l * 16384;
    for (int k = 0; k < 128; k++) a = fmaf(fs[k], wp[k * 128 + j], a);
    float cm = c < 1.0f ? 1.0f : c;
    float v = a / cm;
    lmean[l * 128 + j] = v;
    lml[j] = v;
    __syncthreads();
    float b = b1[j];
    for (int k = 0; k < 128; k++) b = fmaf(lml[k], W1b[k * 128 + j], b);
    lmw[l * 128 + j] = b;
}

// ---------------- TAIL-CD2 (level-bucketed): QW[l] GEMM + hier attn + final GEMM + LN -> out --
__global__ __launch_bounds__(256) void k_tailCD2(const float* __restrict__ fused2,
                                                 const int* __restrict__ perm,
                                                 const int* __restrict__ cnt4,
                                                 const int* __restrict__ off4,
                                                 const int* __restrict__ boff5,
                                                 const unsigned short* __restrict__ QWhi,
                                                 const unsigned short* __restrict__ QWlo,
                                                 const float* __restrict__ qb,
                                                 const float* __restrict__ lmw,
                                                 const float* __restrict__ lmean,
                                                 const float* __restrict__ hW2,
                                                 const unsigned short* __restrict__ Ohi,
                                                 const unsigned short* __restrict__ Olo,
                                                 const float* __restrict__ hob,
                                                 const float* __restrict__ hlg,
                                                 const float* __restrict__ hlb,
                                                 float* __restrict__ out) {
    __shared__ __align__(16) float T[16][132];
    __shared__ __align__(16) float T2[16][132];
    __shared__ float lm[4][128];
    __shared__ float lmwS[4][128];
    __shared__ float w2S[128];
    __shared__ float scS[16][4];
    __shared__ float aw[16][4];
    __shared__ float mu16[16], rs16[16];
    __shared__ int idx16[16];
    int tid = threadIdx.x;
    int b = blockIdx.x;
    if (b >= boff5[4]) return;
    int l = (b >= boff5[3]) ? 3 : (b >= boff5[2]) ? 2 : (b >= boff5[1]) ? 1 : 0;
    int bi = b - boff5[l];
    int base = off4[l] + bi * 16;
    int last = off4[l] + cnt4[l] - 1;
    if (tid < 16) {
        int gp = base + tid;
        if (gp > last) gp = last;
        idx16[tid] = perm[gp];
    }
    for (int idx = tid; idx < 512; idx += 256) {
        lm[idx >> 7][idx & 127] = lmean[idx];
        lmwS[idx >> 7][idx & 127] = lmw[idx];
    }
    if (tid < 128) w2S[tid] = hW2[tid];
    __syncthreads();
#pragma unroll
    for (int i = 0; i < 8; i++) {
        int idx = tid + i * 256;
        int r = idx >> 7, c = idx & 127;
        T[r][c] = fused2[(size_t)idx16[r] * 128 + c];
    }
    __syncthreads();
    int w = tid >> 6, lane = tid & 63, lr = lane & 15, lg = lane >> 4;
    int col0 = w * 32 + lr, col1 = col0 + 16;
    int j = tid & 127, half = tid >> 7;
    // hfa = fused2 @ QW[l] + qb[l]
    {
        bf16x8 ahi[4], alo[4];
#pragma unroll
        for (int k = 0; k < 4; k++) mk_split(&T[lr][k * 32 + lg * 8], ahi[k], alo[k]);
        const unsigned short* wh0 = QWhi + (size_t)l * 16384 + (size_t)col0 * 128 + lg * 8;
        const unsigned short* wl0 = QWlo + (size_t)l * 16384 + (size_t)col0 * 128 + lg * 8;
        const unsigned short* wh1 = QWhi + (size_t)l * 16384 + (size_t)col1 * 128 + lg * 8;
        const unsigned short* wl1 = QWlo + (size_t)l * 16384 + (size_t)col1 * 128 + lg * 8;
        f32x4 a0 = {0.f, 0.f, 0.f, 0.f}, a1 = {0.f, 0.f, 0.f, 0.f};
#pragma unroll
        for (int k = 0; k < 4; k++) {
            bf16x8 bh = *(const bf16x8*)(wh0 + k * 32), bl = *(const bf16x8*)(wl0 + k * 32);
            a0 = MFMA(ahi[k], bh, a0, 0, 0, 0);
            a0 = MFMA(alo[k], bh, a0, 0, 0, 0);
            a0 = MFMA(ahi[k], bl, a0, 0, 0, 0);
            bh = *(const bf16x8*)(wh1 + k * 32); bl = *(const bf16x8*)(wl1 + k * 32);
            a1 = MFMA(ahi[k], bh, a1, 0, 0, 0);
            a1 = MFMA(alo[k], bh, a1, 0, 0, 0);
            a1 = MFMA(ahi[k], bl, a1, 0, 0, 0);
        }
#pragma unroll
        for (int i = 0; i < 4; i++) {
            int r = lg * 4 + i;
            T2[r][col0] = a0[i] + qb[l * 128 + col0];
            T2[r][col1] = a1[i] + qb[l * 128 + col1];
        }
    }
    __syncthreads();
    // hier scores: 4 threads per (row, level') pair, stride-4 cols
    {
        int p = tid >> 2, sub = tid & 3;
        int pr = p & 15, pl = p >> 4;
        float s = 0.0f;
#pragma unroll
        for (int jj = 0; jj < 32; jj++) {
            int j2 = sub + 4 * jj;
            s += tanhf_fast(T2[pr][j2] + lmwS[pl][j2]) * w2S[j2];
        }
        s += __shfl_xor(s, 1);
        s += __shfl_xor(s, 2);
        if (sub == 0) scS[pr][pl] = s;
    }
    __syncthreads();
    if (tid < 16) {
        float sc[4];
        float mx = -1e30f;
#pragma unroll
        for (int ll = 0; ll < 4; ll++) {
            sc[ll] = scS[tid][ll];
            mx = fmaxf(mx, sc[ll]);
        }
        float s = 0.0f;
#pragma unroll
        for (int ll = 0; ll < 4; ll++) { sc[ll] = __expf(sc[ll] - mx); s += sc[ll]; }
        float inv = 1.0f / s;
#pragma unroll
        for (int ll = 0; ll < 4; ll++) aw[tid][ll] = sc[ll] * inv;
    }
    __syncthreads();
    // enhanced = aw @ lmean
#pragma unroll
    for (int r = 0; r < 8; r++) {
        int rr = half * 8 + r;
        float e = 0.0f;
#pragma unroll
        for (int ll = 0; ll < 4; ll++) e = fmaf(aw[rr][ll], lm[ll][j], e);
        T[rr][j] = e;
    }
    __syncthreads();
    // out = relu(LN(enh @ hoW + hob))
    {
        bf16x8 ahi[4], alo[4];
#pragma unroll
        for (int k = 0; k < 4; k++) mk_split(&T[lr][k * 32 + lg * 8], ahi[k], alo[k]);
        const unsigned short* wh0 = Ohi + (size_t)col0 * 128 + lg * 8;
        const unsigned short* wl0 = Olo + (size_t)col0 * 128 + lg * 8;
        const unsigned short* wh1 = Ohi + (size_t)col1 * 128 + lg * 8;
        const unsigned short* wl1 = Olo + (size_t)col1 * 128 + lg * 8;
        f32x4 a0 = {0.f, 0.f, 0.f, 0.f}, a1 = {0.f, 0.f, 0.f, 0.f};
#pragma unroll
        for (int k = 0; k < 4; k++) {
            bf16x8 bh = *(const bf16x8*)(wh0 + k * 32), bl = *(const bf16x8*)(wl0 + k * 32);
            a0 = MFMA(ahi[k], bh, a0, 0, 0, 0);
            a0 = MFMA(alo[k], bh, a0, 0, 0, 0);
            a0 = MFMA(ahi[k], bl, a0, 0, 0, 0);
            bh = *(const bf16x8*)(wh1 + k * 32); bl = *(const bf16x8*)(wl1 + k * 32);
            a1 = MFMA(ahi[k], bh, a1, 0, 0, 0);
            a1 = MFMA(alo[k], bh, a1, 0, 0, 0);
            a1 = MFMA(ahi[k], bl, a1, 0, 0, 0);
        }
#pragma unroll
        for (int i = 0; i < 4; i++) {
            int r = lg * 4 + i;
            T2[r][col0] = a0[i] + hob[col0];
            T2[r][col1] = a1[i] + hob[col1];
        }
    }
    __syncthreads();
    {
        int gr = tid >> 4, l16 = tid & 15;
        float sm = 0.0f, sq = 0.0f;
#pragma unroll
        for (int i = 0; i < 8; i++) {
            float v = T2[gr][l16 + 16 * i];
            sm += v; sq += v * v;
        }
#pragma unroll
        for (int m = 1; m < 16; m <<= 1) { sm += __shfl_xor(sm, m); sq += __shfl_xor(sq, m); }
        if (l16 == 0) {
            float mean = sm * (1.0f / 128.0f);
            float var = sq * (1.0f / 128.0f) - mean * mean;
            mu16[gr] = mean;
            rs16[gr] = rsqrtf(var + 1e-5f);
        }
    }
    __syncthreads();
    {
        float gj = hlg[j], bb = hlb[j];
#pragma unroll
        for (int r = 0; r < 8; r++) {
            int rr = half * 8 + r;
            float v = (T2[rr][j] - mu16[rr]) * rs16[rr] * gj + bb;
            out[(size_t)idx16[rr] * 128 + j] = fmaxf(v, 0.0f);
        }
    }
}

extern "C" void kernel_launch(void* const* d_in, const int* in_sizes, int n_in,
                              void* d_out, int out_size, void* d_ws, size_t ws_size,
                              hipStream_t stream) {
    const float* nf  = (const float*)d_in[0];
    const float* ef  = (const float*)d_in[1];
    const int*   lev = (const int*)d_in[2];
    const int*   ei  = (const int*)d_in[3];
    const float* nlW = (const float*)d_in[4];
    const float* nlb = (const float*)d_in[5];
    const float* neW = (const float*)d_in[6];
    const float* neb = (const float*)d_in[7];
    const float* aW1 = (const float*)d_in[8];
    const float* ab1 = (const float*)d_in[9];
    const float* aW2 = (const float*)d_in[10];
    const float* ab2 = (const float*)d_in[11];
    const float* oW  = (const float*)d_in[12];
    const float* ob  = (const float*)d_in[13];
    const float* lng = (const float*)d_in[14];
    const float* lnb = (const float*)d_in[15];
    const float* eW1 = (const float*)d_in[16];
    const float* eb1 = (const float*)d_in[17];
    const float* eW2 = (const float*)d_in[18];
    const float* eb2 = (const float*)d_in[19];
    const float* eoW = (const float*)d_in[20];
    const float* eob = (const float*)d_in[21];
    const float* elg = (const float*)d_in[22];
    const float* elb = (const float*)d_in[23];
    const float* hpW = (const float*)d_in[24];
    const float* hpb = (const float*)d_in[25];
    const float* hW1 = (const float*)d_in[26];
    const float* hb1 = (const float*)d_in[27];
    const float* hW2 = (const float*)d_in[28];
    const float* hb2 = (const float*)d_in[29];
    const float* hoW = (const float*)d_in[30];
    const float* hob = (const float*)d_in[31];
    const float* hlg = (const float*)d_in[32];
    const float* hlb = (const float*)d_in[33];

    float* ws = (float*)d_ws;
    size_t NH = (size_t)NN * 128;
    float* fused2 = ws;              // NH (CSR scratch aliases this until tailB1)
    float* emb0   = fused2 + NH;     // NH
    float* emb1   = emb0 + NH;       // NH
    float* ebuf   = emb1 + NH;       // EE
    float* scores = ebuf + EE;       // 2*NN
    float* beff   = scores + (size_t)2 * NN;  // 128
    float* fsum   = beff + 128;      // 512
    float* lmean  = fsum + 512;      // 512
    float* lmw    = lmean + 512;     // 512
    float* qb     = lmw + 512;       // 512
    unsigned short* U    = (unsigned short*)(qb + 512);   // NH
    unsigned short* V    = U + NH;                        // NH
    unsigned short* hbf  = V + NH;                        // NH
    unsigned short* WhT  = hbf + NH;                      // 16384
    unsigned short* WUT  = WhT + 16384;
    unsigned short* WVT  = WUT + 16384;
    unsigned short* WET  = WVT + 16384;                   // 8192
    unsigned short* twhi = WET + 8192;                    // 6*16384
    unsigned short* twlo = twhi + 6 * 16384;              // 6*16384
    unsigned short* QWhi = twlo + 6 * 16384;              // 4*16384
    unsigned short* QWlo = QWhi + 4 * 16384;              // 4*16384
    int* perm  = (int*)(QWlo + 4 * 16384);                // NN
    int* cnt4  = perm + NN;                               // 4
    int* off4  = cnt4 + 4;                                // 4
    int* boff5 = off4 + 4;                                // 5
    int* cursorL = boff5 + 5;                             // 4
    // CSR scratch aliases fused2 (dead until k_tailB1)
    int* ceid   = (int*)fused2;          // EE
    int* cdst   = ceid + EE;             // EE
    int* deg    = cdst + EE;             // NN
    int* rowptr = deg + NN;              // NN+1
    int* cursor = rowptr + NN + 1;       // NN
    int* stmp   = cursor + NN;           // NN
    int* sbsum  = stmp + NN;             // 256
    int* sboff  = sbsum + 256;           // 256
    float* out = (float*)d_out;

    WSrc ps;
    ps.s[0] = oW;               // oW t0
    ps.s[1] = oW + 16384;       // oW t1
    ps.s[2] = eW1;              // eW1 t0
    ps.s[3] = eW1 + 16384;      // eW1 t1
    ps.s[4] = eoW;
    ps.s[5] = hoW;

    // level bucketing (independent of the main pipeline)
    k_zeroi<<<1, 4, 0, stream>>>(cnt4, 4);
    k_count<<<128, 256, 0, stream>>>(lev, cnt4);
    k_scan<<<1, 1, 0, stream>>>(cnt4, off4, boff5, cursorL);
    k_scatter<<<125, 256, 0, stream>>>(lev, cursorL, perm);

    k_prep_tail<<<6 * 64, 256, 0, stream>>>(ps, twhi, twlo);
    k_prep_q<<<258, 256, 0, stream>>>(hpW, hpb, hW1, QWhi, QWlo, qb);
    k_zero<<<1, 512, 0, stream>>>(fsum, (size_t)512);

    for (int t = 0; t < 2; t++) {
        const int* eis = ei + (size_t)t * 2 * EE;
        const int* eid = eis + EE;
        // CSR build for this relation
        k_zeroi<<<(NN + 255) / 256, 256, 0, stream>>>(deg, NN);
        k_hist<<<(EE + 255) / 256, 256, 0, stream>>>(eis, deg);
        k_scan1<<<196, 512, 0, stream>>>(deg, stmp, sbsum);
        k_scan2<<<1, 256, 0, stream>>>(sbsum, sboff);
        k_scan3<<<196, 512, 0, stream>>>(deg, stmp, sboff, rowptr, cursor);
        k_csr_scatter<<<(EE + 255) / 256, 256, 0, stream>>>(eis, eid, cursor, ceid, cdst);

        k_prep_head<<<128, 128, 0, stream>>>(nlW + (size_t)t * 16384, nlb + t * 128,
                                             aW1 + (size_t)t * 384 * 128, ab1 + t * 128,
                                             neW + (size_t)t * 64 * 128, neb + t * 128,
                                             WhT, WUT, WVT, WET, beff);
        k_head<<<NN / 16, 256, 0, stream>>>(nf, WhT, WUT, WVT, nlb + t * 128, hbf, U, V);
        k_edge2<<<(EE + 63) / 64, 256, 0, stream>>>(ef + (size_t)t * EE * 64, eis, eid,
                                                    WET, U, V, beff, aW2 + t * 128,
                                                    ab2 + t, ebuf);
        float* embt = (t == 0) ? emb0 : emb1;
        k_tailA2<<<NN / 16, 256, 0, stream>>>(rowptr, ceid, cdst, ebuf, hbf,
                                              twhi + (size_t)t * 16384, twlo + (size_t)t * 16384,
                                              ob + t * 128, lng + t * 128, lnb + t * 128,
                                              twhi + (size_t)(2 + t) * 16384,
                                              eb1 + t * 128, eW2 + t * 128, eb2 + t,
                                              embt, scores, t);
    }
    k_tailB1<<<NN / 16, 256, 0, stream>>>(emb0, emb1, scores,
                                          twhi + (size_t)4 * 16384, twlo + (size_t)4 * 16384,
                                          eob, elg, elb, fused2);
    k_fsum<<<256, 256, 0, stream>>>(fused2, lev, fsum);
    k_fin2<<<4, 128, 0, stream>>>(fsum, cnt4, hpW, hpb, hW1 + 16384, hb1, lmean, lmw);
    k_tailCD2<<<NN / 16 + 4, 256, 0, stream>>>(fused2, perm, cnt4, off4, boff5,
                                               QWhi, QWlo, qb, lmw, lmean, hW2,
                                               twhi + (size_t)5 * 16384, twlo + (size_t)5 * 16384,
                                               hob, hlg, hlb, out);
}

// Round 7
// 1084.639 us; speedup vs baseline: 1.5291x; 1.0929x over previous
//
#include <hip/hip_runtime.h>
#include <math.h>

#define NN 100000
#define EE 500000
// D=H=128, ED=64, T=2, L=4

typedef __attribute__((ext_vector_type(8))) short bf16x8;
typedef __attribute__((ext_vector_type(4))) float f32x4;
#define MFMA __builtin_amdgcn_mfma_f32_16x16x32_bf16

__device__ inline short f2bf(float x) {
    union { float f; unsigned u; } v; v.f = x;
    unsigned r = v.u + 0x7FFF + ((v.u >> 16) & 1);
    return (short)(r >> 16);
}
__device__ inline float bf2f(unsigned short h) {
    union { unsigned u; float f; } v; v.u = ((unsigned)h) << 16; return v.f;
}
__device__ inline float tanhf_fast(float x) {
    float e = __expf(2.0f * x);
    return 1.0f - 2.0f * __builtin_amdgcn_rcpf(e + 1.0f);
}

__device__ inline bf16x8 mk_hi(const float* p) {
    float4 a = *(const float4*)p, b = *(const float4*)(p + 4);
    float v[8] = {a.x, a.y, a.z, a.w, b.x, b.y, b.z, b.w};
    bf16x8 h;
#pragma unroll
    for (int i = 0; i < 8; i++) h[i] = f2bf(v[i]);
    return h;
}
__device__ inline void mk_split(const float* p, bf16x8& hi, bf16x8& lo) {
    float4 a = *(const float4*)p, b = *(const float4*)(p + 4);
    float v[8] = {a.x, a.y, a.z, a.w, b.x, b.y, b.z, b.w};
#pragma unroll
    for (int i = 0; i < 8; i++) {
        short h = f2bf(v[i]);
        hi[i] = h;
        lo[i] = f2bf(v[i] - bf2f((unsigned short)h));
    }
}

// ---------------- zero fill ----------------
__global__ void k_zero(float* __restrict__ p, size_t n) {
    size_t i = (size_t)blockIdx.x * blockDim.x + threadIdx.x;
    size_t stride = (size_t)gridDim.x * blockDim.x;
    for (; i < n; i += stride) p[i] = 0.0f;
}
__global__ void k_zeroi(int* __restrict__ p, int n) {
    int i = blockIdx.x * blockDim.x + threadIdx.x;
    if (i < n) p[i] = 0;
}

// ---------------- CSR build (by source) ----------------
__global__ __launch_bounds__(256) void k_hist(const int* __restrict__ eis, int* __restrict__ deg) {
    int e = blockIdx.x * 256 + threadIdx.x;
    if (e < EE) atomicAdd(&deg[eis[e]], 1);
}
__global__ __launch_bounds__(512) void k_scan1(const int* __restrict__ deg,
                                               int* __restrict__ tmp, int* __restrict__ bsum) {
    __shared__ int sh[2][512];
    int b = blockIdx.x, tid = threadIdx.x;
    int i = b * 512 + tid;
    int v = (i < NN) ? deg[i] : 0;
    int cur = 0;
    sh[0][tid] = v;
    __syncthreads();
    for (int off = 1; off < 512; off <<= 1) {
        int nxt = cur ^ 1;
        int a = sh[cur][tid];
        if (tid >= off) a += sh[cur][tid - off];
        sh[nxt][tid] = a;
        __syncthreads();
        cur = nxt;
    }
    int incl = sh[cur][tid];
    if (i < NN) tmp[i] = incl;
    if (tid == 511) bsum[b] = incl;
}
__global__ void k_scan2(const int* __restrict__ bsum, int* __restrict__ boff) {
    __shared__ int sh[2][256];
    int tid = threadIdx.x;
    int v = (tid < 196) ? bsum[tid] : 0;
    int cur = 0;
    sh[0][tid] = v;
    __syncthreads();
    for (int off = 1; off < 256; off <<= 1) {
        int nxt = cur ^ 1;
        int a = sh[cur][tid];
        if (tid >= off) a += sh[cur][tid - off];
        sh[nxt][tid] = a;
        __syncthreads();
        cur = nxt;
    }
    boff[tid] = sh[cur][tid] - v;
}
__global__ __launch_bounds__(512) void k_scan3(const int* __restrict__ deg,
                                               const int* __restrict__ tmp,
                                               const int* __restrict__ boff,
                                               int* __restrict__ rowptr, int* __restrict__ cursor) {
    int i = blockIdx.x * 512 + threadIdx.x;
    if (i < NN) {
        int r = tmp[i] - deg[i] + boff[blockIdx.x];
        rowptr[i] = r;
        cursor[i] = r;
    }
    if (i == 0) rowptr[NN] = EE;
}
__global__ __launch_bounds__(256) void k_csr_scatter(const int* __restrict__ eis,
                                                     const int* __restrict__ eid,
                                                     int* __restrict__ cursor,
                                                     int* __restrict__ epos,
                                                     int* __restrict__ cdst) {
    int e = blockIdx.x * 256 + threadIdx.x;
    if (e < EE) {
        int s = eis[e];
        int p = atomicAdd(&cursor[s], 1);
        epos[e] = p;
        cdst[p] = eid[e];
    }
}

// ---------------- level bucketing ----------------
__global__ __launch_bounds__(256) void k_count(const int* __restrict__ lev, int* __restrict__ cnt4) {
    __shared__ int lc[4];
    int tid = threadIdx.x;
    if (tid < 4) lc[tid] = 0;
    __syncthreads();
    for (long n = (long)blockIdx.x * 256 + tid; n < NN; n += (long)gridDim.x * 256)
        atomicAdd(&lc[lev[n]], 1);
    __syncthreads();
    if (tid < 4 && lc[tid]) atomicAdd(&cnt4[tid], lc[tid]);
}

__global__ void k_scan(const int* __restrict__ cnt4, int* __restrict__ off4,
                       int* __restrict__ boff5, int* __restrict__ cursor) {
    int o = 0, b = 0;
    for (int l = 0; l < 4; l++) {
        off4[l] = o; cursor[l] = o; boff5[l] = b;
        o += cnt4[l];
        b += (cnt4[l] + 15) >> 4;
    }
    boff5[4] = b;
}

__global__ __launch_bounds__(256) void k_scatter(const int* __restrict__ lev,
                                                 int* __restrict__ cursor,
                                                 int* __restrict__ perm) {
    __shared__ int lc[4], lb[4], lc2[4];
    int tid = threadIdx.x;
    if (tid < 4) { lc[tid] = 0; lc2[tid] = 0; }
    __syncthreads();
    int start = blockIdx.x * 800, end = start + 800;
    if (end > NN) end = NN;
    for (int n = start + tid; n < end; n += 256) atomicAdd(&lc[lev[n]], 1);
    __syncthreads();
    if (tid < 4 && lc[tid]) lb[tid] = atomicAdd(&cursor[tid], lc[tid]);
    __syncthreads();
    for (int n = start + tid; n < end; n += 256) {
        int l = lev[n];
        int p = atomicAdd(&lc2[l], 1);
        perm[lb[l] + p] = n;
    }
}

// ---------------- prep head: WhT, WUT, WVT, WET (bf16 transposed), beff ----------------
__global__ void k_prep_head(const float* __restrict__ Wn, const float* __restrict__ bn,
                            const float* __restrict__ W1, const float* __restrict__ b1,
                            const float* __restrict__ We, const float* __restrict__ be,
                            unsigned short* __restrict__ WhT, unsigned short* __restrict__ WUT,
                            unsigned short* __restrict__ WVT, unsigned short* __restrict__ WET,
                            float* __restrict__ beff) {
    __shared__ float red[2];
    int j = blockIdx.x, k = threadIdx.x;  // 128 blocks x 128 threads
    WhT[j * 128 + k] = (unsigned short)f2bf(Wn[k * 128 + j]);
    float su = 0.0f, sv = 0.0f;
    for (int m = 0; m < 128; m++) {
        float wkm = Wn[k * 128 + m];
        su = fmaf(wkm, W1[m * 128 + j], su);
        sv = fmaf(wkm, W1[(128 + m) * 128 + j], sv);
    }
    WUT[j * 128 + k] = (unsigned short)f2bf(su);
    WVT[j * 128 + k] = (unsigned short)f2bf(sv);
    if (k < 64) {
        float se = 0.0f;
        for (int m = 0; m < 128; m++) se = fmaf(We[k * 128 + m], W1[(256 + m) * 128 + j], se);
        WET[j * 64 + k] = (unsigned short)f2bf(se);
    }
    float tk = bn[k] * (W1[k * 128 + j] + W1[(128 + k) * 128 + j]) + be[k] * W1[(256 + k) * 128 + j];
#pragma unroll
    for (int o = 32; o > 0; o >>= 1) tk += __shfl_down(tk, o);
    if ((k & 63) == 0) red[k >> 6] = tk;
    __syncthreads();
    if (k == 0) beff[j] = b1[j] + red[0] + red[1];
}

// ---------------- prep tail: split-bf16 transposed weights (6 mats) ----------------
struct WSrc { const float* s[6]; };
__global__ void k_prep_tail(WSrc ps, unsigned short* __restrict__ hi,
                            unsigned short* __restrict__ lo) {
    int m = blockIdx.x >> 6, blk = blockIdx.x & 63;
    const float* src = ps.s[m];
    unsigned short* h = hi + (size_t)m * 16384;
    unsigned short* l = lo + (size_t)m * 16384;
    int idx = blk * 256 + threadIdx.x;  // 0..16383
    int k = idx >> 7, j = idx & 127;
    float v = src[idx];
    short hh = f2bf(v);
    h[j * 128 + k] = (unsigned short)hh;
    l[j * 128 + k] = (unsigned short)f2bf(v - bf2f((unsigned short)hh));
}

// ---------------- prep Q: QW[l] = hpW[l] @ hW1a (transposed split bf16), qb[l] = hpb[l]@hW1a --
__global__ void k_prep_q(const float* __restrict__ hpW, const float* __restrict__ hpb,
                         const float* __restrict__ hW1a,
                         unsigned short* __restrict__ QWhi, unsigned short* __restrict__ QWlo,
                         float* __restrict__ qb) {
    int gidx = blockIdx.x * 256 + threadIdx.x;
    if (gidx < 4 * 16384) {
        int l = gidx >> 14, rem = gidx & 16383;
        int k = rem >> 7, j = rem & 127;
        const float* wr = hpW + (size_t)l * 16384 + (size_t)k * 128;
        float v = 0.0f;
        for (int m = 0; m < 128; m++) v = fmaf(wr[m], hW1a[m * 128 + j], v);
        short hh = f2bf(v);
        QWhi[(size_t)l * 16384 + j * 128 + k] = (unsigned short)hh;
        QWlo[(size_t)l * 16384 + j * 128 + k] = (unsigned short)f2bf(v - bf2f((unsigned short)hh));
    } else {
        int e = gidx - 4 * 16384;
        if (e < 512) {
            int l = e >> 7, j = e & 127;
            float v = 0.0f;
            for (int m = 0; m < 128; m++) v = fmaf(hpb[l * 128 + m], hW1a[m * 128 + j], v);
            qb[l * 128 + j] = v;
        }
    }
}

// ---------------- HEAD: hbf = bf16(nf@Wn+bn), U = bf16(nf@WU), V = bf16(nf@WV) ----------------
__global__ __launch_bounds__(256) void k_head(const float* __restrict__ nf,
                                              const unsigned short* __restrict__ WhT,
                                              const unsigned short* __restrict__ WUT,
                                              const unsigned short* __restrict__ WVT,
                                              const float* __restrict__ bn,
                                              unsigned short* __restrict__ hbf,
                                              unsigned short* __restrict__ U,
                                              unsigned short* __restrict__ V) {
    __shared__ __align__(16) float T[16][132];
    int tid = threadIdx.x;
    long row0 = (long)blockIdx.x * 16;
#pragma unroll
    for (int i = 0; i < 8; i++) {
        int idx = tid + i * 256;
        int r = idx >> 7, c = idx & 127;
        T[r][c] = nf[(row0 + r) * 128 + c];
    }
    __syncthreads();
    int w = tid >> 6, lane = tid & 63, lr = lane & 15, lg = lane >> 4;
    bf16x8 A[4];
#pragma unroll
    for (int k = 0; k < 4; k++) A[k] = mk_hi(&T[lr][k * 32 + lg * 8]);
    int col0 = w * 32 + lr, col1 = col0 + 16;
#pragma unroll
    for (int o = 0; o < 3; o++) {
        const unsigned short* wb = (o == 0) ? WhT : (o == 1) ? WUT : WVT;
        unsigned short* ob = (o == 0) ? hbf : (o == 1) ? U : V;
        const unsigned short* w0 = wb + (size_t)col0 * 128 + lg * 8;
        const unsigned short* w1 = wb + (size_t)col1 * 128 + lg * 8;
        f32x4 a0 = {0.f, 0.f, 0.f, 0.f}, a1 = {0.f, 0.f, 0.f, 0.f};
#pragma unroll
        for (int k = 0; k < 4; k++) {
            a0 = MFMA(A[k], *(const bf16x8*)(w0 + k * 32), a0, 0, 0, 0);
            a1 = MFMA(A[k], *(const bf16x8*)(w1 + k * 32), a1, 0, 0, 0);
        }
        float bb0 = (o == 0) ? bn[col0] : 0.0f;
        float bb1 = (o == 0) ? bn[col1] : 0.0f;
        unsigned short* op = ob + (size_t)row0 * 128;
#pragma unroll
        for (int i = 0; i < 4; i++) {
            int r = lg * 4 + i;
            op[(size_t)r * 128 + col0] = (unsigned short)f2bf(a0[i] + bb0);
            op[(size_t)r * 128 + col1] = (unsigned short)f2bf(a1[i] + bb1);
        }
    }
}

// ---------------- EDGE: pre = U[s]+V[d]+ef@WE+beff; score=tanh(pre)@W2+b2; ev -> CSR slot ----
__global__ __launch_bounds__(256) void k_edge2(const float* __restrict__ ef,
                                               const int* __restrict__ eis,
                                               const int* __restrict__ eid,
                                               const int* __restrict__ epos,
                                               const unsigned short* __restrict__ WET,
                                               const unsigned short* __restrict__ U,
                                               const unsigned short* __restrict__ V,
                                               const float* __restrict__ beff,
                                               const float* __restrict__ W2,
                                               const float* __restrict__ b2p,
                                               float* __restrict__ ebuf) {
    __shared__ float part[4][64];
    int tid = threadIdx.x, w = tid >> 6, lane = tid & 63, lr = lane & 15, lg = lane >> 4;
    long e0 = (long)blockIdx.x * 64;
    long rem = ((long)EE - e0) / 16;
    int n16 = rem < 4 ? (int)rem : 4;
    int col0 = w * 32 + lr, col1 = col0 + 16;
    bf16x8 B0[2], B1[2];
#pragma unroll
    for (int kk = 0; kk < 2; kk++) {
        B0[kk] = *(const bf16x8*)(WET + (size_t)col0 * 64 + kk * 32 + lg * 8);
        B1[kk] = *(const bf16x8*)(WET + (size_t)col1 * 64 + kk * 32 + lg * 8);
    }
    float be0 = beff[col0], be1 = beff[col1], w20 = W2[col0], w21 = W2[col1];
    for (int i16 = 0; i16 < n16; i16++) {
        long eg0 = e0 + i16 * 16;
        const float* ep = ef + (size_t)(eg0 + lr) * 64;
        f32x4 a0 = {0.f, 0.f, 0.f, 0.f}, a1 = {0.f, 0.f, 0.f, 0.f};
#pragma unroll
        for (int kk = 0; kk < 2; kk++) {
            bf16x8 a = mk_hi(ep + kk * 32 + lg * 8);
            a0 = MFMA(a, B0[kk], a0, 0, 0, 0);
            a1 = MFMA(a, B1[kk], a1, 0, 0, 0);
        }
        int4 s4 = *(const int4*)(eis + eg0 + lg * 4);
        int4 d4 = *(const int4*)(eid + eg0 + lg * 4);
        int ss[4] = {s4.x, s4.y, s4.z, s4.w};
        int dd[4] = {d4.x, d4.y, d4.z, d4.w};
#pragma unroll
        for (int i = 0; i < 4; i++) {
            float u0 = bf2f(U[(size_t)ss[i] * 128 + col0]) + bf2f(V[(size_t)dd[i] * 128 + col0]);
            float u1 = bf2f(U[(size_t)ss[i] * 128 + col1]) + bf2f(V[(size_t)dd[i] * 128 + col1]);
            float v = tanhf_fast(a0[i] + u0 + be0) * w20 + tanhf_fast(a1[i] + u1 + be1) * w21;
            v += __shfl_xor(v, 1);
            v += __shfl_xor(v, 2);
            v += __shfl_xor(v, 4);
            v += __shfl_xor(v, 8);
            if (lr == 0) part[w][i16 * 16 + lg * 4 + i] = v;
        }
    }
    __syncthreads();
    if (tid < n16 * 16) {
        long e = e0 + tid;
        float a = part[0][tid] + part[1][tid] + part[2][tid] + part[3][tid] + b2p[0];
        ebuf[epos[e]] = __expf(a);
    }
}

// ---------------- TAIL-A2: CSR gather-agg (16 thr/row) + oW GEMM + LN + relu + score MLP ----
__global__ __launch_bounds__(256) void k_tailA2(const int* __restrict__ rowptr,
                                                const int* __restrict__ cdst,
                                                const float* __restrict__ ebufC,
                                                const unsigned short* __restrict__ hbf,
                                                const unsigned short* __restrict__ Whi,
                                                const unsigned short* __restrict__ Wlo,
                                                const float* __restrict__ ob,
                                                const float* __restrict__ g,
                                                const float* __restrict__ bln,
                                                const unsigned short* __restrict__ Shi,
                                                const float* __restrict__ sb1,
                                                const float* __restrict__ sW2,
                                                const float* __restrict__ sb2,
                                                float* __restrict__ emb,
                                                float* __restrict__ scores, int t) {
    __shared__ __align__(16) float T[16][132];
    __shared__ __align__(16) float T2[16][132];
    __shared__ float mu16[16], rs16[16], part[4][16];
    int tid = threadIdx.x;
    long row0 = (long)blockIdx.x * 16;
    // CSR gather: 16 threads per row, each owns 8 contiguous cols (16B of hbf row)
    {
        int r16 = tid >> 4, sub = tid & 15;
        long n = row0 + r16;
        int p0 = rowptr[n], p1 = rowptr[n + 1];
        float acc[8] = {0, 0, 0, 0, 0, 0, 0, 0};
        float sev = 0.0f;
        for (int p = p0; p < p1; p++) {
            int d = cdst[p];
            float ev = ebufC[p];
            bf16x8 hv = *(const bf16x8*)(hbf + (size_t)d * 128 + sub * 8);
            sev += ev;
#pragma unroll
            for (int i = 0; i < 8; i++) acc[i] = fmaf(ev, bf2f((unsigned short)hv[i]), acc[i]);
        }
        float inv = 1.0f / (sev + 1e-16f);
#pragma unroll
        for (int i = 0; i < 8; i++) T[r16][sub * 8 + i] = acc[i] * inv;
    }
    __syncthreads();
    int w = tid >> 6, lane = tid & 63, lr = lane & 15, lg = lane >> 4;
    int col0 = w * 32 + lr, col1 = col0 + 16;
    int j = tid & 127, half = tid >> 7;
    {
        bf16x8 ahi[4], alo[4];
#pragma unroll
        for (int k = 0; k < 4; k++) mk_split(&T[lr][k * 32 + lg * 8], ahi[k], alo[k]);
        const unsigned short* wh0 = Whi + (size_t)col0 * 128 + lg * 8;
        const unsigned short* wl0 = Wlo + (size_t)col0 * 128 + lg * 8;
        const unsigned short* wh1 = Whi + (size_t)col1 * 128 + lg * 8;
        const unsigned short* wl1 = Wlo + (size_t)col1 * 128 + lg * 8;
        f32x4 a0 = {0.f, 0.f, 0.f, 0.f}, a1 = {0.f, 0.f, 0.f, 0.f};
#pragma unroll
        for (int k = 0; k < 4; k++) {
            bf16x8 bh = *(const bf16x8*)(wh0 + k * 32), bl = *(const bf16x8*)(wl0 + k * 32);
            a0 = MFMA(ahi[k], bh, a0, 0, 0, 0);
            a0 = MFMA(alo[k], bh, a0, 0, 0, 0);
            a0 = MFMA(ahi[k], bl, a0, 0, 0, 0);
            bh = *(const bf16x8*)(wh1 + k * 32); bl = *(const bf16x8*)(wl1 + k * 32);
            a1 = MFMA(ahi[k], bh, a1, 0, 0, 0);
            a1 = MFMA(alo[k], bh, a1, 0, 0, 0);
            a1 = MFMA(ahi[k], bl, a1, 0, 0, 0);
        }
#pragma unroll
        for (int i = 0; i < 4; i++) {
            int r = lg * 4 + i;
            T2[r][col0] = a0[i] + ob[col0];
            T2[r][col1] = a1[i] + ob[col1];
        }
    }
    __syncthreads();
    {
        int gr = tid >> 4, l16 = tid & 15;
        float sm = 0.0f, sq = 0.0f;
#pragma unroll
        for (int i = 0; i < 8; i++) {
            float v = T2[gr][l16 + 16 * i];
            sm += v; sq += v * v;
        }
#pragma unroll
        for (int m = 1; m < 16; m <<= 1) { sm += __shfl_xor(sm, m); sq += __shfl_xor(sq, m); }
        if (l16 == 0) {
            float mean = sm * (1.0f / 128.0f);
            float var = sq * (1.0f / 128.0f) - mean * mean;
            mu16[gr] = mean;
            rs16[gr] = rsqrtf(var + 1e-5f);
        }
    }
    __syncthreads();
    {
        float gj = g[j], bb = bln[j];
#pragma unroll
        for (int r = 0; r < 8; r++) {
            int rr = half * 8 + r;
            float v = fmaxf((T2[rr][j] - mu16[rr]) * rs16[rr] * gj + bb, 0.0f);
            emb[(row0 + rr) * 128 + j] = v;
            T2[rr][j] = v;
        }
    }
    __syncthreads();
    {
        bf16x8 ah[4];
#pragma unroll
        for (int k = 0; k < 4; k++) ah[k] = mk_hi(&T2[lr][k * 32 + lg * 8]);
        const unsigned short* wh0 = Shi + (size_t)col0 * 128 + lg * 8;
        const unsigned short* wh1 = Shi + (size_t)col1 * 128 + lg * 8;
        f32x4 a0 = {0.f, 0.f, 0.f, 0.f}, a1 = {0.f, 0.f, 0.f, 0.f};
#pragma unroll
        for (int k = 0; k < 4; k++) {
            a0 = MFMA(ah[k], *(const bf16x8*)(wh0 + k * 32), a0, 0, 0, 0);
            a1 = MFMA(ah[k], *(const bf16x8*)(wh1 + k * 32), a1, 0, 0, 0);
        }
        float b0 = sb1[col0], b1v = sb1[col1], w20 = sW2[col0], w21 = sW2[col1];
#pragma unroll
        for (int i = 0; i < 4; i++) {
            int r = lg * 4 + i;
            float v = tanhf_fast(a0[i] + b0) * w20 + tanhf_fast(a1[i] + b1v) * w21;
            v += __shfl_xor(v, 1);
            v += __shfl_xor(v, 2);
            v += __shfl_xor(v, 4);
            v += __shfl_xor(v, 8);
            if (lr == 0) part[w][r] = v;
        }
    }
    __syncthreads();
    if (tid < 16)
        scores[(row0 + tid) * 2 + t] = part[0][tid] + part[1][tid] + part[2][tid] + part[3][tid] + sb2[0];
}

// ---------------- TAIL-B1: fused2 = relu(LN((w0*emb0+w1*emb1)@eoW + eob)) ----------------
__global__ __launch_bounds__(256) void k_tailB1(const float* __restrict__ emb0,
                                                const float* __restrict__ emb1,
                                                const float* __restrict__ scores,
                                                const unsigned short* __restrict__ Fhi,
                                                const unsigned short* __restrict__ Flo,
                                                const float* __restrict__ eob,
                                                const float* __restrict__ elg,
                                                const float* __restrict__ elb,
                                                float* __restrict__ fused2) {
    __shared__ __align__(16) float T[16][132];
    __shared__ __align__(16) float T2[16][132];
    __shared__ float mu16[16], rs16[16], w0s[16], w1s[16];
    int tid = threadIdx.x;
    long row0 = (long)blockIdx.x * 16;
    if (tid < 16) {
        long r = row0 + tid;
        float s0 = scores[r * 2], s1 = scores[r * 2 + 1];
        float mx = fmaxf(s0, s1);
        float e0 = __expf(s0 - mx), e1 = __expf(s1 - mx);
        float inv = 1.0f / (e0 + e1);
        w0s[tid] = e0 * inv;
        w1s[tid] = e1 * inv;
    }
    __syncthreads();
#pragma unroll
    for (int i = 0; i < 8; i++) {
        int idx = tid + i * 256;
        int r = idx >> 7, c = idx & 127;
        T[r][c] = w0s[r] * emb0[(row0 + r) * 128 + c] + w1s[r] * emb1[(row0 + r) * 128 + c];
    }
    __syncthreads();
    int w = tid >> 6, lane = tid & 63, lr = lane & 15, lg = lane >> 4;
    int col0 = w * 32 + lr, col1 = col0 + 16;
    int j = tid & 127, half = tid >> 7;
    {
        bf16x8 ahi[4], alo[4];
#pragma unroll
        for (int k = 0; k < 4; k++) mk_split(&T[lr][k * 32 + lg * 8], ahi[k], alo[k]);
        const unsigned short* wh0 = Fhi + (size_t)col0 * 128 + lg * 8;
        const unsigned short* wl0 = Flo + (size_t)col0 * 128 + lg * 8;
        const unsigned short* wh1 = Fhi + (size_t)col1 * 128 + lg * 8;
        const unsigned short* wl1 = Flo + (size_t)col1 * 128 + lg * 8;
        f32x4 a0 = {0.f, 0.f, 0.f, 0.f}, a1 = {0.f, 0.f, 0.f, 0.f};
#pragma unroll
        for (int k = 0; k < 4; k++) {
            bf16x8 bh = *(const bf16x8*)(wh0 + k * 32), bl = *(const bf16x8*)(wl0 + k * 32);
            a0 = MFMA(ahi[k], bh, a0, 0, 0, 0);
            a0 = MFMA(alo[k], bh, a0, 0, 0, 0);
            a0 = MFMA(ahi[k], bl, a0, 0, 0, 0);
            bh = *(const bf16x8*)(wh1 + k * 32); bl = *(const bf16x8*)(wl1 + k * 32);
            a1 = MFMA(ahi[k], bh, a1, 0, 0, 0);
            a1 = MFMA(alo[k], bh, a1, 0, 0, 0);
            a1 = MFMA(ahi[k], bl, a1, 0, 0, 0);
        }
#pragma unroll
        for (int i = 0; i < 4; i++) {
            int r = lg * 4 + i;
            T2[r][col0] = a0[i] + eob[col0];
            T2[r][col1] = a1[i] + eob[col1];
        }
    }
    __syncthreads();
    {
        int gr = tid >> 4, l16 = tid & 15;
        float sm = 0.0f, sq = 0.0f;
#pragma unroll
        for (int i = 0; i < 8; i++) {
            float v = T2[gr][l16 + 16 * i];
            sm += v; sq += v * v;
        }
#pragma unroll
        for (int m = 1; m < 16; m <<= 1) { sm += __shfl_xor(sm, m); sq += __shfl_xor(sq, m); }
        if (l16 == 0) {
            float mean = sm * (1.0f / 128.0f);
            float var = sq * (1.0f / 128.0f) - mean * mean;
            mu16[gr] = mean;
            rs16[gr] = rsqrtf(var + 1e-5f);
        }
    }
    __syncthreads();
    {
        float gj = elg[j], bb = elb[j];
#pragma unroll
        for (int r = 0; r < 8; r++) {
            int rr = half * 8 + r;
            float v = fmaxf((T2[rr][j] - mu16[rr]) * rs16[rr] * gj + bb, 0.0f);
            fused2[(row0 + rr) * 128 + j] = v;
        }
    }
}

// ---------------- FSUM: fsum[l] = sum_{lev=l} fused2 ----------------
__global__ __launch_bounds__(256) void k_fsum(const float* __restrict__ fused2,
                                              const int* __restrict__ lev,
                                              float* __restrict__ fsumg) {
    __shared__ float ls[2][4][128];
    int tid = threadIdx.x, half = tid >> 7, j = tid & 127;
#pragma unroll
    for (int l = 0; l < 4; l++) ls[half][l][j] = 0.0f;
    __syncthreads();
    for (long row = (long)blockIdx.x * 2 + half; row < NN; row += (long)gridDim.x * 2) {
        int l = lev[row];
        ls[half][l][j] += fused2[row * 128 + j];
    }
    __syncthreads();
    if (half == 0) {
#pragma unroll
        for (int l = 0; l < 4; l++) atomicAdd(&fsumg[l * 128 + j], ls[0][l][j] + ls[1][l][j]);
    }
}

// ---------------- FIN2: lmean[l] = (fsum[l]@hpW[l]+cnt*hpb[l])/cnt; lmw[l]=lmean[l]@W1b+hb1 --
__global__ void k_fin2(const float* __restrict__ fsum, const int* __restrict__ cnt4,
                       const float* __restrict__ hpW, const float* __restrict__ hpb,
                       const float* __restrict__ W1b, const float* __restrict__ b1,
                       float* __restrict__ lmean, float* __restrict__ lmw) {
    __shared__ float fs[128];
    __shared__ float lml[128];
    int l = blockIdx.x, j = threadIdx.x;
    fs[j] = fsum[l * 128 + j];
    __syncthreads();
    float c = (float)cnt4[l];
    float a = c * hpb[l * 128 + j];
    const float* wp = hpW + (size_t)l * 16384;
    for (int k = 0; k < 128; k++) a = fmaf(fs[k], wp[k * 128 + j], a);
    float cm = c < 1.0f ? 1.0f : c;
    float v = a / cm;
    lmean[l * 128 + j] = v;
    lml[j] = v;
    __syncthreads();
    float b = b1[j];
    for (int k = 0; k < 128; k++) b = fmaf(lml[k], W1b[k * 128 + j], b);
    lmw[l * 128 + j] = b;
}

// ---------------- TAIL-CD2 (level-bucketed): QW[l] GEMM + hier attn + final GEMM + LN -> out --
__global__ __launch_bounds__(256) void k_tailCD2(const float* __restrict__ fused2,
                                                 const int* __restrict__ perm,
                                                 const int* __restrict__ cnt4,
                                                 const int* __restrict__ off4,
                                                 const int* __restrict__ boff5,
                                                 const unsigned short* __restrict__ QWhi,
                                                 const unsigned short* __restrict__ QWlo,
                                                 const float* __restrict__ qb,
                                                 const float* __restrict__ lmw,
                                                 const float* __restrict__ lmean,
                                                 const float* __restrict__ hW2,
                                                 const unsigned short* __restrict__ Ohi,
                                                 const unsigned short* __restrict__ Olo,
                                                 const float* __restrict__ hob,
                                                 const float* __restrict__ hlg,
                                                 const float* __restrict__ hlb,
                                                 float* __restrict__ out) {
    __shared__ __align__(16) float T[16][132];
    __shared__ __align__(16) float T2[16][132];
    __shared__ float lm[4][128];
    __shared__ float lmwS[4][128];
    __shared__ float w2S[128];
    __shared__ float scS[16][4];
    __shared__ float aw[16][4];
    __shared__ float mu16[16], rs16[16];
    __shared__ int idx16[16];
    int tid = threadIdx.x;
    int b = blockIdx.x;
    if (b >= boff5[4]) return;
    int l = (b >= boff5[3]) ? 3 : (b >= boff5[2]) ? 2 : (b >= boff5[1]) ? 1 : 0;
    int bi = b - boff5[l];
    int base = off4[l] + bi * 16;
    int last = off4[l] + cnt4[l] - 1;
    if (tid < 16) {
        int gp = base + tid;
        if (gp > last) gp = last;
        idx16[tid] = perm[gp];
    }
    for (int idx = tid; idx < 512; idx += 256) {
        lm[idx >> 7][idx & 127] = lmean[idx];
        lmwS[idx >> 7][idx & 127] = lmw[idx];
    }
    if (tid < 128) w2S[tid] = hW2[tid];
    __syncthreads();
#pragma unroll
    for (int i = 0; i < 8; i++) {
        int idx = tid + i * 256;
        int r = idx >> 7, c = idx & 127;
        T[r][c] = fused2[(size_t)idx16[r] * 128 + c];
    }
    __syncthreads();
    int w = tid >> 6, lane = tid & 63, lr = lane & 15, lg = lane >> 4;
    int col0 = w * 32 + lr, col1 = col0 + 16;
    int j = tid & 127, half = tid >> 7;
    // hfa = fused2 @ QW[l] + qb[l]
    {
        bf16x8 ahi[4], alo[4];
#pragma unroll
        for (int k = 0; k < 4; k++) mk_split(&T[lr][k * 32 + lg * 8], ahi[k], alo[k]);
        const unsigned short* wh0 = QWhi + (size_t)l * 16384 + (size_t)col0 * 128 + lg * 8;
        const unsigned short* wl0 = QWlo + (size_t)l * 16384 + (size_t)col0 * 128 + lg * 8;
        const unsigned short* wh1 = QWhi + (size_t)l * 16384 + (size_t)col1 * 128 + lg * 8;
        const unsigned short* wl1 = QWlo + (size_t)l * 16384 + (size_t)col1 * 128 + lg * 8;
        f32x4 a0 = {0.f, 0.f, 0.f, 0.f}, a1 = {0.f, 0.f, 0.f, 0.f};
#pragma unroll
        for (int k = 0; k < 4; k++) {
            bf16x8 bh = *(const bf16x8*)(wh0 + k * 32), bl = *(const bf16x8*)(wl0 + k * 32);
            a0 = MFMA(ahi[k], bh, a0, 0, 0, 0);
            a0 = MFMA(alo[k], bh, a0, 0, 0, 0);
            a0 = MFMA(ahi[k], bl, a0, 0, 0, 0);
            bh = *(const bf16x8*)(wh1 + k * 32); bl = *(const bf16x8*)(wl1 + k * 32);
            a1 = MFMA(ahi[k], bh, a1, 0, 0, 0);
            a1 = MFMA(alo[k], bh, a1, 0, 0, 0);
            a1 = MFMA(ahi[k], bl, a1, 0, 0, 0);
        }
#pragma unroll
        for (int i = 0; i < 4; i++) {
            int r = lg * 4 + i;
            T2[r][col0] = a0[i] + qb[l * 128 + col0];
            T2[r][col1] = a1[i] + qb[l * 128 + col1];
        }
    }
    __syncthreads();
    // hier scores: 4 threads per (row, level') pair, stride-4 cols
    {
        int p = tid >> 2, sub = tid & 3;
        int pr = p & 15, pl = p >> 4;
        float s = 0.0f;
#pragma unroll
        for (int jj = 0; jj < 32; jj++) {
            int j2 = sub + 4 * jj;
            s += tanhf_fast(T2[pr][j2] + lmwS[pl][j2]) * w2S[j2];
        }
        s += __shfl_xor(s, 1);
        s += __shfl_xor(s, 2);
        if (sub == 0) scS[pr][pl] = s;
    }
    __syncthreads();
    if (tid < 16) {
        float sc[4];
        float mx = -1e30f;
#pragma unroll
        for (int ll = 0; ll < 4; ll++) {
            sc[ll] = scS[tid][ll];
            mx = fmaxf(mx, sc[ll]);
        }
        float s = 0.0f;
#pragma unroll
        for (int ll = 0; ll < 4; ll++) { sc[ll] = __expf(sc[ll] - mx); s += sc[ll]; }
        float inv = 1.0f / s;
#pragma unroll
        for (int ll = 0; ll < 4; ll++) aw[tid][ll] = sc[ll] * inv;
    }
    __syncthreads();
    // enhanced = aw @ lmean
#pragma unroll
    for (int r = 0; r < 8; r++) {
        int rr = half * 8 + r;
        float e = 0.0f;
#pragma unroll
        for (int ll = 0; ll < 4; ll++) e = fmaf(aw[rr][ll], lm[ll][j], e);
        T[rr][j] = e;
    }
    __syncthreads();
    // out = relu(LN(enh @ hoW + hob))
    {
        bf16x8 ahi[4], alo[4];
#pragma unroll
        for (int k = 0; k < 4; k++) mk_split(&T[lr][k * 32 + lg * 8], ahi[k], alo[k]);
        const unsigned short* wh0 = Ohi + (size_t)col0 * 128 + lg * 8;
        const unsigned short* wl0 = Olo + (size_t)col0 * 128 + lg * 8;
        const unsigned short* wh1 = Ohi + (size_t)col1 * 128 + lg * 8;
        const unsigned short* wl1 = Olo + (size_t)col1 * 128 + lg * 8;
        f32x4 a0 = {0.f, 0.f, 0.f, 0.f}, a1 = {0.f, 0.f, 0.f, 0.f};
#pragma unroll
        for (int k = 0; k < 4; k++) {
            bf16x8 bh = *(const bf16x8*)(wh0 + k * 32), bl = *(const bf16x8*)(wl0 + k * 32);
            a0 = MFMA(ahi[k], bh, a0, 0, 0, 0);
            a0 = MFMA(alo[k], bh, a0, 0, 0, 0);
            a0 = MFMA(ahi[k], bl, a0, 0, 0, 0);
            bh = *(const bf16x8*)(wh1 + k * 32); bl = *(const bf16x8*)(wl1 + k * 32);
            a1 = MFMA(ahi[k], bh, a1, 0, 0, 0);
            a1 = MFMA(alo[k], bh, a1, 0, 0, 0);
            a1 = MFMA(ahi[k], bl, a1, 0, 0, 0);
        }
#pragma unroll
        for (int i = 0; i < 4; i++) {
            int r = lg * 4 + i;
            T2[r][col0] = a0[i] + hob[col0];
            T2[r][col1] = a1[i] + hob[col1];
        }
    }
    __syncthreads();
    {
        int gr = tid >> 4, l16 = tid & 15;
        float sm = 0.0f, sq = 0.0f;
#pragma unroll
        for (int i = 0; i < 8; i++) {
            float v = T2[gr][l16 + 16 * i];
            sm += v; sq += v * v;
        }
#pragma unroll
        for (int m = 1; m < 16; m <<= 1) { sm += __shfl_xor(sm, m); sq += __shfl_xor(sq, m); }
        if (l16 == 0) {
            float mean = sm * (1.0f / 128.0f);
            float var = sq * (1.0f / 128.0f) - mean * mean;
            mu16[gr] = mean;
            rs16[gr] = rsqrtf(var + 1e-5f);
        }
    }
    __syncthreads();
    {
        float gj = hlg[j], bb = hlb[j];
#pragma unroll
        for (int r = 0; r < 8; r++) {
            int rr = half * 8 + r;
            float v = (T2[rr][j] - mu16[rr]) * rs16[rr] * gj + bb;
            out[(size_t)idx16[rr] * 128 + j] = fmaxf(v, 0.0f);
        }
    }
}

extern "C" void kernel_launch(void* const* d_in, const int* in_sizes, int n_in,
                              void* d_out, int out_size, void* d_ws, size_t ws_size,
                              hipStream_t stream) {
    const float* nf  = (const float*)d_in[0];
    const float* ef  = (const float*)d_in[1];
    const int*   lev = (const int*)d_in[2];
    const int*   ei  = (const int*)d_in[3];
    const float* nlW = (const float*)d_in[4];
    const float* nlb = (const float*)d_in[5];
    const float* neW = (const float*)d_in[6];
    const float* neb = (const float*)d_in[7];
    const float* aW1 = (const float*)d_in[8];
    const float* ab1 = (const float*)d_in[9];
    const float* aW2 = (const float*)d_in[10];
    const float* ab2 = (const float*)d_in[11];
    const float* oW  = (const float*)d_in[12];
    const float* ob  = (const float*)d_in[13];
    const float* lng = (const float*)d_in[14];
    const float* lnb = (const float*)d_in[15];
    const float* eW1 = (const float*)d_in[16];
    const float* eb1 = (const float*)d_in[17];
    const float* eW2 = (const float*)d_in[18];
    const float* eb2 = (const float*)d_in[19];
    const float* eoW = (const float*)d_in[20];
    const float* eob = (const float*)d_in[21];
    const float* elg = (const float*)d_in[22];
    const float* elb = (const float*)d_in[23];
    const float* hpW = (const float*)d_in[24];
    const float* hpb = (const float*)d_in[25];
    const float* hW1 = (const float*)d_in[26];
    const float* hb1 = (const float*)d_in[27];
    const float* hW2 = (const float*)d_in[28];
    const float* hb2 = (const float*)d_in[29];
    const float* hoW = (const float*)d_in[30];
    const float* hob = (const float*)d_in[31];
    const float* hlg = (const float*)d_in[32];
    const float* hlb = (const float*)d_in[33];

    float* ws = (float*)d_ws;
    size_t NH = (size_t)NN * 128;
    float* fused2 = ws;              // NH (CSR scratch aliases this until tailB1)
    float* emb0   = fused2 + NH;     // NH
    float* emb1   = emb0 + NH;       // NH
    float* ebuf   = emb1 + NH;       // EE (CSR-ordered ev)
    float* scores = ebuf + EE;       // 2*NN
    float* beff   = scores + (size_t)2 * NN;  // 128
    float* fsum   = beff + 128;      // 512
    float* lmean  = fsum + 512;      // 512
    float* lmw    = lmean + 512;     // 512
    float* qb     = lmw + 512;       // 512
    unsigned short* U    = (unsigned short*)(qb + 512);   // NH
    unsigned short* V    = U + NH;                        // NH
    unsigned short* hbf  = V + NH;                        // NH
    unsigned short* WhT  = hbf + NH;                      // 16384
    unsigned short* WUT  = WhT + 16384;
    unsigned short* WVT  = WUT + 16384;
    unsigned short* WET  = WVT + 16384;                   // 8192
    unsigned short* twhi = WET + 8192;                    // 6*16384
    unsigned short* twlo = twhi + 6 * 16384;              // 6*16384
    unsigned short* QWhi = twlo + 6 * 16384;              // 4*16384
    unsigned short* QWlo = QWhi + 4 * 16384;              // 4*16384
    int* perm  = (int*)(QWlo + 4 * 16384);                // NN
    int* cnt4  = perm + NN;                               // 4
    int* off4  = cnt4 + 4;                                // 4
    int* boff5 = off4 + 4;                                // 5
    int* cursorL = boff5 + 5;                             // 4
    // CSR scratch aliases fused2 (dead until k_tailB1)
    int* epos   = (int*)fused2;          // EE
    int* cdst   = epos + EE;             // EE
    int* deg    = cdst + EE;             // NN
    int* rowptr = deg + NN;              // NN+1
    int* cursor = rowptr + NN + 1;       // NN
    int* stmp   = cursor + NN;           // NN
    int* sbsum  = stmp + NN;             // 256
    int* sboff  = sbsum + 256;           // 256
    float* out = (float*)d_out;

    WSrc ps;
    ps.s[0] = oW;               // oW t0
    ps.s[1] = oW + 16384;       // oW t1
    ps.s[2] = eW1;              // eW1 t0
    ps.s[3] = eW1 + 16384;      // eW1 t1
    ps.s[4] = eoW;
    ps.s[5] = hoW;

    // level bucketing (independent of the main pipeline)
    k_zeroi<<<1, 4, 0, stream>>>(cnt4, 4);
    k_count<<<128, 256, 0, stream>>>(lev, cnt4);
    k_scan<<<1, 1, 0, stream>>>(cnt4, off4, boff5, cursorL);
    k_scatter<<<125, 256, 0, stream>>>(lev, cursorL, perm);

    k_prep_tail<<<6 * 64, 256, 0, stream>>>(ps, twhi, twlo);
    k_prep_q<<<258, 256, 0, stream>>>(hpW, hpb, hW1, QWhi, QWlo, qb);
    k_zero<<<1, 512, 0, stream>>>(fsum, (size_t)512);

    for (int t = 0; t < 2; t++) {
        const int* eis = ei + (size_t)t * 2 * EE;
        const int* eid = eis + EE;
        // CSR build for this relation
        k_zeroi<<<(NN + 255) / 256, 256, 0, stream>>>(deg, NN);
        k_hist<<<(EE + 255) / 256, 256, 0, stream>>>(eis, deg);
        k_scan1<<<196, 512, 0, stream>>>(deg, stmp, sbsum);
        k_scan2<<<1, 256, 0, stream>>>(sbsum, sboff);
        k_scan3<<<196, 512, 0, stream>>>(deg, stmp, sboff, rowptr, cursor);
        k_csr_scatter<<<(EE + 255) / 256, 256, 0, stream>>>(eis, eid, cursor, epos, cdst);

        k_prep_head<<<128, 128, 0, stream>>>(nlW + (size_t)t * 16384, nlb + t * 128,
                                             aW1 + (size_t)t * 384 * 128, ab1 + t * 128,
                                             neW + (size_t)t * 64 * 128, neb + t * 128,
                                             WhT, WUT, WVT, WET, beff);
        k_head<<<NN / 16, 256, 0, stream>>>(nf, WhT, WUT, WVT, nlb + t * 128, hbf, U, V);
        k_edge2<<<(EE + 63) / 64, 256, 0, stream>>>(ef + (size_t)t * EE * 64, eis, eid, epos,
                                                    WET, U, V, beff, aW2 + t * 128,
                                                    ab2 + t, ebuf);
        float* embt = (t == 0) ? emb0 : emb1;
        k_tailA2<<<NN / 16, 256, 0, stream>>>(rowptr, cdst, ebuf, hbf,
                                              twhi + (size_t)t * 16384, twlo + (size_t)t * 16384,
                                              ob + t * 128, lng + t * 128, lnb + t * 128,
                                              twhi + (size_t)(2 + t) * 16384,
                                              eb1 + t * 128, eW2 + t * 128, eb2 + t,
                                              embt, scores, t);
    }
    k_tailB1<<<NN / 16, 256, 0, stream>>>(emb0, emb1, scores,
                                          twhi + (size_t)4 * 16384, twlo + (size_t)4 * 16384,
                                          eob, elg, elb, fused2);
    k_fsum<<<256, 256, 0, stream>>>(fused2, lev, fsum);
    k_fin2<<<4, 128, 0, stream>>>(fsum, cnt4, hpW, hpb, hW1 + 16384, hb1, lmean, lmw);
    k_tailCD2<<<NN / 16 + 4, 256, 0, stream>>>(fused2, perm, cnt4, off4, boff5,
                                               QWhi, QWlo, qb, lmw, lmean, hW2,
                                               twhi + (size_t)5 * 16384, twlo + (size_t)5 * 16384,
                                               hob, hlg, hlb, out);
}

// Round 8
// 1040.723 us; speedup vs baseline: 1.5937x; 1.0422x over previous
//
#include <hip/hip_runtime.h>
#include <math.h>

#define NN 100000
#define EE 500000
// D=H=128, ED=64, T=2, L=4

typedef __attribute__((ext_vector_type(8))) short bf16x8;
typedef __attribute__((ext_vector_type(4))) float f32x4;
#define MFMA __builtin_amdgcn_mfma_f32_16x16x32_bf16

__device__ inline short f2bf(float x) {
    union { float f; unsigned u; } v; v.f = x;
    unsigned r = v.u + 0x7FFF + ((v.u >> 16) & 1);
    return (short)(r >> 16);
}
__device__ inline float bf2f(unsigned short h) {
    union { unsigned u; float f; } v; v.u = ((unsigned)h) << 16; return v.f;
}
__device__ inline float tanhf_fast(float x) {
    float e = __expf(2.0f * x);
    return 1.0f - 2.0f * __builtin_amdgcn_rcpf(e + 1.0f);
}

__device__ inline bf16x8 mk_hi(const float* p) {
    float4 a = *(const float4*)p, b = *(const float4*)(p + 4);
    float v[8] = {a.x, a.y, a.z, a.w, b.x, b.y, b.z, b.w};
    bf16x8 h;
#pragma unroll
    for (int i = 0; i < 8; i++) h[i] = f2bf(v[i]);
    return h;
}
__device__ inline void mk_split(const float* p, bf16x8& hi, bf16x8& lo) {
    float4 a = *(const float4*)p, b = *(const float4*)(p + 4);
    float v[8] = {a.x, a.y, a.z, a.w, b.x, b.y, b.z, b.w};
#pragma unroll
    for (int i = 0; i < 8; i++) {
        short h = f2bf(v[i]);
        hi[i] = h;
        lo[i] = f2bf(v[i] - bf2f((unsigned short)h));
    }
}

// ---------------- zero fill ----------------
__global__ void k_zero(float* __restrict__ p, size_t n) {
    size_t i = (size_t)blockIdx.x * blockDim.x + threadIdx.x;
    size_t stride = (size_t)gridDim.x * blockDim.x;
    for (; i < n; i += stride) p[i] = 0.0f;
}
__global__ void k_zeroi(int* __restrict__ p, int n) {
    int i = blockIdx.x * blockDim.x + threadIdx.x;
    if (i < n) p[i] = 0;
}

// ---------------- CSR build (by source) ----------------
__global__ __launch_bounds__(256) void k_hist(const int* __restrict__ eis, int* __restrict__ deg) {
    int e = blockIdx.x * 256 + threadIdx.x;
    if (e < EE) atomicAdd(&deg[eis[e]], 1);
}
__global__ __launch_bounds__(512) void k_scan1(const int* __restrict__ deg,
                                               int* __restrict__ tmp, int* __restrict__ bsum) {
    __shared__ int sh[2][512];
    int b = blockIdx.x, tid = threadIdx.x;
    int i = b * 512 + tid;
    int v = (i < NN) ? deg[i] : 0;
    int cur = 0;
    sh[0][tid] = v;
    __syncthreads();
    for (int off = 1; off < 512; off <<= 1) {
        int nxt = cur ^ 1;
        int a = sh[cur][tid];
        if (tid >= off) a += sh[cur][tid - off];
        sh[nxt][tid] = a;
        __syncthreads();
        cur = nxt;
    }
    int incl = sh[cur][tid];
    if (i < NN) tmp[i] = incl;
    if (tid == 511) bsum[b] = incl;
}
__global__ void k_scan2(const int* __restrict__ bsum, int* __restrict__ boff) {
    __shared__ int sh[2][256];
    int tid = threadIdx.x;
    int v = (tid < 196) ? bsum[tid] : 0;
    int cur = 0;
    sh[0][tid] = v;
    __syncthreads();
    for (int off = 1; off < 256; off <<= 1) {
        int nxt = cur ^ 1;
        int a = sh[cur][tid];
        if (tid >= off) a += sh[cur][tid - off];
        sh[nxt][tid] = a;
        __syncthreads();
        cur = nxt;
    }
    boff[tid] = sh[cur][tid] - v;
}
__global__ __launch_bounds__(512) void k_scan3(const int* __restrict__ deg,
                                               const int* __restrict__ tmp,
                                               const int* __restrict__ boff,
                                               int* __restrict__ rowptr, int* __restrict__ cursor) {
    int i = blockIdx.x * 512 + threadIdx.x;
    if (i < NN) {
        int r = tmp[i] - deg[i] + boff[blockIdx.x];
        rowptr[i] = r;
        cursor[i] = r;
    }
    if (i == 0) rowptr[NN] = EE;
}
__global__ __launch_bounds__(256) void k_csr_scatter(const int* __restrict__ eis,
                                                     const int* __restrict__ eid,
                                                     int* __restrict__ cursor,
                                                     int* __restrict__ epos,
                                                     int* __restrict__ cdst) {
    int e = blockIdx.x * 256 + threadIdx.x;
    if (e < EE) {
        int s = eis[e];
        int p = atomicAdd(&cursor[s], 1);
        epos[e] = p;
        cdst[p] = eid[e];
    }
}

// ---------------- level bucketing ----------------
__global__ __launch_bounds__(256) void k_count(const int* __restrict__ lev, int* __restrict__ cnt4) {
    __shared__ int lc[4];
    int tid = threadIdx.x;
    if (tid < 4) lc[tid] = 0;
    __syncthreads();
    for (long n = (long)blockIdx.x * 256 + tid; n < NN; n += (long)gridDim.x * 256)
        atomicAdd(&lc[lev[n]], 1);
    __syncthreads();
    if (tid < 4 && lc[tid]) atomicAdd(&cnt4[tid], lc[tid]);
}

__global__ void k_scan(const int* __restrict__ cnt4, int* __restrict__ off4,
                       int* __restrict__ boff5, int* __restrict__ cursor) {
    int o = 0, b = 0;
    for (int l = 0; l < 4; l++) {
        off4[l] = o; cursor[l] = o; boff5[l] = b;
        o += cnt4[l];
        b += (cnt4[l] + 15) >> 4;
    }
    boff5[4] = b;
}

__global__ __launch_bounds__(256) void k_scatter(const int* __restrict__ lev,
                                                 int* __restrict__ cursor,
                                                 int* __restrict__ perm) {
    __shared__ int lc[4], lb[4], lc2[4];
    int tid = threadIdx.x;
    if (tid < 4) { lc[tid] = 0; lc2[tid] = 0; }
    __syncthreads();
    int start = blockIdx.x * 800, end = start + 800;
    if (end > NN) end = NN;
    for (int n = start + tid; n < end; n += 256) atomicAdd(&lc[lev[n]], 1);
    __syncthreads();
    if (tid < 4 && lc[tid]) lb[tid] = atomicAdd(&cursor[tid], lc[tid]);
    __syncthreads();
    for (int n = start + tid; n < end; n += 256) {
        int l = lev[n];
        int p = atomicAdd(&lc2[l], 1);
        perm[lb[l] + p] = n;
    }
}

// ---------------- prep head: WhT, WUT, WVT, WET (bf16 transposed), beff ----------------
__global__ void k_prep_head(const float* __restrict__ Wn, const float* __restrict__ bn,
                            const float* __restrict__ W1, const float* __restrict__ b1,
                            const float* __restrict__ We, const float* __restrict__ be,
                            unsigned short* __restrict__ WhT, unsigned short* __restrict__ WUT,
                            unsigned short* __restrict__ WVT, unsigned short* __restrict__ WET,
                            float* __restrict__ beff) {
    __shared__ float red[2];
    int j = blockIdx.x, k = threadIdx.x;  // 128 blocks x 128 threads
    WhT[j * 128 + k] = (unsigned short)f2bf(Wn[k * 128 + j]);
    float su = 0.0f, sv = 0.0f;
    for (int m = 0; m < 128; m++) {
        float wkm = Wn[k * 128 + m];
        su = fmaf(wkm, W1[m * 128 + j], su);
        sv = fmaf(wkm, W1[(128 + m) * 128 + j], sv);
    }
    WUT[j * 128 + k] = (unsigned short)f2bf(su);
    WVT[j * 128 + k] = (unsigned short)f2bf(sv);
    if (k < 64) {
        float se = 0.0f;
        for (int m = 0; m < 128; m++) se = fmaf(We[k * 128 + m], W1[(256 + m) * 128 + j], se);
        WET[j * 64 + k] = (unsigned short)f2bf(se);
    }
    float tk = bn[k] * (W1[k * 128 + j] + W1[(128 + k) * 128 + j]) + be[k] * W1[(256 + k) * 128 + j];
#pragma unroll
    for (int o = 32; o > 0; o >>= 1) tk += __shfl_down(tk, o);
    if ((k & 63) == 0) red[k >> 6] = tk;
    __syncthreads();
    if (k == 0) beff[j] = b1[j] + red[0] + red[1];
}

// ---------------- prep tail: split-bf16 transposed weights (6 mats) ----------------
struct WSrc { const float* s[6]; };
__global__ void k_prep_tail(WSrc ps, unsigned short* __restrict__ hi,
                            unsigned short* __restrict__ lo) {
    int m = blockIdx.x >> 6, blk = blockIdx.x & 63;
    const float* src = ps.s[m];
    unsigned short* h = hi + (size_t)m * 16384;
    unsigned short* l = lo + (size_t)m * 16384;
    int idx = blk * 256 + threadIdx.x;  // 0..16383
    int k = idx >> 7, j = idx & 127;
    float v = src[idx];
    short hh = f2bf(v);
    h[j * 128 + k] = (unsigned short)hh;
    l[j * 128 + k] = (unsigned short)f2bf(v - bf2f((unsigned short)hh));
}

// ---------------- prep Q: QW[l] = hpW[l] @ hW1a (transposed split bf16), qb[l] = hpb[l]@hW1a --
__global__ void k_prep_q(const float* __restrict__ hpW, const float* __restrict__ hpb,
                         const float* __restrict__ hW1a,
                         unsigned short* __restrict__ QWhi, unsigned short* __restrict__ QWlo,
                         float* __restrict__ qb) {
    int gidx = blockIdx.x * 256 + threadIdx.x;
    if (gidx < 4 * 16384) {
        int l = gidx >> 14, rem = gidx & 16383;
        int k = rem >> 7, j = rem & 127;
        const float* wr = hpW + (size_t)l * 16384 + (size_t)k * 128;
        float v = 0.0f;
        for (int m = 0; m < 128; m++) v = fmaf(wr[m], hW1a[m * 128 + j], v);
        short hh = f2bf(v);
        QWhi[(size_t)l * 16384 + j * 128 + k] = (unsigned short)hh;
        QWlo[(size_t)l * 16384 + j * 128 + k] = (unsigned short)f2bf(v - bf2f((unsigned short)hh));
    } else {
        int e = gidx - 4 * 16384;
        if (e < 512) {
            int l = e >> 7, j = e & 127;
            float v = 0.0f;
            for (int m = 0; m < 128; m++) v = fmaf(hpb[l * 128 + m], hW1a[m * 128 + j], v);
            qb[l * 128 + j] = v;
        }
    }
}

// ---------------- HEAD: hbf = bf16(nf@Wn+bn), U = bf16(nf@WU), V = bf16(nf@WV) ----------------
__global__ __launch_bounds__(256) void k_head(const float* __restrict__ nf,
                                              const unsigned short* __restrict__ WhT,
                                              const unsigned short* __restrict__ WUT,
                                              const unsigned short* __restrict__ WVT,
                                              const float* __restrict__ bn,
                                              unsigned short* __restrict__ hbf,
                                              unsigned short* __restrict__ U,
                                              unsigned short* __restrict__ V) {
    __shared__ __align__(16) float T[16][132];
    int tid = threadIdx.x;
    long row0 = (long)blockIdx.x * 16;
#pragma unroll
    for (int i = 0; i < 8; i++) {
        int idx = tid + i * 256;
        int r = idx >> 7, c = idx & 127;
        T[r][c] = nf[(row0 + r) * 128 + c];
    }
    __syncthreads();
    int w = tid >> 6, lane = tid & 63, lr = lane & 15, lg = lane >> 4;
    bf16x8 A[4];
#pragma unroll
    for (int k = 0; k < 4; k++) A[k] = mk_hi(&T[lr][k * 32 + lg * 8]);
    int col0 = w * 32 + lr, col1 = col0 + 16;
#pragma unroll
    for (int o = 0; o < 3; o++) {
        const unsigned short* wb = (o == 0) ? WhT : (o == 1) ? WUT : WVT;
        unsigned short* ob = (o == 0) ? hbf : (o == 1) ? U : V;
        const unsigned short* w0 = wb + (size_t)col0 * 128 + lg * 8;
        const unsigned short* w1 = wb + (size_t)col1 * 128 + lg * 8;
        f32x4 a0 = {0.f, 0.f, 0.f, 0.f}, a1 = {0.f, 0.f, 0.f, 0.f};
#pragma unroll
        for (int k = 0; k < 4; k++) {
            a0 = MFMA(A[k], *(const bf16x8*)(w0 + k * 32), a0, 0, 0, 0);
            a1 = MFMA(A[k], *(const bf16x8*)(w1 + k * 32), a1, 0, 0, 0);
        }
        float bb0 = (o == 0) ? bn[col0] : 0.0f;
        float bb1 = (o == 0) ? bn[col1] : 0.0f;
        unsigned short* op = ob + (size_t)row0 * 128;
#pragma unroll
        for (int i = 0; i < 4; i++) {
            int r = lg * 4 + i;
            op[(size_t)r * 128 + col0] = (unsigned short)f2bf(a0[i] + bb0);
            op[(size_t)r * 128 + col1] = (unsigned short)f2bf(a1[i] + bb1);
        }
    }
}

// ---------------- EDGE3: LDS-staged pre=U[s]+V[d]; MFMA ef@WE; tanh dot W2; ev -> CSR slot ----
__global__ __launch_bounds__(256) void k_edge3(const float* __restrict__ ef,
                                               const int* __restrict__ eis,
                                               const int* __restrict__ eid,
                                               const int* __restrict__ epos,
                                               const unsigned short* __restrict__ WET,
                                               const unsigned short* __restrict__ U,
                                               const unsigned short* __restrict__ V,
                                               const float* __restrict__ beff,
                                               const float* __restrict__ W2,
                                               const float* __restrict__ b2p,
                                               float* __restrict__ ebuf) {
    __shared__ __align__(16) float pre[64][132];
    __shared__ float part[4][64];
    int tid = threadIdx.x, w = tid >> 6, lane = tid & 63, lr = lane & 15, lg = lane >> 4;
    long e0 = (long)blockIdx.x * 64;
    long remE = (long)EE - e0;
    int nE = remE < 64 ? (int)remE : 64;
    int n16 = (nE + 15) >> 4;
    // ---- stage pre = U[s] + V[d] (wide loads, coalesced per edge row) ----
    {
        int eL = tid >> 2;       // 0..63
        int c4 = tid & 3;        // 4 chunks of 32 cols
        if (eL < nE) {
            long e = e0 + eL;
            int s = eis[e], d = eid[e];
            const unsigned short* up = U + (size_t)s * 128 + c4 * 32;
            const unsigned short* vp = V + (size_t)d * 128 + c4 * 32;
#pragma unroll
            for (int i = 0; i < 4; i++) {
                bf16x8 uv = *(const bf16x8*)(up + i * 8);
                bf16x8 vv = *(const bf16x8*)(vp + i * 8);
                float4 lo4, hi4;
                lo4.x = bf2f((unsigned short)uv[0]) + bf2f((unsigned short)vv[0]);
                lo4.y = bf2f((unsigned short)uv[1]) + bf2f((unsigned short)vv[1]);
                lo4.z = bf2f((unsigned short)uv[2]) + bf2f((unsigned short)vv[2]);
                lo4.w = bf2f((unsigned short)uv[3]) + bf2f((unsigned short)vv[3]);
                hi4.x = bf2f((unsigned short)uv[4]) + bf2f((unsigned short)vv[4]);
                hi4.y = bf2f((unsigned short)uv[5]) + bf2f((unsigned short)vv[5]);
                hi4.z = bf2f((unsigned short)uv[6]) + bf2f((unsigned short)vv[6]);
                hi4.w = bf2f((unsigned short)uv[7]) + bf2f((unsigned short)vv[7]);
                *(float4*)&pre[eL][c4 * 32 + i * 8] = lo4;
                *(float4*)&pre[eL][c4 * 32 + i * 8 + 4] = hi4;
            }
        }
    }
    int col0 = w * 32 + lr, col1 = col0 + 16;
    bf16x8 B0[2], B1[2];
#pragma unroll
    for (int kk = 0; kk < 2; kk++) {
        B0[kk] = *(const bf16x8*)(WET + (size_t)col0 * 64 + kk * 32 + lg * 8);
        B1[kk] = *(const bf16x8*)(WET + (size_t)col1 * 64 + kk * 32 + lg * 8);
    }
    float be0 = beff[col0], be1 = beff[col1], w20 = W2[col0], w21 = W2[col1];
    __syncthreads();
    for (int i16 = 0; i16 < n16; i16++) {
        long eg0 = e0 + i16 * 16;
        const float* ep = ef + (size_t)(eg0 + lr) * 64;
        f32x4 a0 = {0.f, 0.f, 0.f, 0.f}, a1 = {0.f, 0.f, 0.f, 0.f};
#pragma unroll
        for (int kk = 0; kk < 2; kk++) {
            bf16x8 a = mk_hi(ep + kk * 32 + lg * 8);
            a0 = MFMA(a, B0[kk], a0, 0, 0, 0);
            a1 = MFMA(a, B1[kk], a1, 0, 0, 0);
        }
#pragma unroll
        for (int i = 0; i < 4; i++) {
            int eL = i16 * 16 + lg * 4 + i;
            float v = tanhf_fast(a0[i] + pre[eL][col0] + be0) * w20 +
                      tanhf_fast(a1[i] + pre[eL][col1] + be1) * w21;
            v += __shfl_xor(v, 1);
            v += __shfl_xor(v, 2);
            v += __shfl_xor(v, 4);
            v += __shfl_xor(v, 8);
            if (lr == 0) part[w][eL] = v;
        }
    }
    __syncthreads();
    if (tid < nE) {
        long e = e0 + tid;
        float a = part[0][tid] + part[1][tid] + part[2][tid] + part[3][tid] + b2p[0];
        ebuf[epos[e]] = __expf(a);
    }
}

// ---------------- TAIL-A2: CSR gather-agg (16 thr/row) + oW GEMM + LN + relu + score MLP ----
__global__ __launch_bounds__(256) void k_tailA2(const int* __restrict__ rowptr,
                                                const int* __restrict__ cdst,
                                                const float* __restrict__ ebufC,
                                                const unsigned short* __restrict__ hbf,
                                                const unsigned short* __restrict__ Whi,
                                                const unsigned short* __restrict__ Wlo,
                                                const float* __restrict__ ob,
                                                const float* __restrict__ g,
                                                const float* __restrict__ bln,
                                                const unsigned short* __restrict__ Shi,
                                                const float* __restrict__ sb1,
                                                const float* __restrict__ sW2,
                                                const float* __restrict__ sb2,
                                                float* __restrict__ emb,
                                                float* __restrict__ scores, int t) {
    __shared__ __align__(16) float T[16][132];
    __shared__ __align__(16) float T2[16][132];
    __shared__ float mu16[16], rs16[16], part[4][16];
    int tid = threadIdx.x;
    long row0 = (long)blockIdx.x * 16;
    // CSR gather: 16 threads per row, each owns 8 contiguous cols (16B of hbf row)
    {
        int r16 = tid >> 4, sub = tid & 15;
        long n = row0 + r16;
        int p0 = rowptr[n], p1 = rowptr[n + 1];
        float acc[8] = {0, 0, 0, 0, 0, 0, 0, 0};
        float sev = 0.0f;
        for (int p = p0; p < p1; p++) {
            int d = cdst[p];
            float ev = ebufC[p];
            bf16x8 hv = *(const bf16x8*)(hbf + (size_t)d * 128 + sub * 8);
            sev += ev;
#pragma unroll
            for (int i = 0; i < 8; i++) acc[i] = fmaf(ev, bf2f((unsigned short)hv[i]), acc[i]);
        }
        float inv = 1.0f / (sev + 1e-16f);
#pragma unroll
        for (int i = 0; i < 8; i++) T[r16][sub * 8 + i] = acc[i] * inv;
    }
    __syncthreads();
    int w = tid >> 6, lane = tid & 63, lr = lane & 15, lg = lane >> 4;
    int col0 = w * 32 + lr, col1 = col0 + 16;
    int j = tid & 127, half = tid >> 7;
    {
        bf16x8 ahi[4], alo[4];
#pragma unroll
        for (int k = 0; k < 4; k++) mk_split(&T[lr][k * 32 + lg * 8], ahi[k], alo[k]);
        const unsigned short* wh0 = Whi + (size_t)col0 * 128 + lg * 8;
        const unsigned short* wl0 = Wlo + (size_t)col0 * 128 + lg * 8;
        const unsigned short* wh1 = Whi + (size_t)col1 * 128 + lg * 8;
        const unsigned short* wl1 = Wlo + (size_t)col1 * 128 + lg * 8;
        f32x4 a0 = {0.f, 0.f, 0.f, 0.f}, a1 = {0.f, 0.f, 0.f, 0.f};
#pragma unroll
        for (int k = 0; k < 4; k++) {
            bf16x8 bh = *(const bf16x8*)(wh0 + k * 32), bl = *(const bf16x8*)(wl0 + k * 32);
            a0 = MFMA(ahi[k], bh, a0, 0, 0, 0);
            a0 = MFMA(alo[k], bh, a0, 0, 0, 0);
            a0 = MFMA(ahi[k], bl, a0, 0, 0, 0);
            bh = *(const bf16x8*)(wh1 + k * 32); bl = *(const bf16x8*)(wl1 + k * 32);
            a1 = MFMA(ahi[k], bh, a1, 0, 0, 0);
            a1 = MFMA(alo[k], bh, a1, 0, 0, 0);
            a1 = MFMA(ahi[k], bl, a1, 0, 0, 0);
        }
#pragma unroll
        for (int i = 0; i < 4; i++) {
            int r = lg * 4 + i;
            T2[r][col0] = a0[i] + ob[col0];
            T2[r][col1] = a1[i] + ob[col1];
        }
    }
    __syncthreads();
    {
        int gr = tid >> 4, l16 = tid & 15;
        float sm = 0.0f, sq = 0.0f;
#pragma unroll
        for (int i = 0; i < 8; i++) {
            float v = T2[gr][l16 + 16 * i];
            sm += v; sq += v * v;
        }
#pragma unroll
        for (int m = 1; m < 16; m <<= 1) { sm += __shfl_xor(sm, m); sq += __shfl_xor(sq, m); }
        if (l16 == 0) {
            float mean = sm * (1.0f / 128.0f);
            float var = sq * (1.0f / 128.0f) - mean * mean;
            mu16[gr] = mean;
            rs16[gr] = rsqrtf(var + 1e-5f);
        }
    }
    __syncthreads();
    {
        float gj = g[j], bb = bln[j];
#pragma unroll
        for (int r = 0; r < 8; r++) {
            int rr = half * 8 + r;
            float v = fmaxf((T2[rr][j] - mu16[rr]) * rs16[rr] * gj + bb, 0.0f);
            emb[(row0 + rr) * 128 + j] = v;
            T2[rr][j] = v;
        }
    }
    __syncthreads();
    {
        bf16x8 ah[4];
#pragma unroll
        for (int k = 0; k < 4; k++) ah[k] = mk_hi(&T2[lr][k * 32 + lg * 8]);
        const unsigned short* wh0 = Shi + (size_t)col0 * 128 + lg * 8;
        const unsigned short* wh1 = Shi + (size_t)col1 * 128 + lg * 8;
        f32x4 a0 = {0.f, 0.f, 0.f, 0.f}, a1 = {0.f, 0.f, 0.f, 0.f};
#pragma unroll
        for (int k = 0; k < 4; k++) {
            a0 = MFMA(ah[k], *(const bf16x8*)(wh0 + k * 32), a0, 0, 0, 0);
            a1 = MFMA(ah[k], *(const bf16x8*)(wh1 + k * 32), a1, 0, 0, 0);
        }
        float b0 = sb1[col0], b1v = sb1[col1], w20 = sW2[col0], w21 = sW2[col1];
#pragma unroll
        for (int i = 0; i < 4; i++) {
            int r = lg * 4 + i;
            float v = tanhf_fast(a0[i] + b0) * w20 + tanhf_fast(a1[i] + b1v) * w21;
            v += __shfl_xor(v, 1);
            v += __shfl_xor(v, 2);
            v += __shfl_xor(v, 4);
            v += __shfl_xor(v, 8);
            if (lr == 0) part[w][r] = v;
        }
    }
    __syncthreads();
    if (tid < 16)
        scores[(row0 + tid) * 2 + t] = part[0][tid] + part[1][tid] + part[2][tid] + part[3][tid] + sb2[0];
}

// ---------------- TAIL-B1: fused2 = relu(LN((w0*emb0+w1*emb1)@eoW + eob)) ----------------
__global__ __launch_bounds__(256) void k_tailB1(const float* __restrict__ emb0,
                                                const float* __restrict__ emb1,
                                                const float* __restrict__ scores,
                                                const unsigned short* __restrict__ Fhi,
                                                const unsigned short* __restrict__ Flo,
                                                const float* __restrict__ eob,
                                                const float* __restrict__ elg,
                                                const float* __restrict__ elb,
                                                float* __restrict__ fused2) {
    __shared__ __align__(16) float T[16][132];
    __shared__ __align__(16) float T2[16][132];
    __shared__ float mu16[16], rs16[16], w0s[16], w1s[16];
    int tid = threadIdx.x;
    long row0 = (long)blockIdx.x * 16;
    if (tid < 16) {
        long r = row0 + tid;
        float s0 = scores[r * 2], s1 = scores[r * 2 + 1];
        float mx = fmaxf(s0, s1);
        float e0 = __expf(s0 - mx), e1 = __expf(s1 - mx);
        float inv = 1.0f / (e0 + e1);
        w0s[tid] = e0 * inv;
        w1s[tid] = e1 * inv;
    }
    __syncthreads();
#pragma unroll
    for (int i = 0; i < 8; i++) {
        int idx = tid + i * 256;
        int r = idx >> 7, c = idx & 127;
        T[r][c] = w0s[r] * emb0[(row0 + r) * 128 + c] + w1s[r] * emb1[(row0 + r) * 128 + c];
    }
    __syncthreads();
    int w = tid >> 6, lane = tid & 63, lr = lane & 15, lg = lane >> 4;
    int col0 = w * 32 + lr, col1 = col0 + 16;
    int j = tid & 127, half = tid >> 7;
    {
        bf16x8 ahi[4], alo[4];
#pragma unroll
        for (int k = 0; k < 4; k++) mk_split(&T[lr][k * 32 + lg * 8], ahi[k], alo[k]);
        const unsigned short* wh0 = Fhi + (size_t)col0 * 128 + lg * 8;
        const unsigned short* wl0 = Flo + (size_t)col0 * 128 + lg * 8;
        const unsigned short* wh1 = Fhi + (size_t)col1 * 128 + lg * 8;
        const unsigned short* wl1 = Flo + (size_t)col1 * 128 + lg * 8;
        f32x4 a0 = {0.f, 0.f, 0.f, 0.f}, a1 = {0.f, 0.f, 0.f, 0.f};
#pragma unroll
        for (int k = 0; k < 4; k++) {
            bf16x8 bh = *(const bf16x8*)(wh0 + k * 32), bl = *(const bf16x8*)(wl0 + k * 32);
            a0 = MFMA(ahi[k], bh, a0, 0, 0, 0);
            a0 = MFMA(alo[k], bh, a0, 0, 0, 0);
            a0 = MFMA(ahi[k], bl, a0, 0, 0, 0);
            bh = *(const bf16x8*)(wh1 + k * 32); bl = *(const bf16x8*)(wl1 + k * 32);
            a1 = MFMA(ahi[k], bh, a1, 0, 0, 0);
            a1 = MFMA(alo[k], bh, a1, 0, 0, 0);
            a1 = MFMA(ahi[k], bl, a1, 0, 0, 0);
        }
#pragma unroll
        for (int i = 0; i < 4; i++) {
            int r = lg * 4 + i;
            T2[r][col0] = a0[i] + eob[col0];
            T2[r][col1] = a1[i] + eob[col1];
        }
    }
    __syncthreads();
    {
        int gr = tid >> 4, l16 = tid & 15;
        float sm = 0.0f, sq = 0.0f;
#pragma unroll
        for (int i = 0; i < 8; i++) {
            float v = T2[gr][l16 + 16 * i];
            sm += v; sq += v * v;
        }
#pragma unroll
        for (int m = 1; m < 16; m <<= 1) { sm += __shfl_xor(sm, m); sq += __shfl_xor(sq, m); }
        if (l16 == 0) {
            float mean = sm * (1.0f / 128.0f);
            float var = sq * (1.0f / 128.0f) - mean * mean;
            mu16[gr] = mean;
            rs16[gr] = rsqrtf(var + 1e-5f);
        }
    }
    __syncthreads();
    {
        float gj = elg[j], bb = elb[j];
#pragma unroll
        for (int r = 0; r < 8; r++) {
            int rr = half * 8 + r;
            float v = fmaxf((T2[rr][j] - mu16[rr]) * rs16[rr] * gj + bb, 0.0f);
            fused2[(row0 + rr) * 128 + j] = v;
        }
    }
}

// ---------------- FSUM: fsum[l] = sum_{lev=l} fused2 ----------------
__global__ __launch_bounds__(256) void k_fsum(const float* __restrict__ fused2,
                                              const int* __restrict__ lev,
                                              float* __restrict__ fsumg) {
    __shared__ float ls[2][4][128];
    int tid = threadIdx.x, half = tid >> 7, j = tid & 127;
#pragma unroll
    for (int l = 0; l < 4; l++) ls[half][l][j] = 0.0f;
    __syncthreads();
    for (long row = (long)blockIdx.x * 2 + half; row < NN; row += (long)gridDim.x * 2) {
        int l = lev[row];
        ls[half][l][j] += fused2[row * 128 + j];
    }
    __syncthreads();
    if (half == 0) {
#pragma unroll
        for (int l = 0; l < 4; l++) atomicAdd(&fsumg[l * 128 + j], ls[0][l][j] + ls[1][l][j]);
    }
}

// ---------------- FIN2: lmean[l] = (fsum[l]@hpW[l]+cnt*hpb[l])/cnt; lmw[l]=lmean[l]@W1b+hb1 --
__global__ void k_fin2(const float* __restrict__ fsum, const int* __restrict__ cnt4,
                       const float* __restrict__ hpW, const float* __restrict__ hpb,
                       const float* __restrict__ W1b, const float* __restrict__ b1,
                       float* __restrict__ lmean, float* __restrict__ lmw) {
    __shared__ float fs[128];
    __shared__ float lml[128];
    int l = blockIdx.x, j = threadIdx.x;
    fs[j] = fsum[l * 128 + j];
    __syncthreads();
    float c = (float)cnt4[l];
    float a = c * hpb[l * 128 + j];
    const float* wp = hpW + (size_t)l * 16384;
    for (int k = 0; k < 128; k++) a = fmaf(fs[k], wp[k * 128 + j], a);
    float cm = c < 1.0f ? 1.0f : c;
    float v = a / cm;
    lmean[l * 128 + j] = v;
    lml[j] = v;
    __syncthreads();
    float b = b1[j];
    for (int k = 0; k < 128; k++) b = fmaf(lml[k], W1b[k * 128 + j], b);
    lmw[l * 128 + j] = b;
}

// ---------------- TAIL-CD2 (level-bucketed): QW[l] GEMM + hier attn + final GEMM + LN -> out --
__global__ __launch_bounds__(256) void k_tailCD2(const float* __restrict__ fused2,
                                                 const int* __restrict__ perm,
                                                 const int* __restrict__ cnt4,
                                                 const int* __restrict__ off4,
                                                 const int* __restrict__ boff5,
                                                 const unsigned short* __restrict__ QWhi,
                                                 const unsigned short* __restrict__ QWlo,
                                                 const float* __restrict__ qb,
                                                 const float* __restrict__ lmw,
                                                 const float* __restrict__ lmean,
                                                 const float* __restrict__ hW2,
                                                 const unsigned short* __restrict__ Ohi,
                                                 const unsigned short* __restrict__ Olo,
                                                 const float* __restrict__ hob,
                                                 const float* __restrict__ hlg,
                                                 const float* __restrict__ hlb,
                                                 float* __restrict__ out) {
    __shared__ __align__(16) float T[16][132];
    __shared__ __align__(16) float T2[16][132];
    __shared__ float lm[4][128];
    __shared__ float lmwS[4][128];
    __shared__ float w2S[128];
    __shared__ float scS[16][4];
    __shared__ float aw[16][4];
    __shared__ float mu16[16], rs16[16];
    __shared__ int idx16[16];
    int tid = threadIdx.x;
    int b = blockIdx.x;
    if (b >= boff5[4]) return;
    int l = (b >= boff5[3]) ? 3 : (b >= boff5[2]) ? 2 : (b >= boff5[1]) ? 1 : 0;
    int bi = b - boff5[l];
    int base = off4[l] + bi * 16;
    int last = off4[l] + cnt4[l] - 1;
    if (tid < 16) {
        int gp = base + tid;
        if (gp > last) gp = last;
        idx16[tid] = perm[gp];
    }
    for (int idx = tid; idx < 512; idx += 256) {
        lm[idx >> 7][idx & 127] = lmean[idx];
        lmwS[idx >> 7][idx & 127] = lmw[idx];
    }
    if (tid < 128) w2S[tid] = hW2[tid];
    __syncthreads();
#pragma unroll
    for (int i = 0; i < 8; i++) {
        int idx = tid + i * 256;
        int r = idx >> 7, c = idx & 127;
        T[r][c] = fused2[(size_t)idx16[r] * 128 + c];
    }
    __syncthreads();
    int w = tid >> 6, lane = tid & 63, lr = lane & 15, lg = lane >> 4;
    int col0 = w * 32 + lr, col1 = col0 + 16;
    int j = tid & 127, half = tid >> 7;
    // hfa = fused2 @ QW[l] + qb[l]
    {
        bf16x8 ahi[4], alo[4];
#pragma unroll
        for (int k = 0; k < 4; k++) mk_split(&T[lr][k * 32 + lg * 8], ahi[k], alo[k]);
        const unsigned short* wh0 = QWhi + (size_t)l * 16384 + (size_t)col0 * 128 + lg * 8;
        const unsigned short* wl0 = QWlo + (size_t)l * 16384 + (size_t)col0 * 128 + lg * 8;
        const unsigned short* wh1 = QWhi + (size_t)l * 16384 + (size_t)col1 * 128 + lg * 8;
        const unsigned short* wl1 = QWlo + (size_t)l * 16384 + (size_t)col1 * 128 + lg * 8;
        f32x4 a0 = {0.f, 0.f, 0.f, 0.f}, a1 = {0.f, 0.f, 0.f, 0.f};
#pragma unroll
        for (int k = 0; k < 4; k++) {
            bf16x8 bh = *(const bf16x8*)(wh0 + k * 32), bl = *(const bf16x8*)(wl0 + k * 32);
            a0 = MFMA(ahi[k], bh, a0, 0, 0, 0);
            a0 = MFMA(alo[k], bh, a0, 0, 0, 0);
            a0 = MFMA(ahi[k], bl, a0, 0, 0, 0);
            bh = *(const bf16x8*)(wh1 + k * 32); bl = *(const bf16x8*)(wl1 + k * 32);
            a1 = MFMA(ahi[k], bh, a1, 0, 0, 0);
            a1 = MFMA(alo[k], bh, a1, 0, 0, 0);
            a1 = MFMA(ahi[k], bl, a1, 0, 0, 0);
        }
#pragma unroll
        for (int i = 0; i < 4; i++) {
            int r = lg * 4 + i;
            T2[r][col0] = a0[i] + qb[l * 128 + col0];
            T2[r][col1] = a1[i] + qb[l * 128 + col1];
        }
    }
    __syncthreads();
    // hier scores: 4 threads per (row, level') pair, stride-4 cols
    {
        int p = tid >> 2, sub = tid & 3;
        int pr = p & 15, pl = p >> 4;
        float s = 0.0f;
#pragma unroll
        for (int jj = 0; jj < 32; jj++) {
            int j2 = sub + 4 * jj;
            s += tanhf_fast(T2[pr][j2] + lmwS[pl][j2]) * w2S[j2];
        }
        s += __shfl_xor(s, 1);
        s += __shfl_xor(s, 2);
        if (sub == 0) scS[pr][pl] = s;
    }
    __syncthreads();
    if (tid < 16) {
        float sc[4];
        float mx = -1e30f;
#pragma unroll
        for (int ll = 0; ll < 4; ll++) {
            sc[ll] = scS[tid][ll];
            mx = fmaxf(mx, sc[ll]);
        }
        float s = 0.0f;
#pragma unroll
        for (int ll = 0; ll < 4; ll++) { sc[ll] = __expf(sc[ll] - mx); s += sc[ll]; }
        float inv = 1.0f / s;
#pragma unroll
        for (int ll = 0; ll < 4; ll++) aw[tid][ll] = sc[ll] * inv;
    }
    __syncthreads();
    // enhanced = aw @ lmean
#pragma unroll
    for (int r = 0; r < 8; r++) {
        int rr = half * 8 + r;
        float e = 0.0f;
#pragma unroll
        for (int ll = 0; ll < 4; ll++) e = fmaf(aw[rr][ll], lm[ll][j], e);
        T[rr][j] = e;
    }
    __syncthreads();
    // out = relu(LN(enh @ hoW + hob))
    {
        bf16x8 ahi[4], alo[4];
#pragma unroll
        for (int k = 0; k < 4; k++) mk_split(&T[lr][k * 32 + lg * 8], ahi[k], alo[k]);
        const unsigned short* wh0 = Ohi + (size_t)col0 * 128 + lg * 8;
        const unsigned short* wl0 = Olo + (size_t)col0 * 128 + lg * 8;
        const unsigned short* wh1 = Ohi + (size_t)col1 * 128 + lg * 8;
        const unsigned short* wl1 = Olo + (size_t)col1 * 128 + lg * 8;
        f32x4 a0 = {0.f, 0.f, 0.f, 0.f}, a1 = {0.f, 0.f, 0.f, 0.f};
#pragma unroll
        for (int k = 0; k < 4; k++) {
            bf16x8 bh = *(const bf16x8*)(wh0 + k * 32), bl = *(const bf16x8*)(wl0 + k * 32);
            a0 = MFMA(ahi[k], bh, a0, 0, 0, 0);
            a0 = MFMA(alo[k], bh, a0, 0, 0, 0);
            a0 = MFMA(ahi[k], bl, a0, 0, 0, 0);
            bh = *(const bf16x8*)(wh1 + k * 32); bl = *(const bf16x8*)(wl1 + k * 32);
            a1 = MFMA(ahi[k], bh, a1, 0, 0, 0);
            a1 = MFMA(alo[k], bh, a1, 0, 0, 0);
            a1 = MFMA(ahi[k], bl, a1, 0, 0, 0);
        }
#pragma unroll
        for (int i = 0; i < 4; i++) {
            int r = lg * 4 + i;
            T2[r][col0] = a0[i] + hob[col0];
            T2[r][col1] = a1[i] + hob[col1];
        }
    }
    __syncthreads();
    {
        int gr = tid >> 4, l16 = tid & 15;
        float sm = 0.0f, sq = 0.0f;
#pragma unroll
        for (int i = 0; i < 8; i++) {
            float v = T2[gr][l16 + 16 * i];
            sm += v; sq += v * v;
        }
#pragma unroll
        for (int m = 1; m < 16; m <<= 1) { sm += __shfl_xor(sm, m); sq += __shfl_xor(sq, m); }
        if (l16 == 0) {
            float mean = sm * (1.0f / 128.0f);
            float var = sq * (1.0f / 128.0f) - mean * mean;
            mu16[gr] = mean;
            rs16[gr] = rsqrtf(var + 1e-5f);
        }
    }
    __syncthreads();
    {
        float gj = hlg[j], bb = hlb[j];
#pragma unroll
        for (int r = 0; r < 8; r++) {
            int rr = half * 8 + r;
            float v = (T2[rr][j] - mu16[rr]) * rs16[rr] * gj + bb;
            out[(size_t)idx16[rr] * 128 + j] = fmaxf(v, 0.0f);
        }
    }
}

extern "C" void kernel_launch(void* const* d_in, const int* in_sizes, int n_in,
                              void* d_out, int out_size, void* d_ws, size_t ws_size,
                              hipStream_t stream) {
    const float* nf  = (const float*)d_in[0];
    const float* ef  = (const float*)d_in[1];
    const int*   lev = (const int*)d_in[2];
    const int*   ei  = (const int*)d_in[3];
    const float* nlW = (const float*)d_in[4];
    const float* nlb = (const float*)d_in[5];
    const float* neW = (const float*)d_in[6];
    const float* neb = (const float*)d_in[7];
    const float* aW1 = (const float*)d_in[8];
    const float* ab1 = (const float*)d_in[9];
    const float* aW2 = (const float*)d_in[10];
    const float* ab2 = (const float*)d_in[11];
    const float* oW  = (const float*)d_in[12];
    const float* ob  = (const float*)d_in[13];
    const float* lng = (const float*)d_in[14];
    const float* lnb = (const float*)d_in[15];
    const float* eW1 = (const float*)d_in[16];
    const float* eb1 = (const float*)d_in[17];
    const float* eW2 = (const float*)d_in[18];
    const float* eb2 = (const float*)d_in[19];
    const float* eoW = (const float*)d_in[20];
    const float* eob = (const float*)d_in[21];
    const float* elg = (const float*)d_in[22];
    const float* elb = (const float*)d_in[23];
    const float* hpW = (const float*)d_in[24];
    const float* hpb = (const float*)d_in[25];
    const float* hW1 = (const float*)d_in[26];
    const float* hb1 = (const float*)d_in[27];
    const float* hW2 = (const float*)d_in[28];
    const float* hb2 = (const float*)d_in[29];
    const float* hoW = (const float*)d_in[30];
    const float* hob = (const float*)d_in[31];
    const float* hlg = (const float*)d_in[32];
    const float* hlb = (const float*)d_in[33];

    float* ws = (float*)d_ws;
    size_t NH = (size_t)NN * 128;
    float* fused2 = ws;              // NH (CSR scratch aliases this until tailB1)
    float* emb0   = fused2 + NH;     // NH
    float* emb1   = emb0 + NH;       // NH
    float* ebuf   = emb1 + NH;       // EE (CSR-ordered ev)
    float* scores = ebuf + EE;       // 2*NN
    float* beff   = scores + (size_t)2 * NN;  // 128
    float* fsum   = beff + 128;      // 512
    float* lmean  = fsum + 512;      // 512
    float* lmw    = lmean + 512;     // 512
    float* qb     = lmw + 512;       // 512
    unsigned short* U    = (unsigned short*)(qb + 512);   // NH
    unsigned short* V    = U + NH;                        // NH
    unsigned short* hbf  = V + NH;                        // NH
    unsigned short* WhT  = hbf + NH;                      // 16384
    unsigned short* WUT  = WhT + 16384;
    unsigned short* WVT  = WUT + 16384;
    unsigned short* WET  = WVT + 16384;                   // 8192
    unsigned short* twhi = WET + 8192;                    // 6*16384
    unsigned short* twlo = twhi + 6 * 16384;              // 6*16384
    unsigned short* QWhi = twlo + 6 * 16384;              // 4*16384
    unsigned short* QWlo = QWhi + 4 * 16384;              // 4*16384
    int* perm  = (int*)(QWlo + 4 * 16384);                // NN
    int* cnt4  = perm + NN;                               // 4
    int* off4  = cnt4 + 4;                                // 4
    int* boff5 = off4 + 4;                                // 5
    int* cursorL = boff5 + 5;                             // 4
    // CSR scratch aliases fused2 (dead until k_tailB1)
    int* epos   = (int*)fused2;          // EE
    int* cdst   = epos + EE;             // EE
    int* deg    = cdst + EE;             // NN
    int* rowptr = deg + NN;              // NN+1
    int* cursor = rowptr + NN + 1;       // NN
    int* stmp   = cursor + NN;           // NN
    int* sbsum  = stmp + NN;             // 256
    int* sboff  = sbsum + 256;           // 256
    float* out = (float*)d_out;

    WSrc ps;
    ps.s[0] = oW;               // oW t0
    ps.s[1] = oW + 16384;       // oW t1
    ps.s[2] = eW1;              // eW1 t0
    ps.s[3] = eW1 + 16384;      // eW1 t1
    ps.s[4] = eoW;
    ps.s[5] = hoW;

    // level bucketing (independent of the main pipeline)
    k_zeroi<<<1, 4, 0, stream>>>(cnt4, 4);
    k_count<<<128, 256, 0, stream>>>(lev, cnt4);
    k_scan<<<1, 1, 0, stream>>>(cnt4, off4, boff5, cursorL);
    k_scatter<<<125, 256, 0, stream>>>(lev, cursorL, perm);

    k_prep_tail<<<6 * 64, 256, 0, stream>>>(ps, twhi, twlo);
    k_prep_q<<<258, 256, 0, stream>>>(hpW, hpb, hW1, QWhi, QWlo, qb);
    k_zero<<<1, 512, 0, stream>>>(fsum, (size_t)512);

    for (int t = 0; t < 2; t++) {
        const int* eis = ei + (size_t)t * 2 * EE;
        const int* eid = eis + EE;
        // CSR build for this relation
        k_zeroi<<<(NN + 255) / 256, 256, 0, stream>>>(deg, NN);
        k_hist<<<(EE + 255) / 256, 256, 0, stream>>>(eis, deg);
        k_scan1<<<196, 512, 0, stream>>>(deg, stmp, sbsum);
        k_scan2<<<1, 256, 0, stream>>>(sbsum, sboff);
        k_scan3<<<196, 512, 0, stream>>>(deg, stmp, sboff, rowptr, cursor);
        k_csr_scatter<<<(EE + 255) / 256, 256, 0, stream>>>(eis, eid, cursor, epos, cdst);

        k_prep_head<<<128, 128, 0, stream>>>(nlW + (size_t)t * 16384, nlb + t * 128,
                                             aW1 + (size_t)t * 384 * 128, ab1 + t * 128,
                                             neW + (size_t)t * 64 * 128, neb + t * 128,
                                             WhT, WUT, WVT, WET, beff);
        k_head<<<NN / 16, 256, 0, stream>>>(nf, WhT, WUT, WVT, nlb + t * 128, hbf, U, V);
        k_edge3<<<(EE + 63) / 64, 256, 0, stream>>>(ef + (size_t)t * EE * 64, eis, eid, epos,
                                                    WET, U, V, beff, aW2 + t * 128,
                                                    ab2 + t, ebuf);
        float* embt = (t == 0) ? emb0 : emb1;
        k_tailA2<<<NN / 16, 256, 0, stream>>>(rowptr, cdst, ebuf, hbf,
                                              twhi + (size_t)t * 16384, twlo + (size_t)t * 16384,
                                              ob + t * 128, lng + t * 128, lnb + t * 128,
                                              twhi + (size_t)(2 + t) * 16384,
                                              eb1 + t * 128, eW2 + t * 128, eb2 + t,
                                              embt, scores, t);
    }
    k_tailB1<<<NN / 16, 256, 0, stream>>>(emb0, emb1, scores,
                                          twhi + (size_t)4 * 16384, twlo + (size_t)4 * 16384,
                                          eob, elg, elb, fused2);
    k_fsum<<<256, 256, 0, stream>>>(fused2, lev, fsum);
    k_fin2<<<4, 128, 0, stream>>>(fsum, cnt4, hpW, hpb, hW1 + 16384, hb1, lmean, lmw);
    k_tailCD2<<<NN / 16 + 4, 256, 0, stream>>>(fused2, perm, cnt4, off4, boff5,
                                               QWhi, QWlo, qb, lmw, lmean, hW2,
                                               twhi + (size_t)5 * 16384, twlo + (size_t)5 * 16384,
                                               hob, hlg, hlb, out);
}

// Round 9
// 962.114 us; speedup vs baseline: 1.7239x; 1.0817x over previous
//
#include <hip/hip_runtime.h>
#include <math.h>

#define NN 100000
#define EE 500000
#define NH_C (NN * 128)
// D=H=128, ED=64, T=2, L=4

typedef __attribute__((ext_vector_type(8))) short bf16x8;
typedef __attribute__((ext_vector_type(4))) float f32x4;
#define MFMA __builtin_amdgcn_mfma_f32_16x16x32_bf16

__device__ inline short f2bf(float x) {
    union { float f; unsigned u; } v; v.f = x;
    unsigned r = v.u + 0x7FFF + ((v.u >> 16) & 1);
    return (short)(r >> 16);
}
__device__ inline float bf2f(unsigned short h) {
    union { unsigned u; float f; } v; v.u = ((unsigned)h) << 16; return v.f;
}
__device__ inline float tanhf_fast(float x) {
    float e = __expf(2.0f * x);
    return 1.0f - 2.0f * __builtin_amdgcn_rcpf(e + 1.0f);
}

__device__ inline bf16x8 mk_hi(const float* p) {
    float4 a = *(const float4*)p, b = *(const float4*)(p + 4);
    float v[8] = {a.x, a.y, a.z, a.w, b.x, b.y, b.z, b.w};
    bf16x8 h;
#pragma unroll
    for (int i = 0; i < 8; i++) h[i] = f2bf(v[i]);
    return h;
}
__device__ inline bf16x8 mk_hi8(float4 a, float4 b) {
    float v[8] = {a.x, a.y, a.z, a.w, b.x, b.y, b.z, b.w};
    bf16x8 h;
#pragma unroll
    for (int i = 0; i < 8; i++) h[i] = f2bf(v[i]);
    return h;
}
__device__ inline void mk_split(const float* p, bf16x8& hi, bf16x8& lo) {
    float4 a = *(const float4*)p, b = *(const float4*)(p + 4);
    float v[8] = {a.x, a.y, a.z, a.w, b.x, b.y, b.z, b.w};
#pragma unroll
    for (int i = 0; i < 8; i++) {
        short h = f2bf(v[i]);
        hi[i] = h;
        lo[i] = f2bf(v[i] - bf2f((unsigned short)h));
    }
}

// ---------------- zero fill ----------------
__global__ void k_zero(float* __restrict__ p, size_t n) {
    size_t i = (size_t)blockIdx.x * blockDim.x + threadIdx.x;
    size_t stride = (size_t)gridDim.x * blockDim.x;
    for (; i < n; i += stride) p[i] = 0.0f;
}
__global__ void k_zeroi(int* __restrict__ p, int n) {
    int i = blockIdx.x * blockDim.x + threadIdx.x;
    if (i < n) p[i] = 0;
}

// ---------------- CSR build (both relations, concatenated) ----------------
__global__ __launch_bounds__(256) void k_hist2(const int* __restrict__ ei, int* __restrict__ deg2) {
    long g = (long)blockIdx.x * 256 + threadIdx.x;
    if (g < 2L * EE) {
        int t = g >= EE;
        long le = g - (long)t * EE;
        int s = ei[(size_t)t * 2 * EE + le];
        atomicAdd(&deg2[t * NN + s], 1);
    }
}
__global__ __launch_bounds__(512) void k_scan1(const int* __restrict__ deg,
                                               int* __restrict__ tmp, int* __restrict__ bsum) {
    __shared__ int sh[2][512];
    int b = blockIdx.x, tid = threadIdx.x;
    int i = b * 512 + tid;
    int v = (i < 2 * NN) ? deg[i] : 0;
    int cur = 0;
    sh[0][tid] = v;
    __syncthreads();
    for (int off = 1; off < 512; off <<= 1) {
        int nxt = cur ^ 1;
        int a = sh[cur][tid];
        if (tid >= off) a += sh[cur][tid - off];
        sh[nxt][tid] = a;
        __syncthreads();
        cur = nxt;
    }
    int incl = sh[cur][tid];
    if (i < 2 * NN) tmp[i] = incl;
    if (tid == 511) bsum[b] = incl;
}
__global__ __launch_bounds__(512) void k_scan2(const int* __restrict__ bsum, int* __restrict__ boff,
                                               int nB) {
    __shared__ int sh[2][512];
    int tid = threadIdx.x;
    int v = (tid < nB) ? bsum[tid] : 0;
    int cur = 0;
    sh[0][tid] = v;
    __syncthreads();
    for (int off = 1; off < 512; off <<= 1) {
        int nxt = cur ^ 1;
        int a = sh[cur][tid];
        if (tid >= off) a += sh[cur][tid - off];
        sh[nxt][tid] = a;
        __syncthreads();
        cur = nxt;
    }
    boff[tid] = sh[cur][tid] - v;
}
__global__ __launch_bounds__(512) void k_scan3(const int* __restrict__ deg,
                                               const int* __restrict__ tmp,
                                               const int* __restrict__ boff,
                                               int* __restrict__ rowptr, int* __restrict__ cursor) {
    int i = blockIdx.x * 512 + threadIdx.x;
    if (i < 2 * NN) {
        int r = tmp[i] - deg[i] + boff[blockIdx.x];
        rowptr[i] = r;
        cursor[i] = r;
    }
    if (i == 0) rowptr[2 * NN] = 2 * EE;
}
__global__ __launch_bounds__(256) void k_csr_scatter2(const int* __restrict__ ei,
                                                      int* __restrict__ cursor,
                                                      int* __restrict__ epos,
                                                      int* __restrict__ cdst) {
    long g = (long)blockIdx.x * 256 + threadIdx.x;
    if (g < 2L * EE) {
        int t = g >= EE;
        long le = g - (long)t * EE;
        int s = ei[(size_t)t * 2 * EE + le];
        int d = ei[(size_t)t * 2 * EE + EE + le];
        int p = atomicAdd(&cursor[t * NN + s], 1);
        epos[g] = p;
        cdst[p] = d;
    }
}

// ---------------- level bucketing ----------------
__global__ __launch_bounds__(256) void k_count(const int* __restrict__ lev, int* __restrict__ cnt4) {
    __shared__ int lc[4];
    int tid = threadIdx.x;
    if (tid < 4) lc[tid] = 0;
    __syncthreads();
    for (long n = (long)blockIdx.x * 256 + tid; n < NN; n += (long)gridDim.x * 256)
        atomicAdd(&lc[lev[n]], 1);
    __syncthreads();
    if (tid < 4 && lc[tid]) atomicAdd(&cnt4[tid], lc[tid]);
}

__global__ void k_scan(const int* __restrict__ cnt4, int* __restrict__ off4,
                       int* __restrict__ boff5, int* __restrict__ cursor) {
    int o = 0, b = 0;
    for (int l = 0; l < 4; l++) {
        off4[l] = o; cursor[l] = o; boff5[l] = b;
        o += cnt4[l];
        b += (cnt4[l] + 15) >> 4;
    }
    boff5[4] = b;
}

__global__ __launch_bounds__(256) void k_scatter(const int* __restrict__ lev,
                                                 int* __restrict__ cursor,
                                                 int* __restrict__ perm) {
    __shared__ int lc[4], lb[4], lc2[4];
    int tid = threadIdx.x;
    if (tid < 4) { lc[tid] = 0; lc2[tid] = 0; }
    __syncthreads();
    int start = blockIdx.x * 800, end = start + 800;
    if (end > NN) end = NN;
    for (int n = start + tid; n < end; n += 256) atomicAdd(&lc[lev[n]], 1);
    __syncthreads();
    if (tid < 4 && lc[tid]) lb[tid] = atomicAdd(&cursor[tid], lc[tid]);
    __syncthreads();
    for (int n = start + tid; n < end; n += 256) {
        int l = lev[n];
        int p = atomicAdd(&lc2[l], 1);
        perm[lb[l] + p] = n;
    }
}

// ---------------- prep head (both t): WhT2, WUT2, WVT2, WET2 (bf16 T), beff2 ----------------
__global__ void k_prep_head2(const float* __restrict__ nlW, const float* __restrict__ nlb,
                             const float* __restrict__ aW1, const float* __restrict__ ab1,
                             const float* __restrict__ neW, const float* __restrict__ neb,
                             unsigned short* __restrict__ WhT2, unsigned short* __restrict__ WUT2,
                             unsigned short* __restrict__ WVT2, unsigned short* __restrict__ WET2,
                             float* __restrict__ beff2) {
    __shared__ float red[2];
    int t = blockIdx.x >> 7, j = blockIdx.x & 127, k = threadIdx.x;
    const float* Wn = nlW + (size_t)t * 16384;
    const float* bn = nlb + t * 128;
    const float* W1 = aW1 + (size_t)t * 384 * 128;
    const float* b1 = ab1 + t * 128;
    const float* We = neW + (size_t)t * 64 * 128;
    const float* be = neb + t * 128;
    WhT2[(size_t)t * 16384 + j * 128 + k] = (unsigned short)f2bf(Wn[k * 128 + j]);
    float su = 0.0f, sv = 0.0f;
    for (int m = 0; m < 128; m++) {
        float wkm = Wn[k * 128 + m];
        su = fmaf(wkm, W1[m * 128 + j], su);
        sv = fmaf(wkm, W1[(128 + m) * 128 + j], sv);
    }
    WUT2[(size_t)t * 16384 + j * 128 + k] = (unsigned short)f2bf(su);
    WVT2[(size_t)t * 16384 + j * 128 + k] = (unsigned short)f2bf(sv);
    if (k < 64) {
        float se = 0.0f;
        for (int m = 0; m < 128; m++) se = fmaf(We[k * 128 + m], W1[(256 + m) * 128 + j], se);
        WET2[(size_t)t * 8192 + j * 64 + k] = (unsigned short)f2bf(se);
    }
    float tk = bn[k] * (W1[k * 128 + j] + W1[(128 + k) * 128 + j]) + be[k] * W1[(256 + k) * 128 + j];
#pragma unroll
    for (int o = 32; o > 0; o >>= 1) tk += __shfl_down(tk, o);
    if ((k & 63) == 0) red[k >> 6] = tk;
    __syncthreads();
    if (k == 0) beff2[t * 128 + j] = b1[j] + red[0] + red[1];
}

// ---------------- prep tail: split-bf16 transposed weights (6 mats) ----------------
struct WSrc { const float* s[6]; };
__global__ void k_prep_tail(WSrc ps, unsigned short* __restrict__ hi,
                            unsigned short* __restrict__ lo) {
    int m = blockIdx.x >> 6, blk = blockIdx.x & 63;
    const float* src = ps.s[m];
    unsigned short* h = hi + (size_t)m * 16384;
    unsigned short* l = lo + (size_t)m * 16384;
    int idx = blk * 256 + threadIdx.x;
    int k = idx >> 7, j = idx & 127;
    float v = src[idx];
    short hh = f2bf(v);
    h[j * 128 + k] = (unsigned short)hh;
    l[j * 128 + k] = (unsigned short)f2bf(v - bf2f((unsigned short)hh));
}

// ---------------- prep Q: QW[l] = hpW[l] @ hW1a (T split bf16), qb[l] = hpb[l]@hW1a ----------
__global__ void k_prep_q(const float* __restrict__ hpW, const float* __restrict__ hpb,
                         const float* __restrict__ hW1a,
                         unsigned short* __restrict__ QWhi, unsigned short* __restrict__ QWlo,
                         float* __restrict__ qb) {
    int gidx = blockIdx.x * 256 + threadIdx.x;
    if (gidx < 4 * 16384) {
        int l = gidx >> 14, rem = gidx & 16383;
        int k = rem >> 7, j = rem & 127;
        const float* wr = hpW + (size_t)l * 16384 + (size_t)k * 128;
        float v = 0.0f;
        for (int m = 0; m < 128; m++) v = fmaf(wr[m], hW1a[m * 128 + j], v);
        short hh = f2bf(v);
        QWhi[(size_t)l * 16384 + j * 128 + k] = (unsigned short)hh;
        QWlo[(size_t)l * 16384 + j * 128 + k] = (unsigned short)f2bf(v - bf2f((unsigned short)hh));
    } else {
        int e = gidx - 4 * 16384;
        if (e < 512) {
            int l = e >> 7, j = e & 127;
            float v = 0.0f;
            for (int m = 0; m < 128; m++) v = fmaf(hpb[l * 128 + m], hW1a[m * 128 + j], v);
            qb[l * 128 + j] = v;
        }
    }
}

// ---------------- HEAD2: both t from one nf tile -> hbf,U,V (x2) ----------------
__global__ __launch_bounds__(256) void k_head2(const float* __restrict__ nf,
                                               const unsigned short* __restrict__ WhT2,
                                               const unsigned short* __restrict__ WUT2,
                                               const unsigned short* __restrict__ WVT2,
                                               const float* __restrict__ nlb,
                                               unsigned short* __restrict__ hbf2,
                                               unsigned short* __restrict__ U2,
                                               unsigned short* __restrict__ V2) {
    __shared__ __align__(16) float T[16][132];
    int tid = threadIdx.x;
    long row0 = (long)blockIdx.x * 16;
#pragma unroll
    for (int i = 0; i < 8; i++) {
        int idx = tid + i * 256;
        int r = idx >> 7, c = idx & 127;
        T[r][c] = nf[(row0 + r) * 128 + c];
    }
    __syncthreads();
    int w = tid >> 6, lane = tid & 63, lr = lane & 15, lg = lane >> 4;
    bf16x8 A[4];
#pragma unroll
    for (int k = 0; k < 4; k++) A[k] = mk_hi(&T[lr][k * 32 + lg * 8]);
    int col0 = w * 32 + lr, col1 = col0 + 16;
#pragma unroll
    for (int o = 0; o < 6; o++) {
        const unsigned short* wb =
            (o == 0) ? WhT2 : (o == 1) ? WUT2 : (o == 2) ? WVT2 :
            (o == 3) ? WhT2 + 16384 : (o == 4) ? WUT2 + 16384 : WVT2 + 16384;
        unsigned short* ob =
            (o == 0) ? hbf2 : (o == 1) ? U2 : (o == 2) ? V2 :
            (o == 3) ? hbf2 + NH_C : (o == 4) ? U2 + NH_C : V2 + NH_C;
        const unsigned short* w0 = wb + (size_t)col0 * 128 + lg * 8;
        const unsigned short* w1 = wb + (size_t)col1 * 128 + lg * 8;
        f32x4 a0 = {0.f, 0.f, 0.f, 0.f}, a1 = {0.f, 0.f, 0.f, 0.f};
#pragma unroll
        for (int k = 0; k < 4; k++) {
            a0 = MFMA(A[k], *(const bf16x8*)(w0 + k * 32), a0, 0, 0, 0);
            a1 = MFMA(A[k], *(const bf16x8*)(w1 + k * 32), a1, 0, 0, 0);
        }
        float bb0 = (o == 0) ? nlb[col0] : (o == 3) ? nlb[128 + col0] : 0.0f;
        float bb1 = (o == 0) ? nlb[col1] : (o == 3) ? nlb[128 + col1] : 0.0f;
        unsigned short* op = ob + (size_t)row0 * 128;
#pragma unroll
        for (int i = 0; i < 4; i++) {
            int r = lg * 4 + i;
            op[(size_t)r * 128 + col0] = (unsigned short)f2bf(a0[i] + bb0);
            op[(size_t)r * 128 + col1] = (unsigned short)f2bf(a1[i] + bb1);
        }
    }
}

// ---------------- EDGE3B (both t): LDS pre=U[s]+V[d]; prefetched ef MFMA; ev -> CSR slot ----
__global__ __launch_bounds__(256) void k_edge3b(const float* __restrict__ ef,
                                                const int* __restrict__ ei,
                                                const int* __restrict__ epos2,
                                                const unsigned short* __restrict__ WET2,
                                                const unsigned short* __restrict__ U2,
                                                const unsigned short* __restrict__ V2,
                                                const float* __restrict__ beff2,
                                                const float* __restrict__ aW2,
                                                const float* __restrict__ ab2,
                                                float* __restrict__ ebuf2, int NB) {
    __shared__ __align__(16) float pre[64][132];
    __shared__ float part[4][64];
    int tid = threadIdx.x, w = tid >> 6, lane = tid & 63, lr = lane & 15, lg = lane >> 4;
    int t = blockIdx.x >= NB;
    int bi = blockIdx.x - t * NB;
    long e0 = (long)bi * 64;
    long remE = (long)EE - e0;
    int nE = remE < 64 ? (int)remE : 64;
    const float* ef_t = ef + (size_t)t * EE * 64;
    const int* eis = ei + (size_t)t * 2 * EE;
    const int* eid = eis + EE;
    const int* eposT = epos2 + (size_t)t * EE;
    const unsigned short* U_t = U2 + (size_t)t * NH_C;
    const unsigned short* V_t = V2 + (size_t)t * NH_C;
    // ---- stage pre = U[s] + V[d] ----
    {
        int eL = tid >> 2;
        int c4 = tid & 3;
        if (eL < nE) {
            long e = e0 + eL;
            int s = eis[e], d = eid[e];
            const unsigned short* up = U_t + (size_t)s * 128 + c4 * 32;
            const unsigned short* vp = V_t + (size_t)d * 128 + c4 * 32;
#pragma unroll
            for (int i = 0; i < 4; i++) {
                bf16x8 uv = *(const bf16x8*)(up + i * 8);
                bf16x8 vv = *(const bf16x8*)(vp + i * 8);
                float4 lo4, hi4;
                lo4.x = bf2f((unsigned short)uv[0]) + bf2f((unsigned short)vv[0]);
                lo4.y = bf2f((unsigned short)uv[1]) + bf2f((unsigned short)vv[1]);
                lo4.z = bf2f((unsigned short)uv[2]) + bf2f((unsigned short)vv[2]);
                lo4.w = bf2f((unsigned short)uv[3]) + bf2f((unsigned short)vv[3]);
                hi4.x = bf2f((unsigned short)uv[4]) + bf2f((unsigned short)vv[4]);
                hi4.y = bf2f((unsigned short)uv[5]) + bf2f((unsigned short)vv[5]);
                hi4.z = bf2f((unsigned short)uv[6]) + bf2f((unsigned short)vv[6]);
                hi4.w = bf2f((unsigned short)uv[7]) + bf2f((unsigned short)vv[7]);
                *(float4*)&pre[eL][c4 * 32 + i * 8] = lo4;
                *(float4*)&pre[eL][c4 * 32 + i * 8 + 4] = hi4;
            }
        }
    }
    int col0 = w * 32 + lr, col1 = col0 + 16;
    bf16x8 B0[2], B1[2];
#pragma unroll
    for (int kk = 0; kk < 2; kk++) {
        B0[kk] = *(const bf16x8*)(WET2 + (size_t)t * 8192 + (size_t)col0 * 64 + kk * 32 + lg * 8);
        B1[kk] = *(const bf16x8*)(WET2 + (size_t)t * 8192 + (size_t)col1 * 64 + kk * 32 + lg * 8);
    }
    float be0 = beff2[t * 128 + col0], be1 = beff2[t * 128 + col1];
    float w20 = aW2[t * 128 + col0], w21 = aW2[t * 128 + col1];
    __syncthreads();
    if (nE == 64) {
#pragma unroll
        for (int h2 = 0; h2 < 2; h2++) {
            float4 L[8];
#pragma unroll
            for (int i = 0; i < 2; i++) {
                const float* ep = ef_t + (size_t)(e0 + (h2 * 2 + i) * 16 + lr) * 64 + lg * 8;
                L[i * 4 + 0] = *(const float4*)ep;
                L[i * 4 + 1] = *(const float4*)(ep + 4);
                L[i * 4 + 2] = *(const float4*)(ep + 32);
                L[i * 4 + 3] = *(const float4*)(ep + 36);
            }
#pragma unroll
            for (int i = 0; i < 2; i++) {
                int i16 = h2 * 2 + i;
                bf16x8 av0 = mk_hi8(L[i * 4 + 0], L[i * 4 + 1]);
                bf16x8 av1 = mk_hi8(L[i * 4 + 2], L[i * 4 + 3]);
                f32x4 a0 = {0.f, 0.f, 0.f, 0.f}, a1 = {0.f, 0.f, 0.f, 0.f};
                a0 = MFMA(av0, B0[0], a0, 0, 0, 0);
                a0 = MFMA(av1, B0[1], a0, 0, 0, 0);
                a1 = MFMA(av0, B1[0], a1, 0, 0, 0);
                a1 = MFMA(av1, B1[1], a1, 0, 0, 0);
#pragma unroll
                for (int q = 0; q < 4; q++) {
                    int eL = i16 * 16 + lg * 4 + q;
                    float v = tanhf_fast(a0[q] + pre[eL][col0] + be0) * w20 +
                              tanhf_fast(a1[q] + pre[eL][col1] + be1) * w21;
                    v += __shfl_xor(v, 1);
                    v += __shfl_xor(v, 2);
                    v += __shfl_xor(v, 4);
                    v += __shfl_xor(v, 8);
                    if (lr == 0) part[w][eL] = v;
                }
            }
        }
    } else {
        int n16 = (nE + 15) >> 4;
        for (int i16 = 0; i16 < n16; i16++) {
            long eg0 = e0 + i16 * 16;
            const float* ep = ef_t + (size_t)(eg0 + lr) * 64;
            f32x4 a0 = {0.f, 0.f, 0.f, 0.f}, a1 = {0.f, 0.f, 0.f, 0.f};
#pragma unroll
            for (int kk = 0; kk < 2; kk++) {
                bf16x8 a = mk_hi(ep + kk * 32 + lg * 8);
                a0 = MFMA(a, B0[kk], a0, 0, 0, 0);
                a1 = MFMA(a, B1[kk], a1, 0, 0, 0);
            }
#pragma unroll
            for (int q = 0; q < 4; q++) {
                int eL = i16 * 16 + lg * 4 + q;
                float v = tanhf_fast(a0[q] + pre[eL][col0] + be0) * w20 +
                          tanhf_fast(a1[q] + pre[eL][col1] + be1) * w21;
                v += __shfl_xor(v, 1);
                v += __shfl_xor(v, 2);
                v += __shfl_xor(v, 4);
                v += __shfl_xor(v, 8);
                if (lr == 0) part[w][eL] = v;
            }
        }
    }
    __syncthreads();
    if (tid < nE) {
        long e = e0 + tid;
        float a = part[0][tid] + part[1][tid] + part[2][tid] + part[3][tid] + ab2[t];
        ebuf2[eposT[e]] = __expf(a);
    }
}

// ---------------- TAIL-A2B (both t): CSR gather (2-way unroll) + GEMM + LN + score ----------
__global__ __launch_bounds__(256) void k_tailA2b(const int* __restrict__ rowptr2,
                                                 const int* __restrict__ cdst,
                                                 const float* __restrict__ ebufC,
                                                 const unsigned short* __restrict__ hbf2,
                                                 const unsigned short* __restrict__ twhi,
                                                 const unsigned short* __restrict__ twlo,
                                                 const float* __restrict__ ob,
                                                 const float* __restrict__ lng,
                                                 const float* __restrict__ lnb,
                                                 const float* __restrict__ eb1,
                                                 const float* __restrict__ eW2,
                                                 const float* __restrict__ eb2,
                                                 float* __restrict__ emb0,
                                                 float* __restrict__ emb1,
                                                 float* __restrict__ scores, int NBn) {
    __shared__ __align__(16) float T[16][132];
    __shared__ __align__(16) float T2[16][132];
    __shared__ float mu16[16], rs16[16], part[4][16];
    int tid = threadIdx.x;
    int t = blockIdx.x >= NBn;
    int bi = blockIdx.x - t * NBn;
    long row0 = (long)bi * 16;
    const int* rowp = rowptr2 + (size_t)t * NN;
    const unsigned short* hbf_t = hbf2 + (size_t)t * NH_C;
    const unsigned short* Whi = twhi + (size_t)t * 16384;
    const unsigned short* Wlo = twlo + (size_t)t * 16384;
    const unsigned short* Shi = twhi + (size_t)(2 + t) * 16384;
    const float* ob_t = ob + t * 128;
    const float* g_t = lng + t * 128;
    const float* bln_t = lnb + t * 128;
    const float* sb1 = eb1 + t * 128;
    const float* sW2 = eW2 + t * 128;
    float* emb = t ? emb1 : emb0;
    // CSR gather: 16 threads/row, 2-way unrolled
    {
        int r16 = tid >> 4, sub = tid & 15;
        long n = row0 + r16;
        int p0 = rowp[n], p1 = rowp[n + 1];
        float acc[8] = {0, 0, 0, 0, 0, 0, 0, 0};
        float sev = 0.0f;
        int p = p0;
        for (; p + 2 <= p1; p += 2) {
            int d0 = cdst[p], d1 = cdst[p + 1];
            float ev0 = ebufC[p], ev1 = ebufC[p + 1];
            bf16x8 h0 = *(const bf16x8*)(hbf_t + (size_t)d0 * 128 + sub * 8);
            bf16x8 h1 = *(const bf16x8*)(hbf_t + (size_t)d1 * 128 + sub * 8);
            sev += ev0 + ev1;
#pragma unroll
            for (int i = 0; i < 8; i++) {
                acc[i] = fmaf(ev0, bf2f((unsigned short)h0[i]), acc[i]);
                acc[i] = fmaf(ev1, bf2f((unsigned short)h1[i]), acc[i]);
            }
        }
        if (p < p1) {
            int d = cdst[p];
            float ev = ebufC[p];
            bf16x8 hv = *(const bf16x8*)(hbf_t + (size_t)d * 128 + sub * 8);
            sev += ev;
#pragma unroll
            for (int i = 0; i < 8; i++) acc[i] = fmaf(ev, bf2f((unsigned short)hv[i]), acc[i]);
        }
        float inv = 1.0f / (sev + 1e-16f);
#pragma unroll
        for (int i = 0; i < 8; i++) T[r16][sub * 8 + i] = acc[i] * inv;
    }
    __syncthreads();
    int w = tid >> 6, lane = tid & 63, lr = lane & 15, lg = lane >> 4;
    int col0 = w * 32 + lr, col1 = col0 + 16;
    int j = tid & 127, half = tid >> 7;
    {
        bf16x8 ahi[4], alo[4];
#pragma unroll
        for (int k = 0; k < 4; k++) mk_split(&T[lr][k * 32 + lg * 8], ahi[k], alo[k]);
        const unsigned short* wh0 = Whi + (size_t)col0 * 128 + lg * 8;
        const unsigned short* wl0 = Wlo + (size_t)col0 * 128 + lg * 8;
        const unsigned short* wh1 = Whi + (size_t)col1 * 128 + lg * 8;
        const unsigned short* wl1 = Wlo + (size_t)col1 * 128 + lg * 8;
        f32x4 a0 = {0.f, 0.f, 0.f, 0.f}, a1 = {0.f, 0.f, 0.f, 0.f};
#pragma unroll
        for (int k = 0; k < 4; k++) {
            bf16x8 bh = *(const bf16x8*)(wh0 + k * 32), bl = *(const bf16x8*)(wl0 + k * 32);
            a0 = MFMA(ahi[k], bh, a0, 0, 0, 0);
            a0 = MFMA(alo[k], bh, a0, 0, 0, 0);
            a0 = MFMA(ahi[k], bl, a0, 0, 0, 0);
            bh = *(const bf16x8*)(wh1 + k * 32); bl = *(const bf16x8*)(wl1 + k * 32);
            a1 = MFMA(ahi[k], bh, a1, 0, 0, 0);
            a1 = MFMA(alo[k], bh, a1, 0, 0, 0);
            a1 = MFMA(ahi[k], bl, a1, 0, 0, 0);
        }
#pragma unroll
        for (int i = 0; i < 4; i++) {
            int r = lg * 4 + i;
            T2[r][col0] = a0[i] + ob_t[col0];
            T2[r][col1] = a1[i] + ob_t[col1];
        }
    }
    __syncthreads();
    {
        int gr = tid >> 4, l16 = tid & 15;
        float sm = 0.0f, sq = 0.0f;
#pragma unroll
        for (int i = 0; i < 8; i++) {
            float v = T2[gr][l16 + 16 * i];
            sm += v; sq += v * v;
        }
#pragma unroll
        for (int m = 1; m < 16; m <<= 1) { sm += __shfl_xor(sm, m); sq += __shfl_xor(sq, m); }
        if (l16 == 0) {
            float mean = sm * (1.0f / 128.0f);
            float var = sq * (1.0f / 128.0f) - mean * mean;
            mu16[gr] = mean;
            rs16[gr] = rsqrtf(var + 1e-5f);
        }
    }
    __syncthreads();
    {
        float gj = g_t[j], bb = bln_t[j];
#pragma unroll
        for (int r = 0; r < 8; r++) {
            int rr = half * 8 + r;
            float v = fmaxf((T2[rr][j] - mu16[rr]) * rs16[rr] * gj + bb, 0.0f);
            emb[(row0 + rr) * 128 + j] = v;
            T2[rr][j] = v;
        }
    }
    __syncthreads();
    {
        bf16x8 ah[4];
#pragma unroll
        for (int k = 0; k < 4; k++) ah[k] = mk_hi(&T2[lr][k * 32 + lg * 8]);
        const unsigned short* wh0 = Shi + (size_t)col0 * 128 + lg * 8;
        const unsigned short* wh1 = Shi + (size_t)col1 * 128 + lg * 8;
        f32x4 a0 = {0.f, 0.f, 0.f, 0.f}, a1 = {0.f, 0.f, 0.f, 0.f};
#pragma unroll
        for (int k = 0; k < 4; k++) {
            a0 = MFMA(ah[k], *(const bf16x8*)(wh0 + k * 32), a0, 0, 0, 0);
            a1 = MFMA(ah[k], *(const bf16x8*)(wh1 + k * 32), a1, 0, 0, 0);
        }
        float b0 = sb1[col0], b1v = sb1[col1], w20 = sW2[col0], w21 = sW2[col1];
#pragma unroll
        for (int i = 0; i < 4; i++) {
            int r = lg * 4 + i;
            float v = tanhf_fast(a0[i] + b0) * w20 + tanhf_fast(a1[i] + b1v) * w21;
            v += __shfl_xor(v, 1);
            v += __shfl_xor(v, 2);
            v += __shfl_xor(v, 4);
            v += __shfl_xor(v, 8);
            if (lr == 0) part[w][r] = v;
        }
    }
    __syncthreads();
    if (tid < 16)
        scores[(row0 + tid) * 2 + t] = part[0][tid] + part[1][tid] + part[2][tid] + part[3][tid] + eb2[t];
}

// ---------------- TAIL-B1 ----------------
__global__ __launch_bounds__(256) void k_tailB1(const float* __restrict__ emb0,
                                                const float* __restrict__ emb1,
                                                const float* __restrict__ scores,
                                                const unsigned short* __restrict__ Fhi,
                                                const unsigned short* __restrict__ Flo,
                                                const float* __restrict__ eob,
                                                const float* __restrict__ elg,
                                                const float* __restrict__ elb,
                                                float* __restrict__ fused2) {
    __shared__ __align__(16) float T[16][132];
    __shared__ __align__(16) float T2[16][132];
    __shared__ float mu16[16], rs16[16], w0s[16], w1s[16];
    int tid = threadIdx.x;
    long row0 = (long)blockIdx.x * 16;
    if (tid < 16) {
        long r = row0 + tid;
        float s0 = scores[r * 2], s1 = scores[r * 2 + 1];
        float mx = fmaxf(s0, s1);
        float e0 = __expf(s0 - mx), e1 = __expf(s1 - mx);
        float inv = 1.0f / (e0 + e1);
        w0s[tid] = e0 * inv;
        w1s[tid] = e1 * inv;
    }
    __syncthreads();
#pragma unroll
    for (int i = 0; i < 8; i++) {
        int idx = tid + i * 256;
        int r = idx >> 7, c = idx & 127;
        T[r][c] = w0s[r] * emb0[(row0 + r) * 128 + c] + w1s[r] * emb1[(row0 + r) * 128 + c];
    }
    __syncthreads();
    int w = tid >> 6, lane = tid & 63, lr = lane & 15, lg = lane >> 4;
    int col0 = w * 32 + lr, col1 = col0 + 16;
    int j = tid & 127, half = tid >> 7;
    {
        bf16x8 ahi[4], alo[4];
#pragma unroll
        for (int k = 0; k < 4; k++) mk_split(&T[lr][k * 32 + lg * 8], ahi[k], alo[k]);
        const unsigned short* wh0 = Fhi + (size_t)col0 * 128 + lg * 8;
        const unsigned short* wl0 = Flo + (size_t)col0 * 128 + lg * 8;
        const unsigned short* wh1 = Fhi + (size_t)col1 * 128 + lg * 8;
        const unsigned short* wl1 = Flo + (size_t)col1 * 128 + lg * 8;
        f32x4 a0 = {0.f, 0.f, 0.f, 0.f}, a1 = {0.f, 0.f, 0.f, 0.f};
#pragma unroll
        for (int k = 0; k < 4; k++) {
            bf16x8 bh = *(const bf16x8*)(wh0 + k * 32), bl = *(const bf16x8*)(wl0 + k * 32);
            a0 = MFMA(ahi[k], bh, a0, 0, 0, 0);
            a0 = MFMA(alo[k], bh, a0, 0, 0, 0);
            a0 = MFMA(ahi[k], bl, a0, 0, 0, 0);
            bh = *(const bf16x8*)(wh1 + k * 32); bl = *(const bf16x8*)(wl1 + k * 32);
            a1 = MFMA(ahi[k], bh, a1, 0, 0, 0);
            a1 = MFMA(alo[k], bh, a1, 0, 0, 0);
            a1 = MFMA(ahi[k], bl, a1, 0, 0, 0);
        }
#pragma unroll
        for (int i = 0; i < 4; i++) {
            int r = lg * 4 + i;
            T2[r][col0] = a0[i] + eob[col0];
            T2[r][col1] = a1[i] + eob[col1];
        }
    }
    __syncthreads();
    {
        int gr = tid >> 4, l16 = tid & 15;
        float sm = 0.0f, sq = 0.0f;
#pragma unroll
        for (int i = 0; i < 8; i++) {
            float v = T2[gr][l16 + 16 * i];
            sm += v; sq += v * v;
        }
#pragma unroll
        for (int m = 1; m < 16; m <<= 1) { sm += __shfl_xor(sm, m); sq += __shfl_xor(sq, m); }
        if (l16 == 0) {
            float mean = sm * (1.0f / 128.0f);
            float var = sq * (1.0f / 128.0f) - mean * mean;
            mu16[gr] = mean;
            rs16[gr] = rsqrtf(var + 1e-5f);
        }
    }
    __syncthreads();
    {
        float gj = elg[j], bb = elb[j];
#pragma unroll
        for (int r = 0; r < 8; r++) {
            int rr = half * 8 + r;
            float v = fmaxf((T2[rr][j] - mu16[rr]) * rs16[rr] * gj + bb, 0.0f);
            fused2[(row0 + rr) * 128 + j] = v;
        }
    }
}

// ---------------- FSUM ----------------
__global__ __launch_bounds__(256) void k_fsum(const float* __restrict__ fused2,
                                              const int* __restrict__ lev,
                                              float* __restrict__ fsumg) {
    __shared__ float ls[2][4][128];
    int tid = threadIdx.x, half = tid >> 7, j = tid & 127;
#pragma unroll
    for (int l = 0; l < 4; l++) ls[half][l][j] = 0.0f;
    __syncthreads();
    for (long row = (long)blockIdx.x * 2 + half; row < NN; row += (long)gridDim.x * 2) {
        int l = lev[row];
        ls[half][l][j] += fused2[row * 128 + j];
    }
    __syncthreads();
    if (half == 0) {
#pragma unroll
        for (int l = 0; l < 4; l++) atomicAdd(&fsumg[l * 128 + j], ls[0][l][j] + ls[1][l][j]);
    }
}

// ---------------- FIN2 ----------------
__global__ void k_fin2(const float* __restrict__ fsum, const int* __restrict__ cnt4,
                       const float* __restrict__ hpW, const float* __restrict__ hpb,
                       const float* __restrict__ W1b, const float* __restrict__ b1,
                       float* __restrict__ lmean, float* __restrict__ lmw) {
    __shared__ float fs[128];
    __shared__ float lml[128];
    int l = blockIdx.x, j = threadIdx.x;
    fs[j] = fsum[l * 128 + j];
    __syncthreads();
    float c = (float)cnt4[l];
    float a = c * hpb[l * 128 + j];
    const float* wp = hpW + (size_t)l * 16384;
    for (int k = 0; k < 128; k++) a = fmaf(fs[k], wp[k * 128 + j], a);
    float cm = c < 1.0f ? 1.0f : c;
    float v = a / cm;
    lmean[l * 128 + j] = v;
    lml[j] = v;
    __syncthreads();
    float b = b1[j];
    for (int k = 0; k < 128; k++) b = fmaf(lml[k], W1b[k * 128 + j], b);
    lmw[l * 128 + j] = b;
}

// ---------------- TAIL-CD2 (level-bucketed) ----------------
__global__ __launch_bounds__(256) void k_tailCD2(const float* __restrict__ fused2,
                                                 const int* __restrict__ perm,
                                                 const int* __restrict__ cnt4,
                                                 const int* __restrict__ off4,
                                                 const int* __restrict__ boff5,
                                                 const unsigned short* __restrict__ QWhi,
                                                 const unsigned short* __restrict__ QWlo,
                                                 const float* __restrict__ qb,
                                                 const float* __restrict__ lmw,
                                                 const float* __restrict__ lmean,
                                                 const float* __restrict__ hW2,
                                                 const unsigned short* __restrict__ Ohi,
                                                 const unsigned short* __restrict__ Olo,
                                                 const float* __restrict__ hob,
                                                 const float* __restrict__ hlg,
                                                 const float* __restrict__ hlb,
                                                 float* __restrict__ out) {
    __shared__ __align__(16) float T[16][132];
    __shared__ __align__(16) float T2[16][132];
    __shared__ float lm[4][128];
    __shared__ float lmwS[4][128];
    __shared__ float w2S[128];
    __shared__ float scS[16][4];
    __shared__ float aw[16][4];
    __shared__ float mu16[16], rs16[16];
    __shared__ int idx16[16];
    int tid = threadIdx.x;
    int b = blockIdx.x;
    if (b >= boff5[4]) return;
    int l = (b >= boff5[3]) ? 3 : (b >= boff5[2]) ? 2 : (b >= boff5[1]) ? 1 : 0;
    int bi = b - boff5[l];
    int base = off4[l] + bi * 16;
    int last = off4[l] + cnt4[l] - 1;
    if (tid < 16) {
        int gp = base + tid;
        if (gp > last) gp = last;
        idx16[tid] = perm[gp];
    }
    for (int idx = tid; idx < 512; idx += 256) {
        lm[idx >> 7][idx & 127] = lmean[idx];
        lmwS[idx >> 7][idx & 127] = lmw[idx];
    }
    if (tid < 128) w2S[tid] = hW2[tid];
    __syncthreads();
#pragma unroll
    for (int i = 0; i < 8; i++) {
        int idx = tid + i * 256;
        int r = idx >> 7, c = idx & 127;
        T[r][c] = fused2[(size_t)idx16[r] * 128 + c];
    }
    __syncthreads();
    int w = tid >> 6, lane = tid & 63, lr = lane & 15, lg = lane >> 4;
    int col0 = w * 32 + lr, col1 = col0 + 16;
    int j = tid & 127, half = tid >> 7;
    {
        bf16x8 ahi[4], alo[4];
#pragma unroll
        for (int k = 0; k < 4; k++) mk_split(&T[lr][k * 32 + lg * 8], ahi[k], alo[k]);
        const unsigned short* wh0 = QWhi + (size_t)l * 16384 + (size_t)col0 * 128 + lg * 8;
        const unsigned short* wl0 = QWlo + (size_t)l * 16384 + (size_t)col0 * 128 + lg * 8;
        const unsigned short* wh1 = QWhi + (size_t)l * 16384 + (size_t)col1 * 128 + lg * 8;
        const unsigned short* wl1 = QWlo + (size_t)l * 16384 + (size_t)col1 * 128 + lg * 8;
        f32x4 a0 = {0.f, 0.f, 0.f, 0.f}, a1 = {0.f, 0.f, 0.f, 0.f};
#pragma unroll
        for (int k = 0; k < 4; k++) {
            bf16x8 bh = *(const bf16x8*)(wh0 + k * 32), bl = *(const bf16x8*)(wl0 + k * 32);
            a0 = MFMA(ahi[k], bh, a0, 0, 0, 0);
            a0 = MFMA(alo[k], bh, a0, 0, 0, 0);
            a0 = MFMA(ahi[k], bl, a0, 0, 0, 0);
            bh = *(const bf16x8*)(wh1 + k * 32); bl = *(const bf16x8*)(wl1 + k * 32);
            a1 = MFMA(ahi[k], bh, a1, 0, 0, 0);
            a1 = MFMA(alo[k], bh, a1, 0, 0, 0);
            a1 = MFMA(ahi[k], bl, a1, 0, 0, 0);
        }
#pragma unroll
        for (int i = 0; i < 4; i++) {
            int r = lg * 4 + i;
            T2[r][col0] = a0[i] + qb[l * 128 + col0];
            T2[r][col1] = a1[i] + qb[l * 128 + col1];
        }
    }
    __syncthreads();
    {
        int p = tid >> 2, sub = tid & 3;
        int pr = p & 15, pl = p >> 4;
        float s = 0.0f;
#pragma unroll
        for (int jj = 0; jj < 32; jj++) {
            int j2 = sub + 4 * jj;
            s += tanhf_fast(T2[pr][j2] + lmwS[pl][j2]) * w2S[j2];
        }
        s += __shfl_xor(s, 1);
        s += __shfl_xor(s, 2);
        if (sub == 0) scS[pr][pl] = s;
    }
    __syncthreads();
    if (tid < 16) {
        float sc[4];
        float mx = -1e30f;
#pragma unroll
        for (int ll = 0; ll < 4; ll++) {
            sc[ll] = scS[tid][ll];
            mx = fmaxf(mx, sc[ll]);
        }
        float s = 0.0f;
#pragma unroll
        for (int ll = 0; ll < 4; ll++) { sc[ll] = __expf(sc[ll] - mx); s += sc[ll]; }
        float inv = 1.0f / s;
#pragma unroll
        for (int ll = 0; ll < 4; ll++) aw[tid][ll] = sc[ll] * inv;
    }
    __syncthreads();
#pragma unroll
    for (int r = 0; r < 8; r++) {
        int rr = half * 8 + r;
        float e = 0.0f;
#pragma unroll
        for (int ll = 0; ll < 4; ll++) e = fmaf(aw[rr][ll], lm[ll][j], e);
        T[rr][j] = e;
    }
    __syncthreads();
    {
        bf16x8 ahi[4], alo[4];
#pragma unroll
        for (int k = 0; k < 4; k++) mk_split(&T[lr][k * 32 + lg * 8], ahi[k], alo[k]);
        const unsigned short* wh0 = Ohi + (size_t)col0 * 128 + lg * 8;
        const unsigned short* wl0 = Olo + (size_t)col0 * 128 + lg * 8;
        const unsigned short* wh1 = Ohi + (size_t)col1 * 128 + lg * 8;
        const unsigned short* wl1 = Olo + (size_t)col1 * 128 + lg * 8;
        f32x4 a0 = {0.f, 0.f, 0.f, 0.f}, a1 = {0.f, 0.f, 0.f, 0.f};
#pragma unroll
        for (int k = 0; k < 4; k++) {
            bf16x8 bh = *(const bf16x8*)(wh0 + k * 32), bl = *(const bf16x8*)(wl0 + k * 32);
            a0 = MFMA(ahi[k], bh, a0, 0, 0, 0);
            a0 = MFMA(alo[k], bh, a0, 0, 0, 0);
            a0 = MFMA(ahi[k], bl, a0, 0, 0, 0);
            bh = *(const bf16x8*)(wh1 + k * 32); bl = *(const bf16x8*)(wl1 + k * 32);
            a1 = MFMA(ahi[k], bh, a1, 0, 0, 0);
            a1 = MFMA(alo[k], bh, a1, 0, 0, 0);
            a1 = MFMA(ahi[k], bl, a1, 0, 0, 0);
        }
#pragma unroll
        for (int i = 0; i < 4; i++) {
            int r = lg * 4 + i;
            T2[r][col0] = a0[i] + hob[col0];
            T2[r][col1] = a1[i] + hob[col1];
        }
    }
    __syncthreads();
    {
        int gr = tid >> 4, l16 = tid & 15;
        float sm = 0.0f, sq = 0.0f;
#pragma unroll
        for (int i = 0; i < 8; i++) {
            float v = T2[gr][l16 + 16 * i];
            sm += v; sq += v * v;
        }
#pragma unroll
        for (int m = 1; m < 16; m <<= 1) { sm += __shfl_xor(sm, m); sq += __shfl_xor(sq, m); }
        if (l16 == 0) {
            float mean = sm * (1.0f / 128.0f);
            float var = sq * (1.0f / 128.0f) - mean * mean;
            mu16[gr] = mean;
            rs16[gr] = rsqrtf(var + 1e-5f);
        }
    }
    __syncthreads();
    {
        float gj = hlg[j], bb = hlb[j];
#pragma unroll
        for (int r = 0; r < 8; r++) {
            int rr = half * 8 + r;
            float v = (T2[rr][j] - mu16[rr]) * rs16[rr] * gj + bb;
            out[(size_t)idx16[rr] * 128 + j] = fmaxf(v, 0.0f);
        }
    }
}

extern "C" void kernel_launch(void* const* d_in, const int* in_sizes, int n_in,
                              void* d_out, int out_size, void* d_ws, size_t ws_size,
                              hipStream_t stream) {
    const float* nf  = (const float*)d_in[0];
    const float* ef  = (const float*)d_in[1];
    const int*   lev = (const int*)d_in[2];
    const int*   ei  = (const int*)d_in[3];
    const float* nlW = (const float*)d_in[4];
    const float* nlb = (const float*)d_in[5];
    const float* neW = (const float*)d_in[6];
    const float* neb = (const float*)d_in[7];
    const float* aW1 = (const float*)d_in[8];
    const float* ab1 = (const float*)d_in[9];
    const float* aW2 = (const float*)d_in[10];
    const float* ab2 = (const float*)d_in[11];
    const float* oW  = (const float*)d_in[12];
    const float* ob  = (const float*)d_in[13];
    const float* lng = (const float*)d_in[14];
    const float* lnb = (const float*)d_in[15];
    const float* eW1 = (const float*)d_in[16];
    const float* eb1 = (const float*)d_in[17];
    const float* eW2 = (const float*)d_in[18];
    const float* eb2 = (const float*)d_in[19];
    const float* eoW = (const float*)d_in[20];
    const float* eob = (const float*)d_in[21];
    const float* elg = (const float*)d_in[22];
    const float* elb = (const float*)d_in[23];
    const float* hpW = (const float*)d_in[24];
    const float* hpb = (const float*)d_in[25];
    const float* hW1 = (const float*)d_in[26];
    const float* hb1 = (const float*)d_in[27];
    const float* hW2 = (const float*)d_in[28];
    const float* hb2 = (const float*)d_in[29];
    const float* hoW = (const float*)d_in[30];
    const float* hob = (const float*)d_in[31];
    const float* hlg = (const float*)d_in[32];
    const float* hlb = (const float*)d_in[33];

    float* ws = (float*)d_ws;
    size_t NH = (size_t)NN * 128;
    float* fused2 = ws;                       // NH
    float* emb0   = fused2 + NH;              // NH
    float* emb1   = emb0 + NH;                // NH
    float* ebuf2  = emb1 + NH;                // 2*EE
    float* scores = ebuf2 + 2 * (size_t)EE;   // 2*NN
    float* beff2  = scores + (size_t)2 * NN;  // 256
    float* fsum   = beff2 + 256;              // 512
    float* lmean  = fsum + 512;               // 512
    float* lmw    = lmean + 512;              // 512
    float* qb     = lmw + 512;                // 512
    unsigned short* U2    = (unsigned short*)(qb + 512);  // 2*NH
    unsigned short* V2    = U2 + 2 * NH;                  // 2*NH
    unsigned short* hbf2  = V2 + 2 * NH;                  // 2*NH
    unsigned short* WhT2  = hbf2 + 2 * NH;                // 2*16384
    unsigned short* WUT2  = WhT2 + 2 * 16384;
    unsigned short* WVT2  = WUT2 + 2 * 16384;
    unsigned short* WET2  = WVT2 + 2 * 16384;             // 2*8192
    unsigned short* twhi  = WET2 + 2 * 8192;              // 6*16384
    unsigned short* twlo  = twhi + 6 * 16384;             // 6*16384
    unsigned short* QWhi  = twlo + 6 * 16384;             // 4*16384
    unsigned short* QWlo  = QWhi + 4 * 16384;             // 4*16384
    int* perm    = (int*)(QWlo + 4 * 16384);              // NN
    int* cnt4    = perm + NN;
    int* off4    = cnt4 + 4;
    int* boff5   = off4 + 4;
    int* cursorL = boff5 + 5;
    int* deg2    = cursorL + 4;          // 2*NN
    int* rowptr2 = deg2 + 2 * NN;        // 2*NN+1
    int* cursor2 = rowptr2 + 2 * NN + 1; // 2*NN
    int* stmp    = cursor2 + 2 * NN;     // 2*NN
    int* sbsum   = stmp + 2 * NN;        // 512
    int* sboff   = sbsum + 512;          // 512
    int* epos2   = sboff + 512;          // 2*EE
    int* cdst2   = epos2 + 2 * EE;       // 2*EE
    float* out = (float*)d_out;

    WSrc ps;
    ps.s[0] = oW;
    ps.s[1] = oW + 16384;
    ps.s[2] = eW1;
    ps.s[3] = eW1 + 16384;
    ps.s[4] = eoW;
    ps.s[5] = hoW;

    const int NB_E = (EE + 63) / 64;     // 7813
    const int NB_N = NN / 16;            // 6250
    const int SCB = (2 * NN + 511) / 512; // 391

    // level bucketing
    k_zeroi<<<1, 4, 0, stream>>>(cnt4, 4);
    k_count<<<128, 256, 0, stream>>>(lev, cnt4);
    k_scan<<<1, 1, 0, stream>>>(cnt4, off4, boff5, cursorL);
    k_scatter<<<125, 256, 0, stream>>>(lev, cursorL, perm);

    // weight prep
    k_prep_tail<<<6 * 64, 256, 0, stream>>>(ps, twhi, twlo);
    k_prep_q<<<258, 256, 0, stream>>>(hpW, hpb, hW1, QWhi, QWlo, qb);
    k_zero<<<1, 512, 0, stream>>>(fsum, (size_t)512);

    // CSR build (both relations at once)
    k_zeroi<<<(2 * NN + 255) / 256, 256, 0, stream>>>(deg2, 2 * NN);
    k_hist2<<<(2 * EE + 255) / 256, 256, 0, stream>>>(ei, deg2);
    k_scan1<<<SCB, 512, 0, stream>>>(deg2, stmp, sbsum);
    k_scan2<<<1, 512, 0, stream>>>(sbsum, sboff, SCB);
    k_scan3<<<SCB, 512, 0, stream>>>(deg2, stmp, sboff, rowptr2, cursor2);
    k_csr_scatter2<<<(2 * EE + 255) / 256, 256, 0, stream>>>(ei, cursor2, epos2, cdst2);

    // head (both t, one nf pass)
    k_prep_head2<<<256, 128, 0, stream>>>(nlW, nlb, aW1, ab1, neW, neb,
                                          WhT2, WUT2, WVT2, WET2, beff2);
    k_head2<<<NB_N, 256, 0, stream>>>(nf, WhT2, WUT2, WVT2, nlb, hbf2, U2, V2);

    // edge scores (both t)
    k_edge3b<<<2 * NB_E, 256, 0, stream>>>(ef, ei, epos2, WET2, U2, V2, beff2,
                                           aW2, ab2, ebuf2, NB_E);
    // aggregation + relation tail (both t)
    k_tailA2b<<<2 * NB_N, 256, 0, stream>>>(rowptr2, cdst2, ebuf2, hbf2, twhi, twlo,
                                            ob, lng, lnb, eb1, eW2, eb2,
                                            emb0, emb1, scores, NB_N);

    k_tailB1<<<NB_N, 256, 0, stream>>>(emb0, emb1, scores,
                                       twhi + (size_t)4 * 16384, twlo + (size_t)4 * 16384,
                                       eob, elg, elb, fused2);
    k_fsum<<<256, 256, 0, stream>>>(fused2, lev, fsum);
    k_fin2<<<4, 128, 0, stream>>>(fsum, cnt4, hpW, hpb, hW1 + 16384, hb1, lmean, lmw);
    k_tailCD2<<<NB_N + 4, 256, 0, stream>>>(fused2, perm, cnt4, off4, boff5,
                                            QWhi, QWlo, qb, lmw, lmean, hW2,
                                            twhi + (size_t)5 * 16384, twlo + (size_t)5 * 16384,
                                            hob, hlg, hlb, out);
}

// Round 10
// 955.521 us; speedup vs baseline: 1.7358x; 1.0069x over previous
//
#include <hip/hip_runtime.h>
#include <math.h>

#define NN 100000
#define EE 500000
#define NH_C (NN * 128)
#define EBLK 32
// D=H=128, ED=64, T=2, L=4

typedef __attribute__((ext_vector_type(8))) short bf16x8;
typedef __attribute__((ext_vector_type(4))) float f32x4;
#define MFMA __builtin_amdgcn_mfma_f32_16x16x32_bf16

__device__ inline short f2bf(float x) {
    union { float f; unsigned u; } v; v.f = x;
    unsigned r = v.u + 0x7FFF + ((v.u >> 16) & 1);
    return (short)(r >> 16);
}
__device__ inline float bf2f(unsigned short h) {
    union { unsigned u; float f; } v; v.u = ((unsigned)h) << 16; return v.f;
}
__device__ inline float tanhf_fast(float x) {
    float e = __expf(2.0f * x);
    return 1.0f - 2.0f * __builtin_amdgcn_rcpf(e + 1.0f);
}

__device__ inline bf16x8 mk_hi(const float* p) {
    float4 a = *(const float4*)p, b = *(const float4*)(p + 4);
    float v[8] = {a.x, a.y, a.z, a.w, b.x, b.y, b.z, b.w};
    bf16x8 h;
#pragma unroll
    for (int i = 0; i < 8; i++) h[i] = f2bf(v[i]);
    return h;
}
__device__ inline bf16x8 mk_hi8(float4 a, float4 b) {
    float v[8] = {a.x, a.y, a.z, a.w, b.x, b.y, b.z, b.w};
    bf16x8 h;
#pragma unroll
    for (int i = 0; i < 8; i++) h[i] = f2bf(v[i]);
    return h;
}
__device__ inline void mk_split(const float* p, bf16x8& hi, bf16x8& lo) {
    float4 a = *(const float4*)p, b = *(const float4*)(p + 4);
    float v[8] = {a.x, a.y, a.z, a.w, b.x, b.y, b.z, b.w};
#pragma unroll
    for (int i = 0; i < 8; i++) {
        short h = f2bf(v[i]);
        hi[i] = h;
        lo[i] = f2bf(v[i] - bf2f((unsigned short)h));
    }
}

// ---------------- zero fill ----------------
__global__ void k_zero(float* __restrict__ p, size_t n) {
    size_t i = (size_t)blockIdx.x * blockDim.x + threadIdx.x;
    size_t stride = (size_t)gridDim.x * blockDim.x;
    for (; i < n; i += stride) p[i] = 0.0f;
}
__global__ void k_zeroi(int* __restrict__ p, int n) {
    int i = blockIdx.x * blockDim.x + threadIdx.x;
    if (i < n) p[i] = 0;
}

// ---------------- CSR build (both relations, concatenated) ----------------
__global__ __launch_bounds__(256) void k_hist2(const int* __restrict__ ei, int* __restrict__ deg2) {
    long g = (long)blockIdx.x * 256 + threadIdx.x;
    if (g < 2L * EE) {
        int t = g >= EE;
        long le = g - (long)t * EE;
        int s = ei[(size_t)t * 2 * EE + le];
        atomicAdd(&deg2[t * NN + s], 1);
    }
}
__global__ __launch_bounds__(512) void k_scan1(const int* __restrict__ deg,
                                               int* __restrict__ tmp, int* __restrict__ bsum) {
    __shared__ int sh[2][512];
    int b = blockIdx.x, tid = threadIdx.x;
    int i = b * 512 + tid;
    int v = (i < 2 * NN) ? deg[i] : 0;
    int cur = 0;
    sh[0][tid] = v;
    __syncthreads();
    for (int off = 1; off < 512; off <<= 1) {
        int nxt = cur ^ 1;
        int a = sh[cur][tid];
        if (tid >= off) a += sh[cur][tid - off];
        sh[nxt][tid] = a;
        __syncthreads();
        cur = nxt;
    }
    int incl = sh[cur][tid];
    if (i < 2 * NN) tmp[i] = incl;
    if (tid == 511) bsum[b] = incl;
}
__global__ __launch_bounds__(512) void k_scan2(const int* __restrict__ bsum, int* __restrict__ boff,
                                               int nB) {
    __shared__ int sh[2][512];
    int tid = threadIdx.x;
    int v = (tid < nB) ? bsum[tid] : 0;
    int cur = 0;
    sh[0][tid] = v;
    __syncthreads();
    for (int off = 1; off < 512; off <<= 1) {
        int nxt = cur ^ 1;
        int a = sh[cur][tid];
        if (tid >= off) a += sh[cur][tid - off];
        sh[nxt][tid] = a;
        __syncthreads();
        cur = nxt;
    }
    boff[tid] = sh[cur][tid] - v;
}
__global__ __launch_bounds__(512) void k_scan3(const int* __restrict__ deg,
                                               const int* __restrict__ tmp,
                                               const int* __restrict__ boff,
                                               int* __restrict__ rowptr, int* __restrict__ cursor) {
    int i = blockIdx.x * 512 + threadIdx.x;
    if (i < 2 * NN) {
        int r = tmp[i] - deg[i] + boff[blockIdx.x];
        rowptr[i] = r;
        cursor[i] = r;
    }
    if (i == 0) rowptr[2 * NN] = 2 * EE;
}
__global__ __launch_bounds__(256) void k_csr_scatter2(const int* __restrict__ ei,
                                                      int* __restrict__ cursor,
                                                      int* __restrict__ epos,
                                                      int* __restrict__ cdst) {
    long g = (long)blockIdx.x * 256 + threadIdx.x;
    if (g < 2L * EE) {
        int t = g >= EE;
        long le = g - (long)t * EE;
        int s = ei[(size_t)t * 2 * EE + le];
        int d = ei[(size_t)t * 2 * EE + EE + le];
        int p = atomicAdd(&cursor[t * NN + s], 1);
        epos[g] = p;
        cdst[p] = d;
    }
}

// ---------------- level bucketing ----------------
__global__ __launch_bounds__(256) void k_count(const int* __restrict__ lev, int* __restrict__ cnt4) {
    __shared__ int lc[4];
    int tid = threadIdx.x;
    if (tid < 4) lc[tid] = 0;
    __syncthreads();
    for (long n = (long)blockIdx.x * 256 + tid; n < NN; n += (long)gridDim.x * 256)
        atomicAdd(&lc[lev[n]], 1);
    __syncthreads();
    if (tid < 4 && lc[tid]) atomicAdd(&cnt4[tid], lc[tid]);
}

__global__ void k_scan(const int* __restrict__ cnt4, int* __restrict__ off4,
                       int* __restrict__ boff5, int* __restrict__ cursor) {
    int o = 0, b = 0;
    for (int l = 0; l < 4; l++) {
        off4[l] = o; cursor[l] = o; boff5[l] = b;
        o += cnt4[l];
        b += (cnt4[l] + 15) >> 4;
    }
    boff5[4] = b;
}

__global__ __launch_bounds__(256) void k_scatter(const int* __restrict__ lev,
                                                 int* __restrict__ cursor,
                                                 int* __restrict__ perm) {
    __shared__ int lc[4], lb[4], lc2[4];
    int tid = threadIdx.x;
    if (tid < 4) { lc[tid] = 0; lc2[tid] = 0; }
    __syncthreads();
    int start = blockIdx.x * 800, end = start + 800;
    if (end > NN) end = NN;
    for (int n = start + tid; n < end; n += 256) atomicAdd(&lc[lev[n]], 1);
    __syncthreads();
    if (tid < 4 && lc[tid]) lb[tid] = atomicAdd(&cursor[tid], lc[tid]);
    __syncthreads();
    for (int n = start + tid; n < end; n += 256) {
        int l = lev[n];
        int p = atomicAdd(&lc2[l], 1);
        perm[lb[l] + p] = n;
    }
}

// ---------------- prep head (both t): WhT2, WUT2, WVT2, WET2 (bf16 T), beff2 ----------------
__global__ void k_prep_head2(const float* __restrict__ nlW, const float* __restrict__ nlb,
                             const float* __restrict__ aW1, const float* __restrict__ ab1,
                             const float* __restrict__ neW, const float* __restrict__ neb,
                             unsigned short* __restrict__ WhT2, unsigned short* __restrict__ WUT2,
                             unsigned short* __restrict__ WVT2, unsigned short* __restrict__ WET2,
                             float* __restrict__ beff2) {
    __shared__ float red[2];
    int t = blockIdx.x >> 7, j = blockIdx.x & 127, k = threadIdx.x;
    const float* Wn = nlW + (size_t)t * 16384;
    const float* bn = nlb + t * 128;
    const float* W1 = aW1 + (size_t)t * 384 * 128;
    const float* b1 = ab1 + t * 128;
    const float* We = neW + (size_t)t * 64 * 128;
    const float* be = neb + t * 128;
    WhT2[(size_t)t * 16384 + j * 128 + k] = (unsigned short)f2bf(Wn[k * 128 + j]);
    float su = 0.0f, sv = 0.0f;
    for (int m = 0; m < 128; m++) {
        float wkm = Wn[k * 128 + m];
        su = fmaf(wkm, W1[m * 128 + j], su);
        sv = fmaf(wkm, W1[(128 + m) * 128 + j], sv);
    }
    WUT2[(size_t)t * 16384 + j * 128 + k] = (unsigned short)f2bf(su);
    WVT2[(size_t)t * 16384 + j * 128 + k] = (unsigned short)f2bf(sv);
    if (k < 64) {
        float se = 0.0f;
        for (int m = 0; m < 128; m++) se = fmaf(We[k * 128 + m], W1[(256 + m) * 128 + j], se);
        WET2[(size_t)t * 8192 + j * 64 + k] = (unsigned short)f2bf(se);
    }
    float tk = bn[k] * (W1[k * 128 + j] + W1[(128 + k) * 128 + j]) + be[k] * W1[(256 + k) * 128 + j];
#pragma unroll
    for (int o = 32; o > 0; o >>= 1) tk += __shfl_down(tk, o);
    if ((k & 63) == 0) red[k >> 6] = tk;
    __syncthreads();
    if (k == 0) beff2[t * 128 + j] = b1[j] + red[0] + red[1];
}

// ---------------- prep tail: split-bf16 transposed weights (6 mats) ----------------
struct WSrc { const float* s[6]; };
__global__ void k_prep_tail(WSrc ps, unsigned short* __restrict__ hi,
                            unsigned short* __restrict__ lo) {
    int m = blockIdx.x >> 6, blk = blockIdx.x & 63;
    const float* src = ps.s[m];
    unsigned short* h = hi + (size_t)m * 16384;
    unsigned short* l = lo + (size_t)m * 16384;
    int idx = blk * 256 + threadIdx.x;
    int k = idx >> 7, j = idx & 127;
    float v = src[idx];
    short hh = f2bf(v);
    h[j * 128 + k] = (unsigned short)hh;
    l[j * 128 + k] = (unsigned short)f2bf(v - bf2f((unsigned short)hh));
}

// ---------------- prep Q: QW[l] = hpW[l] @ hW1a (T split bf16), qb[l] = hpb[l]@hW1a ----------
__global__ void k_prep_q(const float* __restrict__ hpW, const float* __restrict__ hpb,
                         const float* __restrict__ hW1a,
                         unsigned short* __restrict__ QWhi, unsigned short* __restrict__ QWlo,
                         float* __restrict__ qb) {
    int gidx = blockIdx.x * 256 + threadIdx.x;
    if (gidx < 4 * 16384) {
        int l = gidx >> 14, rem = gidx & 16383;
        int k = rem >> 7, j = rem & 127;
        const float* wr = hpW + (size_t)l * 16384 + (size_t)k * 128;
        float v = 0.0f;
        for (int m = 0; m < 128; m++) v = fmaf(wr[m], hW1a[m * 128 + j], v);
        short hh = f2bf(v);
        QWhi[(size_t)l * 16384 + j * 128 + k] = (unsigned short)hh;
        QWlo[(size_t)l * 16384 + j * 128 + k] = (unsigned short)f2bf(v - bf2f((unsigned short)hh));
    } else {
        int e = gidx - 4 * 16384;
        if (e < 512) {
            int l = e >> 7, j = e & 127;
            float v = 0.0f;
            for (int m = 0; m < 128; m++) v = fmaf(hpb[l * 128 + m], hW1a[m * 128 + j], v);
            qb[l * 128 + j] = v;
        }
    }
}

// ---------------- HEAD2: both t from one nf tile -> hbf,U,V (x2) ----------------
__global__ __launch_bounds__(256) void k_head2(const float* __restrict__ nf,
                                               const unsigned short* __restrict__ WhT2,
                                               const unsigned short* __restrict__ WUT2,
                                               const unsigned short* __restrict__ WVT2,
                                               const float* __restrict__ nlb,
                                               unsigned short* __restrict__ hbf2,
                                               unsigned short* __restrict__ U2,
                                               unsigned short* __restrict__ V2) {
    __shared__ __align__(16) float T[16][132];
    int tid = threadIdx.x;
    long row0 = (long)blockIdx.x * 16;
#pragma unroll
    for (int i = 0; i < 8; i++) {
        int idx = tid + i * 256;
        int r = idx >> 7, c = idx & 127;
        T[r][c] = nf[(row0 + r) * 128 + c];
    }
    __syncthreads();
    int w = tid >> 6, lane = tid & 63, lr = lane & 15, lg = lane >> 4;
    bf16x8 A[4];
#pragma unroll
    for (int k = 0; k < 4; k++) A[k] = mk_hi(&T[lr][k * 32 + lg * 8]);
    int col0 = w * 32 + lr, col1 = col0 + 16;
#pragma unroll
    for (int o = 0; o < 6; o++) {
        const unsigned short* wb =
            (o == 0) ? WhT2 : (o == 1) ? WUT2 : (o == 2) ? WVT2 :
            (o == 3) ? WhT2 + 16384 : (o == 4) ? WUT2 + 16384 : WVT2 + 16384;
        unsigned short* ob =
            (o == 0) ? hbf2 : (o == 1) ? U2 : (o == 2) ? V2 :
            (o == 3) ? hbf2 + NH_C : (o == 4) ? U2 + NH_C : V2 + NH_C;
        const unsigned short* w0 = wb + (size_t)col0 * 128 + lg * 8;
        const unsigned short* w1 = wb + (size_t)col1 * 128 + lg * 8;
        f32x4 a0 = {0.f, 0.f, 0.f, 0.f}, a1 = {0.f, 0.f, 0.f, 0.f};
#pragma unroll
        for (int k = 0; k < 4; k++) {
            a0 = MFMA(A[k], *(const bf16x8*)(w0 + k * 32), a0, 0, 0, 0);
            a1 = MFMA(A[k], *(const bf16x8*)(w1 + k * 32), a1, 0, 0, 0);
        }
        float bb0 = (o == 0) ? nlb[col0] : (o == 3) ? nlb[128 + col0] : 0.0f;
        float bb1 = (o == 0) ? nlb[col1] : (o == 3) ? nlb[128 + col1] : 0.0f;
        unsigned short* op = ob + (size_t)row0 * 128;
#pragma unroll
        for (int i = 0; i < 4; i++) {
            int r = lg * 4 + i;
            op[(size_t)r * 128 + col0] = (unsigned short)f2bf(a0[i] + bb0);
            op[(size_t)r * 128 + col1] = (unsigned short)f2bf(a1[i] + bb1);
        }
    }
}

// ---------------- EDGE4 (both t, EBLK=32): LDS pre=U[s]+V[d]; ef MFMA; ev -> CSR slot ----
__global__ __launch_bounds__(256) void k_edge4(const float* __restrict__ ef,
                                               const int* __restrict__ ei,
                                               const int* __restrict__ epos2,
                                               const unsigned short* __restrict__ WET2,
                                               const unsigned short* __restrict__ U2,
                                               const unsigned short* __restrict__ V2,
                                               const float* __restrict__ beff2,
                                               const float* __restrict__ aW2,
                                               const float* __restrict__ ab2,
                                               float* __restrict__ ebuf2, int NB) {
    __shared__ __align__(16) float pre[EBLK][132];
    __shared__ float part[4][EBLK];
    int tid = threadIdx.x, w = tid >> 6, lane = tid & 63, lr = lane & 15, lg = lane >> 4;
    int t = blockIdx.x >= NB;
    int bi = blockIdx.x - t * NB;
    long e0 = (long)bi * EBLK;
    const float* ef_t = ef + (size_t)t * EE * 64;
    const int* eis = ei + (size_t)t * 2 * EE;
    const int* eid = eis + EE;
    const int* eposT = epos2 + (size_t)t * EE;
    const unsigned short* U_t = U2 + (size_t)t * NH_C;
    const unsigned short* V_t = V2 + (size_t)t * NH_C;
    // ---- stage: 8 threads/edge, diagonal chunk skew to spread LDS banks ----
    {
        int eL = tid >> 3, sub = tid & 7;
        int uch = (sub + eL) & 7;
        long e = e0 + eL;
        int s = eis[e], d = eid[e];
        const unsigned short* up = U_t + (size_t)s * 128 + uch * 16;
        const unsigned short* vp = V_t + (size_t)d * 128 + uch * 16;
        bf16x8 u0 = *(const bf16x8*)up, u1 = *(const bf16x8*)(up + 8);
        bf16x8 v0 = *(const bf16x8*)vp, v1 = *(const bf16x8*)(vp + 8);
        float tv[16];
#pragma unroll
        for (int i = 0; i < 8; i++)
            tv[i] = bf2f((unsigned short)u0[i]) + bf2f((unsigned short)v0[i]);
#pragma unroll
        for (int i = 0; i < 8; i++)
            tv[8 + i] = bf2f((unsigned short)u1[i]) + bf2f((unsigned short)v1[i]);
#pragma unroll
        for (int i = 0; i < 4; i++) {
            float4 f4 = {tv[4 * i], tv[4 * i + 1], tv[4 * i + 2], tv[4 * i + 3]};
            *(float4*)&pre[eL][uch * 16 + 4 * i] = f4;
        }
    }
    int col0 = w * 32 + lr, col1 = col0 + 16;
    bf16x8 B0[2], B1[2];
#pragma unroll
    for (int kk = 0; kk < 2; kk++) {
        B0[kk] = *(const bf16x8*)(WET2 + (size_t)t * 8192 + (size_t)col0 * 64 + kk * 32 + lg * 8);
        B1[kk] = *(const bf16x8*)(WET2 + (size_t)t * 8192 + (size_t)col1 * 64 + kk * 32 + lg * 8);
    }
    float be0 = beff2[t * 128 + col0], be1 = beff2[t * 128 + col1];
    float w20 = aW2[t * 128 + col0], w21 = aW2[t * 128 + col1];
    __syncthreads();
#pragma unroll
    for (int i16 = 0; i16 < 2; i16++) {
        const float* ep = ef_t + (size_t)(e0 + i16 * 16 + lr) * 64 + lg * 8;
        float4 L0 = *(const float4*)ep;
        float4 L1 = *(const float4*)(ep + 4);
        float4 L2 = *(const float4*)(ep + 32);
        float4 L3 = *(const float4*)(ep + 36);
        bf16x8 av0 = mk_hi8(L0, L1);
        bf16x8 av1 = mk_hi8(L2, L3);
        f32x4 a0 = {0.f, 0.f, 0.f, 0.f}, a1 = {0.f, 0.f, 0.f, 0.f};
        a0 = MFMA(av0, B0[0], a0, 0, 0, 0);
        a0 = MFMA(av1, B0[1], a0, 0, 0, 0);
        a1 = MFMA(av0, B1[0], a1, 0, 0, 0);
        a1 = MFMA(av1, B1[1], a1, 0, 0, 0);
#pragma unroll
        for (int q = 0; q < 4; q++) {
            int eL = i16 * 16 + lg * 4 + q;
            float v = tanhf_fast(a0[q] + pre[eL][col0] + be0) * w20 +
                      tanhf_fast(a1[q] + pre[eL][col1] + be1) * w21;
            v += __shfl_xor(v, 1);
            v += __shfl_xor(v, 2);
            v += __shfl_xor(v, 4);
            v += __shfl_xor(v, 8);
            if (lr == 0) part[w][eL] = v;
        }
    }
    __syncthreads();
    if (tid < EBLK) {
        long e = e0 + tid;
        float a = part[0][tid] + part[1][tid] + part[2][tid] + part[3][tid] + ab2[t];
        ebuf2[eposT[e]] = __expf(a);
    }
}

// ---------------- TAIL-A2B (both t): CSR gather (4-way unroll) + GEMM + LN + score ----------
__global__ __launch_bounds__(256) void k_tailA2b(const int* __restrict__ rowptr2,
                                                 const int* __restrict__ cdst,
                                                 const float* __restrict__ ebufC,
                                                 const unsigned short* __restrict__ hbf2,
                                                 const unsigned short* __restrict__ twhi,
                                                 const unsigned short* __restrict__ twlo,
                                                 const float* __restrict__ ob,
                                                 const float* __restrict__ lng,
                                                 const float* __restrict__ lnb,
                                                 const float* __restrict__ eb1,
                                                 const float* __restrict__ eW2,
                                                 const float* __restrict__ eb2,
                                                 float* __restrict__ emb0,
                                                 float* __restrict__ emb1,
                                                 float* __restrict__ scores, int NBn) {
    __shared__ __align__(16) float T[16][132];
    __shared__ __align__(16) float T2[16][132];
    __shared__ float mu16[16], rs16[16], part[4][16];
    int tid = threadIdx.x;
    int t = blockIdx.x >= NBn;
    int bi = blockIdx.x - t * NBn;
    long row0 = (long)bi * 16;
    const int* rowp = rowptr2 + (size_t)t * NN;
    const unsigned short* hbf_t = hbf2 + (size_t)t * NH_C;
    const unsigned short* Whi = twhi + (size_t)t * 16384;
    const unsigned short* Wlo = twlo + (size_t)t * 16384;
    const unsigned short* Shi = twhi + (size_t)(2 + t) * 16384;
    const float* ob_t = ob + t * 128;
    const float* g_t = lng + t * 128;
    const float* bln_t = lnb + t * 128;
    const float* sb1 = eb1 + t * 128;
    const float* sW2 = eW2 + t * 128;
    float* emb = t ? emb1 : emb0;
    // CSR gather: 16 threads/row, 4-way unrolled
    {
        int r16 = tid >> 4, sub = tid & 15;
        long n = row0 + r16;
        int p0 = rowp[n], p1 = rowp[n + 1];
        float acc[8] = {0, 0, 0, 0, 0, 0, 0, 0};
        float sev = 0.0f;
        int p = p0;
        for (; p + 4 <= p1; p += 4) {
            int d0 = cdst[p], d1 = cdst[p + 1], d2 = cdst[p + 2], d3 = cdst[p + 3];
            float ev0 = ebufC[p], ev1 = ebufC[p + 1];
            float ev2 = ebufC[p + 2], ev3 = ebufC[p + 3];
            bf16x8 h0 = *(const bf16x8*)(hbf_t + (size_t)d0 * 128 + sub * 8);
            bf16x8 h1 = *(const bf16x8*)(hbf_t + (size_t)d1 * 128 + sub * 8);
            bf16x8 h2 = *(const bf16x8*)(hbf_t + (size_t)d2 * 128 + sub * 8);
            bf16x8 h3 = *(const bf16x8*)(hbf_t + (size_t)d3 * 128 + sub * 8);
            sev += ev0 + ev1 + ev2 + ev3;
#pragma unroll
            for (int i = 0; i < 8; i++) {
                acc[i] = fmaf(ev0, bf2f((unsigned short)h0[i]), acc[i]);
                acc[i] = fmaf(ev1, bf2f((unsigned short)h1[i]), acc[i]);
                acc[i] = fmaf(ev2, bf2f((unsigned short)h2[i]), acc[i]);
                acc[i] = fmaf(ev3, bf2f((unsigned short)h3[i]), acc[i]);
            }
        }
        for (; p < p1; p++) {
            int d = cdst[p];
            float ev = ebufC[p];
            bf16x8 hv = *(const bf16x8*)(hbf_t + (size_t)d * 128 + sub * 8);
            sev += ev;
#pragma unroll
            for (int i = 0; i < 8; i++) acc[i] = fmaf(ev, bf2f((unsigned short)hv[i]), acc[i]);
        }
        float inv = 1.0f / (sev + 1e-16f);
#pragma unroll
        for (int i = 0; i < 8; i++) T[r16][sub * 8 + i] = acc[i] * inv;
    }
    __syncthreads();
    int w = tid >> 6, lane = tid & 63, lr = lane & 15, lg = lane >> 4;
    int col0 = w * 32 + lr, col1 = col0 + 16;
    int j = tid & 127, half = tid >> 7;
    {
        bf16x8 ahi[4], alo[4];
#pragma unroll
        for (int k = 0; k < 4; k++) mk_split(&T[lr][k * 32 + lg * 8], ahi[k], alo[k]);
        const unsigned short* wh0 = Whi + (size_t)col0 * 128 + lg * 8;
        const unsigned short* wl0 = Wlo + (size_t)col0 * 128 + lg * 8;
        const unsigned short* wh1 = Whi + (size_t)col1 * 128 + lg * 8;
        const unsigned short* wl1 = Wlo + (size_t)col1 * 128 + lg * 8;
        f32x4 a0 = {0.f, 0.f, 0.f, 0.f}, a1 = {0.f, 0.f, 0.f, 0.f};
#pragma unroll
        for (int k = 0; k < 4; k++) {
            bf16x8 bh = *(const bf16x8*)(wh0 + k * 32), bl = *(const bf16x8*)(wl0 + k * 32);
            a0 = MFMA(ahi[k], bh, a0, 0, 0, 0);
            a0 = MFMA(alo[k], bh, a0, 0, 0, 0);
            a0 = MFMA(ahi[k], bl, a0, 0, 0, 0);
            bh = *(const bf16x8*)(wh1 + k * 32); bl = *(const bf16x8*)(wl1 + k * 32);
            a1 = MFMA(ahi[k], bh, a1, 0, 0, 0);
            a1 = MFMA(alo[k], bh, a1, 0, 0, 0);
            a1 = MFMA(ahi[k], bl, a1, 0, 0, 0);
        }
#pragma unroll
        for (int i = 0; i < 4; i++) {
            int r = lg * 4 + i;
            T2[r][col0] = a0[i] + ob_t[col0];
            T2[r][col1] = a1[i] + ob_t[col1];
        }
    }
    __syncthreads();
    {
        int gr = tid >> 4, l16 = tid & 15;
        float sm = 0.0f, sq = 0.0f;
#pragma unroll
        for (int i = 0; i < 8; i++) {
            float v = T2[gr][l16 + 16 * i];
            sm += v; sq += v * v;
        }
#pragma unroll
        for (int m = 1; m < 16; m <<= 1) { sm += __shfl_xor(sm, m); sq += __shfl_xor(sq, m); }
        if (l16 == 0) {
            float mean = sm * (1.0f / 128.0f);
            float var = sq * (1.0f / 128.0f) - mean * mean;
            mu16[gr] = mean;
            rs16[gr] = rsqrtf(var + 1e-5f);
        }
    }
    __syncthreads();
    {
        float gj = g_t[j], bb = bln_t[j];
#pragma unroll
        for (int r = 0; r < 8; r++) {
            int rr = half * 8 + r;
            float v = fmaxf((T2[rr][j] - mu16[rr]) * rs16[rr] * gj + bb, 0.0f);
            emb[(row0 + rr) * 128 + j] = v;
            T2[rr][j] = v;
        }
    }
    __syncthreads();
    {
        bf16x8 ah[4];
#pragma unroll
        for (int k = 0; k < 4; k++) ah[k] = mk_hi(&T2[lr][k * 32 + lg * 8]);
        const unsigned short* wh0 = Shi + (size_t)col0 * 128 + lg * 8;
        const unsigned short* wh1 = Shi + (size_t)col1 * 128 + lg * 8;
        f32x4 a0 = {0.f, 0.f, 0.f, 0.f}, a1 = {0.f, 0.f, 0.f, 0.f};
#pragma unroll
        for (int k = 0; k < 4; k++) {
            a0 = MFMA(ah[k], *(const bf16x8*)(wh0 + k * 32), a0, 0, 0, 0);
            a1 = MFMA(ah[k], *(const bf16x8*)(wh1 + k * 32), a1, 0, 0, 0);
        }
        float b0 = sb1[col0], b1v = sb1[col1], w20 = sW2[col0], w21 = sW2[col1];
#pragma unroll
        for (int i = 0; i < 4; i++) {
            int r = lg * 4 + i;
            float v = tanhf_fast(a0[i] + b0) * w20 + tanhf_fast(a1[i] + b1v) * w21;
            v += __shfl_xor(v, 1);
            v += __shfl_xor(v, 2);
            v += __shfl_xor(v, 4);
            v += __shfl_xor(v, 8);
            if (lr == 0) part[w][r] = v;
        }
    }
    __syncthreads();
    if (tid < 16)
        scores[(row0 + tid) * 2 + t] = part[0][tid] + part[1][tid] + part[2][tid] + part[3][tid] + eb2[t];
}

// ---------------- TAIL-B1 ----------------
__global__ __launch_bounds__(256) void k_tailB1(const float* __restrict__ emb0,
                                                const float* __restrict__ emb1,
                                                const float* __restrict__ scores,
                                                const unsigned short* __restrict__ Fhi,
                                                const unsigned short* __restrict__ Flo,
                                                const float* __restrict__ eob,
                                                const float* __restrict__ elg,
                                                const float* __restrict__ elb,
                                                float* __restrict__ fused2) {
    __shared__ __align__(16) float T[16][132];
    __shared__ __align__(16) float T2[16][132];
    __shared__ float mu16[16], rs16[16], w0s[16], w1s[16];
    int tid = threadIdx.x;
    long row0 = (long)blockIdx.x * 16;
    if (tid < 16) {
        long r = row0 + tid;
        float s0 = scores[r * 2], s1 = scores[r * 2 + 1];
        float mx = fmaxf(s0, s1);
        float e0 = __expf(s0 - mx), e1 = __expf(s1 - mx);
        float inv = 1.0f / (e0 + e1);
        w0s[tid] = e0 * inv;
        w1s[tid] = e1 * inv;
    }
    __syncthreads();
#pragma unroll
    for (int i = 0; i < 8; i++) {
        int idx = tid + i * 256;
        int r = idx >> 7, c = idx & 127;
        T[r][c] = w0s[r] * emb0[(row0 + r) * 128 + c] + w1s[r] * emb1[(row0 + r) * 128 + c];
    }
    __syncthreads();
    int w = tid >> 6, lane = tid & 63, lr = lane & 15, lg = lane >> 4;
    int col0 = w * 32 + lr, col1 = col0 + 16;
    int j = tid & 127, half = tid >> 7;
    {
        bf16x8 ahi[4], alo[4];
#pragma unroll
        for (int k = 0; k < 4; k++) mk_split(&T[lr][k * 32 + lg * 8], ahi[k], alo[k]);
        const unsigned short* wh0 = Fhi + (size_t)col0 * 128 + lg * 8;
        const unsigned short* wl0 = Flo + (size_t)col0 * 128 + lg * 8;
        const unsigned short* wh1 = Fhi + (size_t)col1 * 128 + lg * 8;
        const unsigned short* wl1 = Flo + (size_t)col1 * 128 + lg * 8;
        f32x4 a0 = {0.f, 0.f, 0.f, 0.f}, a1 = {0.f, 0.f, 0.f, 0.f};
#pragma unroll
        for (int k = 0; k < 4; k++) {
            bf16x8 bh = *(const bf16x8*)(wh0 + k * 32), bl = *(const bf16x8*)(wl0 + k * 32);
            a0 = MFMA(ahi[k], bh, a0, 0, 0, 0);
            a0 = MFMA(alo[k], bh, a0, 0, 0, 0);
            a0 = MFMA(ahi[k], bl, a0, 0, 0, 0);
            bh = *(const bf16x8*)(wh1 + k * 32); bl = *(const bf16x8*)(wl1 + k * 32);
            a1 = MFMA(ahi[k], bh, a1, 0, 0, 0);
            a1 = MFMA(alo[k], bh, a1, 0, 0, 0);
            a1 = MFMA(ahi[k], bl, a1, 0, 0, 0);
        }
#pragma unroll
        for (int i = 0; i < 4; i++) {
            int r = lg * 4 + i;
            T2[r][col0] = a0[i] + eob[col0];
            T2[r][col1] = a1[i] + eob[col1];
        }
    }
    __syncthreads();
    {
        int gr = tid >> 4, l16 = tid & 15;
        float sm = 0.0f, sq = 0.0f;
#pragma unroll
        for (int i = 0; i < 8; i++) {
            float v = T2[gr][l16 + 16 * i];
            sm += v; sq += v * v;
        }
#pragma unroll
        for (int m = 1; m < 16; m <<= 1) { sm += __shfl_xor(sm, m); sq += __shfl_xor(sq, m); }
        if (l16 == 0) {
            float mean = sm * (1.0f / 128.0f);
            float var = sq * (1.0f / 128.0f) - mean * mean;
            mu16[gr] = mean;
            rs16[gr] = rsqrtf(var + 1e-5f);
        }
    }
    __syncthreads();
    {
        float gj = elg[j], bb = elb[j];
#pragma unroll
        for (int r = 0; r < 8; r++) {
            int rr = half * 8 + r;
            float v = fmaxf((T2[rr][j] - mu16[rr]) * rs16[rr] * gj + bb, 0.0f);
            fused2[(row0 + rr) * 128 + j] = v;
        }
    }
}

// ---------------- FSUM ----------------
__global__ __launch_bounds__(256) void k_fsum(const float* __restrict__ fused2,
                                              const int* __restrict__ lev,
                                              float* __restrict__ fsumg) {
    __shared__ float ls[2][4][128];
    int tid = threadIdx.x, half = tid >> 7, j = tid & 127;
#pragma unroll
    for (int l = 0; l < 4; l++) ls[half][l][j] = 0.0f;
    __syncthreads();
    for (long row = (long)blockIdx.x * 2 + half; row < NN; row += (long)gridDim.x * 2) {
        int l = lev[row];
        ls[half][l][j] += fused2[row * 128 + j];
    }
    __syncthreads();
    if (half == 0) {
#pragma unroll
        for (int l = 0; l < 4; l++) atomicAdd(&fsumg[l * 128 + j], ls[0][l][j] + ls[1][l][j]);
    }
}

// ---------------- FIN2 ----------------
__global__ void k_fin2(const float* __restrict__ fsum, const int* __restrict__ cnt4,
                       const float* __restrict__ hpW, const float* __restrict__ hpb,
                       const float* __restrict__ W1b, const float* __restrict__ b1,
                       float* __restrict__ lmean, float* __restrict__ lmw) {
    __shared__ float fs[128];
    __shared__ float lml[128];
    int l = blockIdx.x, j = threadIdx.x;
    fs[j] = fsum[l * 128 + j];
    __syncthreads();
    float c = (float)cnt4[l];
    float a = c * hpb[l * 128 + j];
    const float* wp = hpW + (size_t)l * 16384;
    for (int k = 0; k < 128; k++) a = fmaf(fs[k], wp[k * 128 + j], a);
    float cm = c < 1.0f ? 1.0f : c;
    float v = a / cm;
    lmean[l * 128 + j] = v;
    lml[j] = v;
    __syncthreads();
    float b = b1[j];
    for (int k = 0; k < 128; k++) b = fmaf(lml[k], W1b[k * 128 + j], b);
    lmw[l * 128 + j] = b;
}

// ---------------- TAIL-CD2 (level-bucketed) ----------------
__global__ __launch_bounds__(256) void k_tailCD2(const float* __restrict__ fused2,
                                                 const int* __restrict__ perm,
                                                 const int* __restrict__ cnt4,
                                                 const int* __restrict__ off4,
                                                 const int* __restrict__ boff5,
                                                 const unsigned short* __restrict__ QWhi,
                                                 const unsigned short* __restrict__ QWlo,
                                                 const float* __restrict__ qb,
                                                 const float* __restrict__ lmw,
                                                 const float* __restrict__ lmean,
                                                 const float* __restrict__ hW2,
                                                 const unsigned short* __restrict__ Ohi,
                                                 const unsigned short* __restrict__ Olo,
                                                 const float* __restrict__ hob,
                                                 const float* __restrict__ hlg,
                                                 const float* __restrict__ hlb,
                                                 float* __restrict__ out) {
    __shared__ __align__(16) float T[16][132];
    __shared__ __align__(16) float T2[16][132];
    __shared__ float lm[4][128];
    __shared__ float lmwS[4][128];
    __shared__ float w2S[128];
    __shared__ float scS[16][4];
    __shared__ float aw[16][4];
    __shared__ float mu16[16], rs16[16];
    __shared__ int idx16[16];
    int tid = threadIdx.x;
    int b = blockIdx.x;
    if (b >= boff5[4]) return;
    int l = (b >= boff5[3]) ? 3 : (b >= boff5[2]) ? 2 : (b >= boff5[1]) ? 1 : 0;
    int bi = b - boff5[l];
    int base = off4[l] + bi * 16;
    int last = off4[l] + cnt4[l] - 1;
    if (tid < 16) {
        int gp = base + tid;
        if (gp > last) gp = last;
        idx16[tid] = perm[gp];
    }
    for (int idx = tid; idx < 512; idx += 256) {
        lm[idx >> 7][idx & 127] = lmean[idx];
        lmwS[idx >> 7][idx & 127] = lmw[idx];
    }
    if (tid < 128) w2S[tid] = hW2[tid];
    __syncthreads();
#pragma unroll
    for (int i = 0; i < 8; i++) {
        int idx = tid + i * 256;
        int r = idx >> 7, c = idx & 127;
        T[r][c] = fused2[(size_t)idx16[r] * 128 + c];
    }
    __syncthreads();
    int w = tid >> 6, lane = tid & 63, lr = lane & 15, lg = lane >> 4;
    int col0 = w * 32 + lr, col1 = col0 + 16;
    int j = tid & 127, half = tid >> 7;
    {
        bf16x8 ahi[4], alo[4];
#pragma unroll
        for (int k = 0; k < 4; k++) mk_split(&T[lr][k * 32 + lg * 8], ahi[k], alo[k]);
        const unsigned short* wh0 = QWhi + (size_t)l * 16384 + (size_t)col0 * 128 + lg * 8;
        const unsigned short* wl0 = QWlo + (size_t)l * 16384 + (size_t)col0 * 128 + lg * 8;
        const unsigned short* wh1 = QWhi + (size_t)l * 16384 + (size_t)col1 * 128 + lg * 8;
        const unsigned short* wl1 = QWlo + (size_t)l * 16384 + (size_t)col1 * 128 + lg * 8;
        f32x4 a0 = {0.f, 0.f, 0.f, 0.f}, a1 = {0.f, 0.f, 0.f, 0.f};
#pragma unroll
        for (int k = 0; k < 4; k++) {
            bf16x8 bh = *(const bf16x8*)(wh0 + k * 32), bl = *(const bf16x8*)(wl0 + k * 32);
            a0 = MFMA(ahi[k], bh, a0, 0, 0, 0);
            a0 = MFMA(alo[k], bh, a0, 0, 0, 0);
            a0 = MFMA(ahi[k], bl, a0, 0, 0, 0);
            bh = *(const bf16x8*)(wh1 + k * 32); bl = *(const bf16x8*)(wl1 + k * 32);
            a1 = MFMA(ahi[k], bh, a1, 0, 0, 0);
            a1 = MFMA(alo[k], bh, a1, 0, 0, 0);
            a1 = MFMA(ahi[k], bl, a1, 0, 0, 0);
        }
#pragma unroll
        for (int i = 0; i < 4; i++) {
            int r = lg * 4 + i;
            T2[r][col0] = a0[i] + qb[l * 128 + col0];
            T2[r][col1] = a1[i] + qb[l * 128 + col1];
        }
    }
    __syncthreads();
    {
        int p = tid >> 2, sub = tid & 3;
        int pr = p & 15, pl = p >> 4;
        float s = 0.0f;
#pragma unroll
        for (int jj = 0; jj < 32; jj++) {
            int j2 = sub + 4 * jj;
            s += tanhf_fast(T2[pr][j2] + lmwS[pl][j2]) * w2S[j2];
        }
        s += __shfl_xor(s, 1);
        s += __shfl_xor(s, 2);
        if (sub == 0) scS[pr][pl] = s;
    }
    __syncthreads();
    if (tid < 16) {
        float sc[4];
        float mx = -1e30f;
#pragma unroll
        for (int ll = 0; ll < 4; ll++) {
            sc[ll] = scS[tid][ll];
            mx = fmaxf(mx, sc[ll]);
        }
        float s = 0.0f;
#pragma unroll
        for (int ll = 0; ll < 4; ll++) { sc[ll] = __expf(sc[ll] - mx); s += sc[ll]; }
        float inv = 1.0f / s;
#pragma unroll
        for (int ll = 0; ll < 4; ll++) aw[tid][ll] = sc[ll] * inv;
    }
    __syncthreads();
#pragma unroll
    for (int r = 0; r < 8; r++) {
        int rr = half * 8 + r;
        float e = 0.0f;
#pragma unroll
        for (int ll = 0; ll < 4; ll++) e = fmaf(aw[rr][ll], lm[ll][j], e);
        T[rr][j] = e;
    }
    __syncthreads();
    {
        bf16x8 ahi[4], alo[4];
#pragma unroll
        for (int k = 0; k < 4; k++) mk_split(&T[lr][k * 32 + lg * 8], ahi[k], alo[k]);
        const unsigned short* wh0 = Ohi + (size_t)col0 * 128 + lg * 8;
        const unsigned short* wl0 = Olo + (size_t)col0 * 128 + lg * 8;
        const unsigned short* wh1 = Ohi + (size_t)col1 * 128 + lg * 8;
        const unsigned short* wl1 = Olo + (size_t)col1 * 128 + lg * 8;
        f32x4 a0 = {0.f, 0.f, 0.f, 0.f}, a1 = {0.f, 0.f, 0.f, 0.f};
#pragma unroll
        for (int k = 0; k < 4; k++) {
            bf16x8 bh = *(const bf16x8*)(wh0 + k * 32), bl = *(const bf16x8*)(wl0 + k * 32);
            a0 = MFMA(ahi[k], bh, a0, 0, 0, 0);
            a0 = MFMA(alo[k], bh, a0, 0, 0, 0);
            a0 = MFMA(ahi[k], bl, a0, 0, 0, 0);
            bh = *(const bf16x8*)(wh1 + k * 32); bl = *(const bf16x8*)(wl1 + k * 32);
            a1 = MFMA(ahi[k], bh, a1, 0, 0, 0);
            a1 = MFMA(alo[k], bh, a1, 0, 0, 0);
            a1 = MFMA(ahi[k], bl, a1, 0, 0, 0);
        }
#pragma unroll
        for (int i = 0; i < 4; i++) {
            int r = lg * 4 + i;
            T2[r][col0] = a0[i] + hob[col0];
            T2[r][col1] = a1[i] + hob[col1];
        }
    }
    __syncthreads();
    {
        int gr = tid >> 4, l16 = tid & 15;
        float sm = 0.0f, sq = 0.0f;
#pragma unroll
        for (int i = 0; i < 8; i++) {
            float v = T2[gr][l16 + 16 * i];
            sm += v; sq += v * v;
        }
#pragma unroll
        for (int m = 1; m < 16; m <<= 1) { sm += __shfl_xor(sm, m); sq += __shfl_xor(sq, m); }
        if (l16 == 0) {
            float mean = sm * (1.0f / 128.0f);
            float var = sq * (1.0f / 128.0f) - mean * mean;
            mu16[gr] = mean;
            rs16[gr] = rsqrtf(var + 1e-5f);
        }
    }
    __syncthreads();
    {
        float gj = hlg[j], bb = hlb[j];
#pragma unroll
        for (int r = 0; r < 8; r++) {
            int rr = half * 8 + r;
            float v = (T2[rr][j] - mu16[rr]) * rs16[rr] * gj + bb;
            out[(size_t)idx16[rr] * 128 + j] = fmaxf(v, 0.0f);
        }
    }
}

extern "C" void kernel_launch(void* const* d_in, const int* in_sizes, int n_in,
                              void* d_out, int out_size, void* d_ws, size_t ws_size,
                              hipStream_t stream) {
    const float* nf  = (const float*)d_in[0];
    const float* ef  = (const float*)d_in[1];
    const int*   lev = (const int*)d_in[2];
    const int*   ei  = (const int*)d_in[3];
    const float* nlW = (const float*)d_in[4];
    const float* nlb = (const float*)d_in[5];
    const float* neW = (const float*)d_in[6];
    const float* neb = (const float*)d_in[7];
    const float* aW1 = (const float*)d_in[8];
    const float* ab1 = (const float*)d_in[9];
    const float* aW2 = (const float*)d_in[10];
    const float* ab2 = (const float*)d_in[11];
    const float* oW  = (const float*)d_in[12];
    const float* ob  = (const float*)d_in[13];
    const float* lng = (const float*)d_in[14];
    const float* lnb = (const float*)d_in[15];
    const float* eW1 = (const float*)d_in[16];
    const float* eb1 = (const float*)d_in[17];
    const float* eW2 = (const float*)d_in[18];
    const float* eb2 = (const float*)d_in[19];
    const float* eoW = (const float*)d_in[20];
    const float* eob = (const float*)d_in[21];
    const float* elg = (const float*)d_in[22];
    const float* elb = (const float*)d_in[23];
    const float* hpW = (const float*)d_in[24];
    const float* hpb = (const float*)d_in[25];
    const float* hW1 = (const float*)d_in[26];
    const float* hb1 = (const float*)d_in[27];
    const float* hW2 = (const float*)d_in[28];
    const float* hb2 = (const float*)d_in[29];
    const float* hoW = (const float*)d_in[30];
    const float* hob = (const float*)d_in[31];
    const float* hlg = (const float*)d_in[32];
    const float* hlb = (const float*)d_in[33];

    float* ws = (float*)d_ws;
    size_t NH = (size_t)NN * 128;
    float* fused2 = ws;                       // NH
    float* emb0   = fused2 + NH;              // NH
    float* emb1   = emb0 + NH;                // NH
    float* ebuf2  = emb1 + NH;                // 2*EE
    float* scores = ebuf2 + 2 * (size_t)EE;   // 2*NN
    float* beff2  = scores + (size_t)2 * NN;  // 256
    float* fsum   = beff2 + 256;              // 512
    float* lmean  = fsum + 512;               // 512
    float* lmw    = lmean + 512;              // 512
    float* qb     = lmw + 512;                // 512
    unsigned short* U2    = (unsigned short*)(qb + 512);  // 2*NH
    unsigned short* V2    = U2 + 2 * NH;                  // 2*NH
    unsigned short* hbf2  = V2 + 2 * NH;                  // 2*NH
    unsigned short* WhT2  = hbf2 + 2 * NH;                // 2*16384
    unsigned short* WUT2  = WhT2 + 2 * 16384;
    unsigned short* WVT2  = WUT2 + 2 * 16384;
    unsigned short* WET2  = WVT2 + 2 * 16384;             // 2*8192
    unsigned short* twhi  = WET2 + 2 * 8192;              // 6*16384
    unsigned short* twlo  = twhi + 6 * 16384;             // 6*16384
    unsigned short* QWhi  = twlo + 6 * 16384;             // 4*16384
    unsigned short* QWlo  = QWhi + 4 * 16384;             // 4*16384
    int* perm    = (int*)(QWlo + 4 * 16384);              // NN
    int* cnt4    = perm + NN;
    int* off4    = cnt4 + 4;
    int* boff5   = off4 + 4;
    int* cursorL = boff5 + 5;
    int* deg2    = cursorL + 4;          // 2*NN
    int* rowptr2 = deg2 + 2 * NN;        // 2*NN+1
    int* cursor2 = rowptr2 + 2 * NN + 1; // 2*NN
    int* stmp    = cursor2 + 2 * NN;     // 2*NN
    int* sbsum   = stmp + 2 * NN;        // 512
    int* sboff   = sbsum + 512;          // 512
    int* epos2   = sboff + 512;          // 2*EE
    int* cdst2   = epos2 + 2 * EE;       // 2*EE
    float* out = (float*)d_out;

    WSrc ps;
    ps.s[0] = oW;
    ps.s[1] = oW + 16384;
    ps.s[2] = eW1;
    ps.s[3] = eW1 + 16384;
    ps.s[4] = eoW;
    ps.s[5] = hoW;

    const int NB_E = EE / EBLK;           // 15625
    const int NB_N = NN / 16;             // 6250
    const int SCB = (2 * NN + 511) / 512; // 391

    // level bucketing
    k_zeroi<<<1, 4, 0, stream>>>(cnt4, 4);
    k_count<<<128, 256, 0, stream>>>(lev, cnt4);
    k_scan<<<1, 1, 0, stream>>>(cnt4, off4, boff5, cursorL);
    k_scatter<<<125, 256, 0, stream>>>(lev, cursorL, perm);

    // weight prep
    k_prep_tail<<<6 * 64, 256, 0, stream>>>(ps, twhi, twlo);
    k_prep_q<<<258, 256, 0, stream>>>(hpW, hpb, hW1, QWhi, QWlo, qb);
    k_zero<<<1, 512, 0, stream>>>(fsum, (size_t)512);

    // CSR build (both relations at once)
    k_zeroi<<<(2 * NN + 255) / 256, 256, 0, stream>>>(deg2, 2 * NN);
    k_hist2<<<(2 * EE + 255) / 256, 256, 0, stream>>>(ei, deg2);
    k_scan1<<<SCB, 512, 0, stream>>>(deg2, stmp, sbsum);
    k_scan2<<<1, 512, 0, stream>>>(sbsum, sboff, SCB);
    k_scan3<<<SCB, 512, 0, stream>>>(deg2, stmp, sboff, rowptr2, cursor2);
    k_csr_scatter2<<<(2 * EE + 255) / 256, 256, 0, stream>>>(ei, cursor2, epos2, cdst2);

    // head (both t, one nf pass)
    k_prep_head2<<<256, 128, 0, stream>>>(nlW, nlb, aW1, ab1, neW, neb,
                                          WhT2, WUT2, WVT2, WET2, beff2);
    k_head2<<<NB_N, 256, 0, stream>>>(nf, WhT2, WUT2, WVT2, nlb, hbf2, U2, V2);

    // edge scores (both t)
    k_edge4<<<2 * NB_E, 256, 0, stream>>>(ef, ei, epos2, WET2, U2, V2, beff2,
                                          aW2, ab2, ebuf2, NB_E);
    // aggregation + relation tail (both t)
    k_tailA2b<<<2 * NB_N, 256, 0, stream>>>(rowptr2, cdst2, ebuf2, hbf2, twhi, twlo,
                                            ob, lng, lnb, eb1, eW2, eb2,
                                            emb0, emb1, scores, NB_N);

    k_tailB1<<<NB_N, 256, 0, stream>>>(emb0, emb1, scores,
                                       twhi + (size_t)4 * 16384, twlo + (size_t)4 * 16384,
                                       eob, elg, elb, fused2);
    k_fsum<<<256, 256, 0, stream>>>(fused2, lev, fsum);
    k_fin2<<<4, 128, 0, stream>>>(fsum, cnt4, hpW, hpb, hW1 + 16384, hb1, lmean, lmw);
    k_tailCD2<<<NB_N + 4, 256, 0, stream>>>(fused2, perm, cnt4, off4, boff5,
                                            QWhi, QWlo, qb, lmw, lmean, hW2,
                                            twhi + (size_t)5 * 16384, twlo + (size_t)5 * 16384,
                                            hob, hlg, hlb, out);
}

// Round 11
// 942.765 us; speedup vs baseline: 1.7592x; 1.0135x over previous
//
#include <hip/hip_runtime.h>
#include <math.h>

#define NN 100000
#define EE 500000
#define NH_C (NN * 128)
#define EBLK 32
// D=H=128, ED=64, T=2, L=4

typedef __attribute__((ext_vector_type(8))) short bf16x8;
typedef __attribute__((ext_vector_type(4))) float f32x4;
#define MFMA __builtin_amdgcn_mfma_f32_16x16x32_bf16

__device__ inline short f2bf(float x) {
    union { float f; unsigned u; } v; v.f = x;
    unsigned r = v.u + 0x7FFF + ((v.u >> 16) & 1);
    return (short)(r >> 16);
}
__device__ inline float bf2f(unsigned short h) {
    union { unsigned u; float f; } v; v.u = ((unsigned)h) << 16; return v.f;
}
__device__ inline float tanhf_fast(float x) {
    float e = __expf(2.0f * x);
    return 1.0f - 2.0f * __builtin_amdgcn_rcpf(e + 1.0f);
}

__device__ inline bf16x8 mk_hi(const float* p) {
    float4 a = *(const float4*)p, b = *(const float4*)(p + 4);
    float v[8] = {a.x, a.y, a.z, a.w, b.x, b.y, b.z, b.w};
    bf16x8 h;
#pragma unroll
    for (int i = 0; i < 8; i++) h[i] = f2bf(v[i]);
    return h;
}
__device__ inline bf16x8 mk_hi8(float4 a, float4 b) {
    float v[8] = {a.x, a.y, a.z, a.w, b.x, b.y, b.z, b.w};
    bf16x8 h;
#pragma unroll
    for (int i = 0; i < 8; i++) h[i] = f2bf(v[i]);
    return h;
}
__device__ inline void mk_split(const float* p, bf16x8& hi, bf16x8& lo) {
    float4 a = *(const float4*)p, b = *(const float4*)(p + 4);
    float v[8] = {a.x, a.y, a.z, a.w, b.x, b.y, b.z, b.w};
#pragma unroll
    for (int i = 0; i < 8; i++) {
        short h = f2bf(v[i]);
        hi[i] = h;
        lo[i] = f2bf(v[i] - bf2f((unsigned short)h));
    }
}

// ---------------- zero fill ----------------
__global__ void k_zero(float* __restrict__ p, size_t n) {
    size_t i = (size_t)blockIdx.x * blockDim.x + threadIdx.x;
    size_t stride = (size_t)gridDim.x * blockDim.x;
    for (; i < n; i += stride) p[i] = 0.0f;
}
__global__ void k_zeroi(int* __restrict__ p, int n) {
    int i = blockIdx.x * blockDim.x + threadIdx.x;
    if (i < n) p[i] = 0;
}

// ---------------- CSR build (both relations, concatenated) ----------------
__global__ __launch_bounds__(256) void k_hist2(const int* __restrict__ ei, int* __restrict__ deg2) {
    long g = (long)blockIdx.x * 256 + threadIdx.x;
    if (g < 2L * EE) {
        int t = g >= EE;
        long le = g - (long)t * EE;
        int s = ei[(size_t)t * 2 * EE + le];
        atomicAdd(&deg2[t * NN + s], 1);
    }
}
__global__ __launch_bounds__(512) void k_scan1(const int* __restrict__ deg,
                                               int* __restrict__ tmp, int* __restrict__ bsum) {
    __shared__ int sh[2][512];
    int b = blockIdx.x, tid = threadIdx.x;
    int i = b * 512 + tid;
    int v = (i < 2 * NN) ? deg[i] : 0;
    int cur = 0;
    sh[0][tid] = v;
    __syncthreads();
    for (int off = 1; off < 512; off <<= 1) {
        int nxt = cur ^ 1;
        int a = sh[cur][tid];
        if (tid >= off) a += sh[cur][tid - off];
        sh[nxt][tid] = a;
        __syncthreads();
        cur = nxt;
    }
    int incl = sh[cur][tid];
    if (i < 2 * NN) tmp[i] = incl;
    if (tid == 511) bsum[b] = incl;
}
__global__ __launch_bounds__(512) void k_scan2(const int* __restrict__ bsum, int* __restrict__ boff,
                                               int nB) {
    __shared__ int sh[2][512];
    int tid = threadIdx.x;
    int v = (tid < nB) ? bsum[tid] : 0;
    int cur = 0;
    sh[0][tid] = v;
    __syncthreads();
    for (int off = 1; off < 512; off <<= 1) {
        int nxt = cur ^ 1;
        int a = sh[cur][tid];
        if (tid >= off) a += sh[cur][tid - off];
        sh[nxt][tid] = a;
        __syncthreads();
        cur = nxt;
    }
    boff[tid] = sh[cur][tid] - v;
}
__global__ __launch_bounds__(512) void k_scan3(const int* __restrict__ deg,
                                               const int* __restrict__ tmp,
                                               const int* __restrict__ boff,
                                               int* __restrict__ rowptr, int* __restrict__ cursor) {
    int i = blockIdx.x * 512 + threadIdx.x;
    if (i < 2 * NN) {
        int r = tmp[i] - deg[i] + boff[blockIdx.x];
        rowptr[i] = r;
        cursor[i] = r;
    }
    if (i == 0) rowptr[2 * NN] = 2 * EE;
}
__global__ __launch_bounds__(256) void k_csr_scatter3(const int* __restrict__ ei,
                                                      int* __restrict__ cursor,
                                                      int* __restrict__ ceid,
                                                      int* __restrict__ cs,
                                                      int* __restrict__ cdst) {
    long g = (long)blockIdx.x * 256 + threadIdx.x;
    if (g < 2L * EE) {
        int t = g >= EE;
        long le = g - (long)t * EE;
        int s = ei[(size_t)t * 2 * EE + le];
        int d = ei[(size_t)t * 2 * EE + EE + le];
        int p = atomicAdd(&cursor[t * NN + s], 1);
        ceid[p] = (int)le;
        cs[p] = s;
        cdst[p] = d;
    }
}

// ---------------- level bucketing ----------------
__global__ __launch_bounds__(256) void k_count(const int* __restrict__ lev, int* __restrict__ cnt4) {
    __shared__ int lc[4];
    int tid = threadIdx.x;
    if (tid < 4) lc[tid] = 0;
    __syncthreads();
    for (long n = (long)blockIdx.x * 256 + tid; n < NN; n += (long)gridDim.x * 256)
        atomicAdd(&lc[lev[n]], 1);
    __syncthreads();
    if (tid < 4 && lc[tid]) atomicAdd(&cnt4[tid], lc[tid]);
}

__global__ void k_scan(const int* __restrict__ cnt4, int* __restrict__ off4,
                       int* __restrict__ boff5, int* __restrict__ cursor) {
    int o = 0, b = 0;
    for (int l = 0; l < 4; l++) {
        off4[l] = o; cursor[l] = o; boff5[l] = b;
        o += cnt4[l];
        b += (cnt4[l] + 15) >> 4;
    }
    boff5[4] = b;
}

__global__ __launch_bounds__(256) void k_scatter(const int* __restrict__ lev,
                                                 int* __restrict__ cursor,
                                                 int* __restrict__ perm) {
    __shared__ int lc[4], lb[4], lc2[4];
    int tid = threadIdx.x;
    if (tid < 4) { lc[tid] = 0; lc2[tid] = 0; }
    __syncthreads();
    int start = blockIdx.x * 800, end = start + 800;
    if (end > NN) end = NN;
    for (int n = start + tid; n < end; n += 256) atomicAdd(&lc[lev[n]], 1);
    __syncthreads();
    if (tid < 4 && lc[tid]) lb[tid] = atomicAdd(&cursor[tid], lc[tid]);
    __syncthreads();
    for (int n = start + tid; n < end; n += 256) {
        int l = lev[n];
        int p = atomicAdd(&lc2[l], 1);
        perm[lb[l] + p] = n;
    }
}

// ---------------- prep head (both t): WhT2, WUT2, WVT2, WET2 (bf16 T), beff2 ----------------
__global__ void k_prep_head2(const float* __restrict__ nlW, const float* __restrict__ nlb,
                             const float* __restrict__ aW1, const float* __restrict__ ab1,
                             const float* __restrict__ neW, const float* __restrict__ neb,
                             unsigned short* __restrict__ WhT2, unsigned short* __restrict__ WUT2,
                             unsigned short* __restrict__ WVT2, unsigned short* __restrict__ WET2,
                             float* __restrict__ beff2) {
    __shared__ float red[2];
    int t = blockIdx.x >> 7, j = blockIdx.x & 127, k = threadIdx.x;
    const float* Wn = nlW + (size_t)t * 16384;
    const float* bn = nlb + t * 128;
    const float* W1 = aW1 + (size_t)t * 384 * 128;
    const float* b1 = ab1 + t * 128;
    const float* We = neW + (size_t)t * 64 * 128;
    const float* be = neb + t * 128;
    WhT2[(size_t)t * 16384 + j * 128 + k] = (unsigned short)f2bf(Wn[k * 128 + j]);
    float su = 0.0f, sv = 0.0f;
    for (int m = 0; m < 128; m++) {
        float wkm = Wn[k * 128 + m];
        su = fmaf(wkm, W1[m * 128 + j], su);
        sv = fmaf(wkm, W1[(128 + m) * 128 + j], sv);
    }
    WUT2[(size_t)t * 16384 + j * 128 + k] = (unsigned short)f2bf(su);
    WVT2[(size_t)t * 16384 + j * 128 + k] = (unsigned short)f2bf(sv);
    if (k < 64) {
        float se = 0.0f;
        for (int m = 0; m < 128; m++) se = fmaf(We[k * 128 + m], W1[(256 + m) * 128 + j], se);
        WET2[(size_t)t * 8192 + j * 64 + k] = (unsigned short)f2bf(se);
    }
    float tk = bn[k] * (W1[k * 128 + j] + W1[(128 + k) * 128 + j]) + be[k] * W1[(256 + k) * 128 + j];
#pragma unroll
    for (int o = 32; o > 0; o >>= 1) tk += __shfl_down(tk, o);
    if ((k & 63) == 0) red[k >> 6] = tk;
    __syncthreads();
    if (k == 0) beff2[t * 128 + j] = b1[j] + red[0] + red[1];
}

// ---------------- prep tail: split-bf16 transposed weights (6 mats) ----------------
struct WSrc { const float* s[6]; };
__global__ void k_prep_tail(WSrc ps, unsigned short* __restrict__ hi,
                            unsigned short* __restrict__ lo) {
    int m = blockIdx.x >> 6, blk = blockIdx.x & 63;
    const float* src = ps.s[m];
    unsigned short* h = hi + (size_t)m * 16384;
    unsigned short* l = lo + (size_t)m * 16384;
    int idx = blk * 256 + threadIdx.x;
    int k = idx >> 7, j = idx & 127;
    float v = src[idx];
    short hh = f2bf(v);
    h[j * 128 + k] = (unsigned short)hh;
    l[j * 128 + k] = (unsigned short)f2bf(v - bf2f((unsigned short)hh));
}

// ---------------- prep Q: QW[l] = hpW[l] @ hW1a (T split bf16), qb[l] = hpb[l]@hW1a ----------
__global__ void k_prep_q(const float* __restrict__ hpW, const float* __restrict__ hpb,
                         const float* __restrict__ hW1a,
                         unsigned short* __restrict__ QWhi, unsigned short* __restrict__ QWlo,
                         float* __restrict__ qb) {
    int gidx = blockIdx.x * 256 + threadIdx.x;
    if (gidx < 4 * 16384) {
        int l = gidx >> 14, rem = gidx & 16383;
        int k = rem >> 7, j = rem & 127;
        const float* wr = hpW + (size_t)l * 16384 + (size_t)k * 128;
        float v = 0.0f;
        for (int m = 0; m < 128; m++) v = fmaf(wr[m], hW1a[m * 128 + j], v);
        short hh = f2bf(v);
        QWhi[(size_t)l * 16384 + j * 128 + k] = (unsigned short)hh;
        QWlo[(size_t)l * 16384 + j * 128 + k] = (unsigned short)f2bf(v - bf2f((unsigned short)hh));
    } else {
        int e = gidx - 4 * 16384;
        if (e < 512) {
            int l = e >> 7, j = e & 127;
            float v = 0.0f;
            for (int m = 0; m < 128; m++) v = fmaf(hpb[l * 128 + m], hW1a[m * 128 + j], v);
            qb[l * 128 + j] = v;
        }
    }
}

// ---------------- HEAD2: both t from one nf tile -> hbf,U,V (x2) ----------------
__global__ __launch_bounds__(256) void k_head2(const float* __restrict__ nf,
                                               const unsigned short* __restrict__ WhT2,
                                               const unsigned short* __restrict__ WUT2,
                                               const unsigned short* __restrict__ WVT2,
                                               const float* __restrict__ nlb,
                                               unsigned short* __restrict__ hbf2,
                                               unsigned short* __restrict__ U2,
                                               unsigned short* __restrict__ V2) {
    __shared__ __align__(16) float T[16][132];
    int tid = threadIdx.x;
    long row0 = (long)blockIdx.x * 16;
#pragma unroll
    for (int i = 0; i < 8; i++) {
        int idx = tid + i * 256;
        int r = idx >> 7, c = idx & 127;
        T[r][c] = nf[(row0 + r) * 128 + c];
    }
    __syncthreads();
    int w = tid >> 6, lane = tid & 63, lr = lane & 15, lg = lane >> 4;
    bf16x8 A[4];
#pragma unroll
    for (int k = 0; k < 4; k++) A[k] = mk_hi(&T[lr][k * 32 + lg * 8]);
    int col0 = w * 32 + lr, col1 = col0 + 16;
#pragma unroll
    for (int o = 0; o < 6; o++) {
        const unsigned short* wb =
            (o == 0) ? WhT2 : (o == 1) ? WUT2 : (o == 2) ? WVT2 :
            (o == 3) ? WhT2 + 16384 : (o == 4) ? WUT2 + 16384 : WVT2 + 16384;
        unsigned short* ob =
            (o == 0) ? hbf2 : (o == 1) ? U2 : (o == 2) ? V2 :
            (o == 3) ? hbf2 + NH_C : (o == 4) ? U2 + NH_C : V2 + NH_C;
        const unsigned short* w0 = wb + (size_t)col0 * 128 + lg * 8;
        const unsigned short* w1 = wb + (size_t)col1 * 128 + lg * 8;
        f32x4 a0 = {0.f, 0.f, 0.f, 0.f}, a1 = {0.f, 0.f, 0.f, 0.f};
#pragma unroll
        for (int k = 0; k < 4; k++) {
            a0 = MFMA(A[k], *(const bf16x8*)(w0 + k * 32), a0, 0, 0, 0);
            a1 = MFMA(A[k], *(const bf16x8*)(w1 + k * 32), a1, 0, 0, 0);
        }
        float bb0 = (o == 0) ? nlb[col0] : (o == 3) ? nlb[128 + col0] : 0.0f;
        float bb1 = (o == 0) ? nlb[col1] : (o == 3) ? nlb[128 + col1] : 0.0f;
        unsigned short* op = ob + (size_t)row0 * 128;
#pragma unroll
        for (int i = 0; i < 4; i++) {
            int r = lg * 4 + i;
            op[(size_t)r * 128 + col0] = (unsigned short)f2bf(a0[i] + bb0);
            op[(size_t)r * 128 + col1] = (unsigned short)f2bf(a1[i] + bb1);
        }
    }
}

// ---------------- EDGE5 (CSR order, both t): U seq/L1-hot, V+ef gather, ev coalesced ----
__global__ __launch_bounds__(256) void k_edge5(const float* __restrict__ ef,
                                               const int* __restrict__ ceid,
                                               const int* __restrict__ cs,
                                               const int* __restrict__ cdst,
                                               const unsigned short* __restrict__ WET2,
                                               const unsigned short* __restrict__ U2,
                                               const unsigned short* __restrict__ V2,
                                               const float* __restrict__ beff2,
                                               const float* __restrict__ aW2,
                                               const float* __restrict__ ab2,
                                               float* __restrict__ ebuf2) {
    __shared__ __align__(16) float pre[EBLK][132];
    __shared__ float part[4][EBLK];
    __shared__ int eS[EBLK];
    int tid = threadIdx.x, w = tid >> 6, lane = tid & 63, lr = lane & 15, lg = lane >> 4;
    long p0 = (long)blockIdx.x * EBLK;
    int t = p0 >= (long)EE;
    const float* ef_t = ef + (size_t)t * EE * 64;
    const unsigned short* U_t = U2 + (size_t)t * NH_C;
    const unsigned short* V_t = V2 + (size_t)t * NH_C;
    // ---- stage pre = U[s] + V[d]; 8 threads/edge, CSR order => U rows L1-hot ----
    {
        int eL = tid >> 3, sub = tid & 7;
        int uch = (sub + eL) & 7;
        long p = p0 + eL;
        int s = cs[p], d = cdst[p];
        const unsigned short* up = U_t + (size_t)s * 128 + uch * 16;
        const unsigned short* vp = V_t + (size_t)d * 128 + uch * 16;
        bf16x8 u0 = *(const bf16x8*)up, u1 = *(const bf16x8*)(up + 8);
        bf16x8 v0 = *(const bf16x8*)vp, v1 = *(const bf16x8*)(vp + 8);
        float tv[16];
#pragma unroll
        for (int i = 0; i < 8; i++)
            tv[i] = bf2f((unsigned short)u0[i]) + bf2f((unsigned short)v0[i]);
#pragma unroll
        for (int i = 0; i < 8; i++)
            tv[8 + i] = bf2f((unsigned short)u1[i]) + bf2f((unsigned short)v1[i]);
#pragma unroll
        for (int i = 0; i < 4; i++) {
            float4 f4 = {tv[4 * i], tv[4 * i + 1], tv[4 * i + 2], tv[4 * i + 3]};
            *(float4*)&pre[eL][uch * 16 + 4 * i] = f4;
        }
    }
    if (tid < EBLK) eS[tid] = ceid[p0 + tid];
    int col0 = w * 32 + lr, col1 = col0 + 16;
    bf16x8 B0[2], B1[2];
#pragma unroll
    for (int kk = 0; kk < 2; kk++) {
        B0[kk] = *(const bf16x8*)(WET2 + (size_t)t * 8192 + (size_t)col0 * 64 + kk * 32 + lg * 8);
        B1[kk] = *(const bf16x8*)(WET2 + (size_t)t * 8192 + (size_t)col1 * 64 + kk * 32 + lg * 8);
    }
    float be0 = beff2[t * 128 + col0], be1 = beff2[t * 128 + col1];
    float w20 = aW2[t * 128 + col0], w21 = aW2[t * 128 + col1];
    __syncthreads();
#pragma unroll
    for (int i16 = 0; i16 < 2; i16++) {
        int e = eS[i16 * 16 + lr];
        const float* ep = ef_t + (size_t)e * 64 + lg * 8;
        float4 L0 = *(const float4*)ep;
        float4 L1 = *(const float4*)(ep + 4);
        float4 L2 = *(const float4*)(ep + 32);
        float4 L3 = *(const float4*)(ep + 36);
        bf16x8 av0 = mk_hi8(L0, L1);
        bf16x8 av1 = mk_hi8(L2, L3);
        f32x4 a0 = {0.f, 0.f, 0.f, 0.f}, a1 = {0.f, 0.f, 0.f, 0.f};
        a0 = MFMA(av0, B0[0], a0, 0, 0, 0);
        a0 = MFMA(av1, B0[1], a0, 0, 0, 0);
        a1 = MFMA(av0, B1[0], a1, 0, 0, 0);
        a1 = MFMA(av1, B1[1], a1, 0, 0, 0);
#pragma unroll
        for (int q = 0; q < 4; q++) {
            int eL = i16 * 16 + lg * 4 + q;
            float v = tanhf_fast(a0[q] + pre[eL][col0] + be0) * w20 +
                      tanhf_fast(a1[q] + pre[eL][col1] + be1) * w21;
            v += __shfl_xor(v, 1);
            v += __shfl_xor(v, 2);
            v += __shfl_xor(v, 4);
            v += __shfl_xor(v, 8);
            if (lr == 0) part[w][eL] = v;
        }
    }
    __syncthreads();
    if (tid < EBLK) {
        float a = part[0][tid] + part[1][tid] + part[2][tid] + part[3][tid] + ab2[t];
        ebuf2[p0 + tid] = __expf(a);
    }
}

// ---------------- TAIL-A2B (both t): CSR gather (4-way unroll) + GEMM + LN + score ----------
__global__ __launch_bounds__(256) void k_tailA2b(const int* __restrict__ rowptr2,
                                                 const int* __restrict__ cdst,
                                                 const float* __restrict__ ebufC,
                                                 const unsigned short* __restrict__ hbf2,
                                                 const unsigned short* __restrict__ twhi,
                                                 const unsigned short* __restrict__ twlo,
                                                 const float* __restrict__ ob,
                                                 const float* __restrict__ lng,
                                                 const float* __restrict__ lnb,
                                                 const float* __restrict__ eb1,
                                                 const float* __restrict__ eW2,
                                                 const float* __restrict__ eb2,
                                                 float* __restrict__ emb0,
                                                 float* __restrict__ emb1,
                                                 float* __restrict__ scores, int NBn) {
    __shared__ __align__(16) float T[16][132];
    __shared__ __align__(16) float T2[16][132];
    __shared__ float mu16[16], rs16[16], part[4][16];
    int tid = threadIdx.x;
    int t = blockIdx.x >= NBn;
    int bi = blockIdx.x - t * NBn;
    long row0 = (long)bi * 16;
    const int* rowp = rowptr2 + (size_t)t * NN;
    const unsigned short* hbf_t = hbf2 + (size_t)t * NH_C;
    const unsigned short* Whi = twhi + (size_t)t * 16384;
    const unsigned short* Wlo = twlo + (size_t)t * 16384;
    const unsigned short* Shi = twhi + (size_t)(2 + t) * 16384;
    const float* ob_t = ob + t * 128;
    const float* g_t = lng + t * 128;
    const float* bln_t = lnb + t * 128;
    const float* sb1 = eb1 + t * 128;
    const float* sW2 = eW2 + t * 128;
    float* emb = t ? emb1 : emb0;
    // CSR gather: 16 threads/row, 4-way unrolled
    {
        int r16 = tid >> 4, sub = tid & 15;
        long n = row0 + r16;
        int p0 = rowp[n], p1 = rowp[n + 1];
        float acc[8] = {0, 0, 0, 0, 0, 0, 0, 0};
        float sev = 0.0f;
        int p = p0;
        for (; p + 4 <= p1; p += 4) {
            int d0 = cdst[p], d1 = cdst[p + 1], d2 = cdst[p + 2], d3 = cdst[p + 3];
            float ev0 = ebufC[p], ev1 = ebufC[p + 1];
            float ev2 = ebufC[p + 2], ev3 = ebufC[p + 3];
            bf16x8 h0 = *(const bf16x8*)(hbf_t + (size_t)d0 * 128 + sub * 8);
            bf16x8 h1 = *(const bf16x8*)(hbf_t + (size_t)d1 * 128 + sub * 8);
            bf16x8 h2 = *(const bf16x8*)(hbf_t + (size_t)d2 * 128 + sub * 8);
            bf16x8 h3 = *(const bf16x8*)(hbf_t + (size_t)d3 * 128 + sub * 8);
            sev += ev0 + ev1 + ev2 + ev3;
#pragma unroll
            for (int i = 0; i < 8; i++) {
                acc[i] = fmaf(ev0, bf2f((unsigned short)h0[i]), acc[i]);
                acc[i] = fmaf(ev1, bf2f((unsigned short)h1[i]), acc[i]);
                acc[i] = fmaf(ev2, bf2f((unsigned short)h2[i]), acc[i]);
                acc[i] = fmaf(ev3, bf2f((unsigned short)h3[i]), acc[i]);
            }
        }
        for (; p < p1; p++) {
            int d = cdst[p];
            float ev = ebufC[p];
            bf16x8 hv = *(const bf16x8*)(hbf_t + (size_t)d * 128 + sub * 8);
            sev += ev;
#pragma unroll
            for (int i = 0; i < 8; i++) acc[i] = fmaf(ev, bf2f((unsigned short)hv[i]), acc[i]);
        }
        float inv = 1.0f / (sev + 1e-16f);
#pragma unroll
        for (int i = 0; i < 8; i++) T[r16][sub * 8 + i] = acc[i] * inv;
    }
    __syncthreads();
    int w = tid >> 6, lane = tid & 63, lr = lane & 15, lg = lane >> 4;
    int col0 = w * 32 + lr, col1 = col0 + 16;
    int j = tid & 127, half = tid >> 7;
    {
        bf16x8 ahi[4], alo[4];
#pragma unroll
        for (int k = 0; k < 4; k++) mk_split(&T[lr][k * 32 + lg * 8], ahi[k], alo[k]);
        const unsigned short* wh0 = Whi + (size_t)col0 * 128 + lg * 8;
        const unsigned short* wl0 = Wlo + (size_t)col0 * 128 + lg * 8;
        const unsigned short* wh1 = Whi + (size_t)col1 * 128 + lg * 8;
        const unsigned short* wl1 = Wlo + (size_t)col1 * 128 + lg * 8;
        f32x4 a0 = {0.f, 0.f, 0.f, 0.f}, a1 = {0.f, 0.f, 0.f, 0.f};
#pragma unroll
        for (int k = 0; k < 4; k++) {
            bf16x8 bh = *(const bf16x8*)(wh0 + k * 32), bl = *(const bf16x8*)(wl0 + k * 32);
            a0 = MFMA(ahi[k], bh, a0, 0, 0, 0);
            a0 = MFMA(alo[k], bh, a0, 0, 0, 0);
            a0 = MFMA(ahi[k], bl, a0, 0, 0, 0);
            bh = *(const bf16x8*)(wh1 + k * 32); bl = *(const bf16x8*)(wl1 + k * 32);
            a1 = MFMA(ahi[k], bh, a1, 0, 0, 0);
            a1 = MFMA(alo[k], bh, a1, 0, 0, 0);
            a1 = MFMA(ahi[k], bl, a1, 0, 0, 0);
        }
#pragma unroll
        for (int i = 0; i < 4; i++) {
            int r = lg * 4 + i;
            T2[r][col0] = a0[i] + ob_t[col0];
            T2[r][col1] = a1[i] + ob_t[col1];
        }
    }
    __syncthreads();
    {
        int gr = tid >> 4, l16 = tid & 15;
        float sm = 0.0f, sq = 0.0f;
#pragma unroll
        for (int i = 0; i < 8; i++) {
            float v = T2[gr][l16 + 16 * i];
            sm += v; sq += v * v;
        }
#pragma unroll
        for (int m = 1; m < 16; m <<= 1) { sm += __shfl_xor(sm, m); sq += __shfl_xor(sq, m); }
        if (l16 == 0) {
            float mean = sm * (1.0f / 128.0f);
            float var = sq * (1.0f / 128.0f) - mean * mean;
            mu16[gr] = mean;
            rs16[gr] = rsqrtf(var + 1e-5f);
        }
    }
    __syncthreads();
    {
        float gj = g_t[j], bb = bln_t[j];
#pragma unroll
        for (int r = 0; r < 8; r++) {
            int rr = half * 8 + r;
            float v = fmaxf((T2[rr][j] - mu16[rr]) * rs16[rr] * gj + bb, 0.0f);
            emb[(row0 + rr) * 128 + j] = v;
            T2[rr][j] = v;
        }
    }
    __syncthreads();
    {
        bf16x8 ah[4];
#pragma unroll
        for (int k = 0; k < 4; k++) ah[k] = mk_hi(&T2[lr][k * 32 + lg * 8]);
        const unsigned short* wh0 = Shi + (size_t)col0 * 128 + lg * 8;
        const unsigned short* wh1 = Shi + (size_t)col1 * 128 + lg * 8;
        f32x4 a0 = {0.f, 0.f, 0.f, 0.f}, a1 = {0.f, 0.f, 0.f, 0.f};
#pragma unroll
        for (int k = 0; k < 4; k++) {
            a0 = MFMA(ah[k], *(const bf16x8*)(wh0 + k * 32), a0, 0, 0, 0);
            a1 = MFMA(ah[k], *(const bf16x8*)(wh1 + k * 32), a1, 0, 0, 0);
        }
        float b0 = sb1[col0], b1v = sb1[col1], w20 = sW2[col0], w21 = sW2[col1];
#pragma unroll
        for (int i = 0; i < 4; i++) {
            int r = lg * 4 + i;
            float v = tanhf_fast(a0[i] + b0) * w20 + tanhf_fast(a1[i] + b1v) * w21;
            v += __shfl_xor(v, 1);
            v += __shfl_xor(v, 2);
            v += __shfl_xor(v, 4);
            v += __shfl_xor(v, 8);
            if (lr == 0) part[w][r] = v;
        }
    }
    __syncthreads();
    if (tid < 16)
        scores[(row0 + tid) * 2 + t] = part[0][tid] + part[1][tid] + part[2][tid] + part[3][tid] + eb2[t];
}

// ---------------- TAIL-B1 ----------------
__global__ __launch_bounds__(256) void k_tailB1(const float* __restrict__ emb0,
                                                const float* __restrict__ emb1,
                                                const float* __restrict__ scores,
                                                const unsigned short* __restrict__ Fhi,
                                                const unsigned short* __restrict__ Flo,
                                                const float* __restrict__ eob,
                                                const float* __restrict__ elg,
                                                const float* __restrict__ elb,
                                                float* __restrict__ fused2) {
    __shared__ __align__(16) float T[16][132];
    __shared__ __align__(16) float T2[16][132];
    __shared__ float mu16[16], rs16[16], w0s[16], w1s[16];
    int tid = threadIdx.x;
    long row0 = (long)blockIdx.x * 16;
    if (tid < 16) {
        long r = row0 + tid;
        float s0 = scores[r * 2], s1 = scores[r * 2 + 1];
        float mx = fmaxf(s0, s1);
        float e0 = __expf(s0 - mx), e1 = __expf(s1 - mx);
        float inv = 1.0f / (e0 + e1);
        w0s[tid] = e0 * inv;
        w1s[tid] = e1 * inv;
    }
    __syncthreads();
#pragma unroll
    for (int i = 0; i < 8; i++) {
        int idx = tid + i * 256;
        int r = idx >> 7, c = idx & 127;
        T[r][c] = w0s[r] * emb0[(row0 + r) * 128 + c] + w1s[r] * emb1[(row0 + r) * 128 + c];
    }
    __syncthreads();
    int w = tid >> 6, lane = tid & 63, lr = lane & 15, lg = lane >> 4;
    int col0 = w * 32 + lr, col1 = col0 + 16;
    int j = tid & 127, half = tid >> 7;
    {
        bf16x8 ahi[4], alo[4];
#pragma unroll
        for (int k = 0; k < 4; k++) mk_split(&T[lr][k * 32 + lg * 8], ahi[k], alo[k]);
        const unsigned short* wh0 = Fhi + (size_t)col0 * 128 + lg * 8;
        const unsigned short* wl0 = Flo + (size_t)col0 * 128 + lg * 8;
        const unsigned short* wh1 = Fhi + (size_t)col1 * 128 + lg * 8;
        const unsigned short* wl1 = Flo + (size_t)col1 * 128 + lg * 8;
        f32x4 a0 = {0.f, 0.f, 0.f, 0.f}, a1 = {0.f, 0.f, 0.f, 0.f};
#pragma unroll
        for (int k = 0; k < 4; k++) {
            bf16x8 bh = *(const bf16x8*)(wh0 + k * 32), bl = *(const bf16x8*)(wl0 + k * 32);
            a0 = MFMA(ahi[k], bh, a0, 0, 0, 0);
            a0 = MFMA(alo[k], bh, a0, 0, 0, 0);
            a0 = MFMA(ahi[k], bl, a0, 0, 0, 0);
            bh = *(const bf16x8*)(wh1 + k * 32); bl = *(const bf16x8*)(wl1 + k * 32);
            a1 = MFMA(ahi[k], bh, a1, 0, 0, 0);
            a1 = MFMA(alo[k], bh, a1, 0, 0, 0);
            a1 = MFMA(ahi[k], bl, a1, 0, 0, 0);
        }
#pragma unroll
        for (int i = 0; i < 4; i++) {
            int r = lg * 4 + i;
            T2[r][col0] = a0[i] + eob[col0];
            T2[r][col1] = a1[i] + eob[col1];
        }
    }
    __syncthreads();
    {
        int gr = tid >> 4, l16 = tid & 15;
        float sm = 0.0f, sq = 0.0f;
#pragma unroll
        for (int i = 0; i < 8; i++) {
            float v = T2[gr][l16 + 16 * i];
            sm += v; sq += v * v;
        }
#pragma unroll
        for (int m = 1; m < 16; m <<= 1) { sm += __shfl_xor(sm, m); sq += __shfl_xor(sq, m); }
        if (l16 == 0) {
            float mean = sm * (1.0f / 128.0f);
            float var = sq * (1.0f / 128.0f) - mean * mean;
            mu16[gr] = mean;
            rs16[gr] = rsqrtf(var + 1e-5f);
        }
    }
    __syncthreads();
    {
        float gj = elg[j], bb = elb[j];
#pragma unroll
        for (int r = 0; r < 8; r++) {
            int rr = half * 8 + r;
            float v = fmaxf((T2[rr][j] - mu16[rr]) * rs16[rr] * gj + bb, 0.0f);
            fused2[(row0 + rr) * 128 + j] = v;
        }
    }
}

// ---------------- FSUM ----------------
__global__ __launch_bounds__(256) void k_fsum(const float* __restrict__ fused2,
                                              const int* __restrict__ lev,
                                              float* __restrict__ fsumg) {
    __shared__ float ls[2][4][128];
    int tid = threadIdx.x, half = tid >> 7, j = tid & 127;
#pragma unroll
    for (int l = 0; l < 4; l++) ls[half][l][j] = 0.0f;
    __syncthreads();
    for (long row = (long)blockIdx.x * 2 + half; row < NN; row += (long)gridDim.x * 2) {
        int l = lev[row];
        ls[half][l][j] += fused2[row * 128 + j];
    }
    __syncthreads();
    if (half == 0) {
#pragma unroll
        for (int l = 0; l < 4; l++) atomicAdd(&fsumg[l * 128 + j], ls[0][l][j] + ls[1][l][j]);
    }
}

// ---------------- FIN2 ----------------
__global__ void k_fin2(const float* __restrict__ fsum, const int* __restrict__ cnt4,
                       const float* __restrict__ hpW, const float* __restrict__ hpb,
                       const float* __restrict__ W1b, const float* __restrict__ b1,
                       float* __restrict__ lmean, float* __restrict__ lmw) {
    __shared__ float fs[128];
    __shared__ float lml[128];
    int l = blockIdx.x, j = threadIdx.x;
    fs[j] = fsum[l * 128 + j];
    __syncthreads();
    float c = (float)cnt4[l];
    float a = c * hpb[l * 128 + j];
    const float* wp = hpW + (size_t)l * 16384;
    for (int k = 0; k < 128; k++) a = fmaf(fs[k], wp[k * 128 + j], a);
    float cm = c < 1.0f ? 1.0f : c;
    float v = a / cm;
    lmean[l * 128 + j] = v;
    lml[j] = v;
    __syncthreads();
    float b = b1[j];
    for (int k = 0; k < 128; k++) b = fmaf(lml[k], W1b[k * 128 + j], b);
    lmw[l * 128 + j] = b;
}

// ---------------- TAIL-CD2 (level-bucketed) ----------------
__global__ __launch_bounds__(256) void k_tailCD2(const float* __restrict__ fused2,
                                                 const int* __restrict__ perm,
                                                 const int* __restrict__ cnt4,
                                                 const int* __restrict__ off4,
                                                 const int* __restrict__ boff5,
                                                 const unsigned short* __restrict__ QWhi,
                                                 const unsigned short* __restrict__ QWlo,
                                                 const float* __restrict__ qb,
                                                 const float* __restrict__ lmw,
                                                 const float* __restrict__ lmean,
                                                 const float* __restrict__ hW2,
                                                 const unsigned short* __restrict__ Ohi,
                                                 const unsigned short* __restrict__ Olo,
                                                 const float* __restrict__ hob,
                                                 const float* __restrict__ hlg,
                                                 const float* __restrict__ hlb,
                                                 float* __restrict__ out) {
    __shared__ __align__(16) float T[16][132];
    __shared__ __align__(16) float T2[16][132];
    __shared__ float lm[4][128];
    __shared__ float lmwS[4][128];
    __shared__ float w2S[128];
    __shared__ float scS[16][4];
    __shared__ float aw[16][4];
    __shared__ float mu16[16], rs16[16];
    __shared__ int idx16[16];
    int tid = threadIdx.x;
    int b = blockIdx.x;
    if (b >= boff5[4]) return;
    int l = (b >= boff5[3]) ? 3 : (b >= boff5[2]) ? 2 : (b >= boff5[1]) ? 1 : 0;
    int bi = b - boff5[l];
    int base = off4[l] + bi * 16;
    int last = off4[l] + cnt4[l] - 1;
    if (tid < 16) {
        int gp = base + tid;
        if (gp > last) gp = last;
        idx16[tid] = perm[gp];
    }
    for (int idx = tid; idx < 512; idx += 256) {
        lm[idx >> 7][idx & 127] = lmean[idx];
        lmwS[idx >> 7][idx & 127] = lmw[idx];
    }
    if (tid < 128) w2S[tid] = hW2[tid];
    __syncthreads();
#pragma unroll
    for (int i = 0; i < 8; i++) {
        int idx = tid + i * 256;
        int r = idx >> 7, c = idx & 127;
        T[r][c] = fused2[(size_t)idx16[r] * 128 + c];
    }
    __syncthreads();
    int w = tid >> 6, lane = tid & 63, lr = lane & 15, lg = lane >> 4;
    int col0 = w * 32 + lr, col1 = col0 + 16;
    int j = tid & 127, half = tid >> 7;
    {
        bf16x8 ahi[4], alo[4];
#pragma unroll
        for (int k = 0; k < 4; k++) mk_split(&T[lr][k * 32 + lg * 8], ahi[k], alo[k]);
        const unsigned short* wh0 = QWhi + (size_t)l * 16384 + (size_t)col0 * 128 + lg * 8;
        const unsigned short* wl0 = QWlo + (size_t)l * 16384 + (size_t)col0 * 128 + lg * 8;
        const unsigned short* wh1 = QWhi + (size_t)l * 16384 + (size_t)col1 * 128 + lg * 8;
        const unsigned short* wl1 = QWlo + (size_t)l * 16384 + (size_t)col1 * 128 + lg * 8;
        f32x4 a0 = {0.f, 0.f, 0.f, 0.f}, a1 = {0.f, 0.f, 0.f, 0.f};
#pragma unroll
        for (int k = 0; k < 4; k++) {
            bf16x8 bh = *(const bf16x8*)(wh0 + k * 32), bl = *(const bf16x8*)(wl0 + k * 32);
            a0 = MFMA(ahi[k], bh, a0, 0, 0, 0);
            a0 = MFMA(alo[k], bh, a0, 0, 0, 0);
            a0 = MFMA(ahi[k], bl, a0, 0, 0, 0);
            bh = *(const bf16x8*)(wh1 + k * 32); bl = *(const bf16x8*)(wl1 + k * 32);
            a1 = MFMA(ahi[k], bh, a1, 0, 0, 0);
            a1 = MFMA(alo[k], bh, a1, 0, 0, 0);
            a1 = MFMA(ahi[k], bl, a1, 0, 0, 0);
        }
#pragma unroll
        for (int i = 0; i < 4; i++) {
            int r = lg * 4 + i;
            T2[r][col0] = a0[i] + qb[l * 128 + col0];
            T2[r][col1] = a1[i] + qb[l * 128 + col1];
        }
    }
    __syncthreads();
    {
        int p = tid >> 2, sub = tid & 3;
        int pr = p & 15, pl = p >> 4;
        float s = 0.0f;
#pragma unroll
        for (int jj = 0; jj < 32; jj++) {
            int j2 = sub + 4 * jj;
            s += tanhf_fast(T2[pr][j2] + lmwS[pl][j2]) * w2S[j2];
        }
        s += __shfl_xor(s, 1);
        s += __shfl_xor(s, 2);
        if (sub == 0) scS[pr][pl] = s;
    }
    __syncthreads();
    if (tid < 16) {
        float sc[4];
        float mx = -1e30f;
#pragma unroll
        for (int ll = 0; ll < 4; ll++) {
            sc[ll] = scS[tid][ll];
            mx = fmaxf(mx, sc[ll]);
        }
        float s = 0.0f;
#pragma unroll
        for (int ll = 0; ll < 4; ll++) { sc[ll] = __expf(sc[ll] - mx); s += sc[ll]; }
        float inv = 1.0f / s;
#pragma unroll
        for (int ll = 0; ll < 4; ll++) aw[tid][ll] = sc[ll] * inv;
    }
    __syncthreads();
#pragma unroll
    for (int r = 0; r < 8; r++) {
        int rr = half * 8 + r;
        float e = 0.0f;
#pragma unroll
        for (int ll = 0; ll < 4; ll++) e = fmaf(aw[rr][ll], lm[ll][j], e);
        T[rr][j] = e;
    }
    __syncthreads();
    {
        bf16x8 ahi[4], alo[4];
#pragma unroll
        for (int k = 0; k < 4; k++) mk_split(&T[lr][k * 32 + lg * 8], ahi[k], alo[k]);
        const unsigned short* wh0 = Ohi + (size_t)col0 * 128 + lg * 8;
        const unsigned short* wl0 = Olo + (size_t)col0 * 128 + lg * 8;
        const unsigned short* wh1 = Ohi + (size_t)col1 * 128 + lg * 8;
        const unsigned short* wl1 = Olo + (size_t)col1 * 128 + lg * 8;
        f32x4 a0 = {0.f, 0.f, 0.f, 0.f}, a1 = {0.f, 0.f, 0.f, 0.f};
#pragma unroll
        for (int k = 0; k < 4; k++) {
            bf16x8 bh = *(const bf16x8*)(wh0 + k * 32), bl = *(const bf16x8*)(wl0 + k * 32);
            a0 = MFMA(ahi[k], bh, a0, 0, 0, 0);
            a0 = MFMA(alo[k], bh, a0, 0, 0, 0);
            a0 = MFMA(ahi[k], bl, a0, 0, 0, 0);
            bh = *(const bf16x8*)(wh1 + k * 32); bl = *(const bf16x8*)(wl1 + k * 32);
            a1 = MFMA(ahi[k], bh, a1, 0, 0, 0);
            a1 = MFMA(alo[k], bh, a1, 0, 0, 0);
            a1 = MFMA(ahi[k], bl, a1, 0, 0, 0);
        }
#pragma unroll
        for (int i = 0; i < 4; i++) {
            int r = lg * 4 + i;
            T2[r][col0] = a0[i] + hob[col0];
            T2[r][col1] = a1[i] + hob[col1];
        }
    }
    __syncthreads();
    {
        int gr = tid >> 4, l16 = tid & 15;
        float sm = 0.0f, sq = 0.0f;
#pragma unroll
        for (int i = 0; i < 8; i++) {
            float v = T2[gr][l16 + 16 * i];
            sm += v; sq += v * v;
        }
#pragma unroll
        for (int m = 1; m < 16; m <<= 1) { sm += __shfl_xor(sm, m); sq += __shfl_xor(sq, m); }
        if (l16 == 0) {
            float mean = sm * (1.0f / 128.0f);
            float var = sq * (1.0f / 128.0f) - mean * mean;
            mu16[gr] = mean;
            rs16[gr] = rsqrtf(var + 1e-5f);
        }
    }
    __syncthreads();
    {
        float gj = hlg[j], bb = hlb[j];
#pragma unroll
        for (int r = 0; r < 8; r++) {
            int rr = half * 8 + r;
            float v = (T2[rr][j] - mu16[rr]) * rs16[rr] * gj + bb;
            out[(size_t)idx16[rr] * 128 + j] = fmaxf(v, 0.0f);
        }
    }
}

extern "C" void kernel_launch(void* const* d_in, const int* in_sizes, int n_in,
                              void* d_out, int out_size, void* d_ws, size_t ws_size,
                              hipStream_t stream) {
    const float* nf  = (const float*)d_in[0];
    const float* ef  = (const float*)d_in[1];
    const int*   lev = (const int*)d_in[2];
    const int*   ei  = (const int*)d_in[3];
    const float* nlW = (const float*)d_in[4];
    const float* nlb = (const float*)d_in[5];
    const float* neW = (const float*)d_in[6];
    const float* neb = (const float*)d_in[7];
    const float* aW1 = (const float*)d_in[8];
    const float* ab1 = (const float*)d_in[9];
    const float* aW2 = (const float*)d_in[10];
    const float* ab2 = (const float*)d_in[11];
    const float* oW  = (const float*)d_in[12];
    const float* ob  = (const float*)d_in[13];
    const float* lng = (const float*)d_in[14];
    const float* lnb = (const float*)d_in[15];
    const float* eW1 = (const float*)d_in[16];
    const float* eb1 = (const float*)d_in[17];
    const float* eW2 = (const float*)d_in[18];
    const float* eb2 = (const float*)d_in[19];
    const float* eoW = (const float*)d_in[20];
    const float* eob = (const float*)d_in[21];
    const float* elg = (const float*)d_in[22];
    const float* elb = (const float*)d_in[23];
    const float* hpW = (const float*)d_in[24];
    const float* hpb = (const float*)d_in[25];
    const float* hW1 = (const float*)d_in[26];
    const float* hb1 = (const float*)d_in[27];
    const float* hW2 = (const float*)d_in[28];
    const float* hb2 = (const float*)d_in[29];
    const float* hoW = (const float*)d_in[30];
    const float* hob = (const float*)d_in[31];
    const float* hlg = (const float*)d_in[32];
    const float* hlb = (const float*)d_in[33];

    float* ws = (float*)d_ws;
    size_t NH = (size_t)NN * 128;
    float* fused2 = ws;                       // NH
    float* emb0   = fused2 + NH;              // NH
    float* emb1   = emb0 + NH;                // NH
    float* ebuf2  = emb1 + NH;                // 2*EE (CSR order)
    float* scores = ebuf2 + 2 * (size_t)EE;   // 2*NN
    float* beff2  = scores + (size_t)2 * NN;  // 256
    float* fsum   = beff2 + 256;              // 512
    float* lmean  = fsum + 512;               // 512
    float* lmw    = lmean + 512;              // 512
    float* qb     = lmw + 512;                // 512
    unsigned short* U2    = (unsigned short*)(qb + 512);  // 2*NH
    unsigned short* V2    = U2 + 2 * NH;                  // 2*NH
    unsigned short* hbf2  = V2 + 2 * NH;                  // 2*NH
    unsigned short* WhT2  = hbf2 + 2 * NH;                // 2*16384
    unsigned short* WUT2  = WhT2 + 2 * 16384;
    unsigned short* WVT2  = WUT2 + 2 * 16384;
    unsigned short* WET2  = WVT2 + 2 * 16384;             // 2*8192
    unsigned short* twhi  = WET2 + 2 * 8192;              // 6*16384
    unsigned short* twlo  = twhi + 6 * 16384;             // 6*16384
    unsigned short* QWhi  = twlo + 6 * 16384;             // 4*16384
    unsigned short* QWlo  = QWhi + 4 * 16384;             // 4*16384
    int* perm    = (int*)(QWlo + 4 * 16384);              // NN
    int* cnt4    = perm + NN;
    int* off4    = cnt4 + 4;
    int* boff5   = off4 + 4;
    int* cursorL = boff5 + 5;
    int* deg2    = cursorL + 4;          // 2*NN
    int* rowptr2 = deg2 + 2 * NN;        // 2*NN+1
    int* cursor2 = rowptr2 + 2 * NN + 1; // 2*NN
    int* stmp    = cursor2 + 2 * NN;     // 2*NN
    int* sbsum   = stmp + 2 * NN;        // 512
    int* sboff   = sbsum + 512;          // 512
    int* ceid2   = sboff + 512;          // 2*EE
    int* cs2     = ceid2 + 2 * EE;       // 2*EE
    int* cdst2   = cs2 + 2 * EE;         // 2*EE
    float* out = (float*)d_out;

    WSrc ps;
    ps.s[0] = oW;
    ps.s[1] = oW + 16384;
    ps.s[2] = eW1;
    ps.s[3] = eW1 + 16384;
    ps.s[4] = eoW;
    ps.s[5] = hoW;

    const int NB_N = NN / 16;             // 6250
    const int SCB = (2 * NN + 511) / 512; // 391

    // level bucketing
    k_zeroi<<<1, 4, 0, stream>>>(cnt4, 4);
    k_count<<<128, 256, 0, stream>>>(lev, cnt4);
    k_scan<<<1, 1, 0, stream>>>(cnt4, off4, boff5, cursorL);
    k_scatter<<<125, 256, 0, stream>>>(lev, cursorL, perm);

    // weight prep
    k_prep_tail<<<6 * 64, 256, 0, stream>>>(ps, twhi, twlo);
    k_prep_q<<<258, 256, 0, stream>>>(hpW, hpb, hW1, QWhi, QWlo, qb);
    k_zero<<<1, 512, 0, stream>>>(fsum, (size_t)512);

    // CSR build (both relations at once)
    k_zeroi<<<(2 * NN + 255) / 256, 256, 0, stream>>>(deg2, 2 * NN);
    k_hist2<<<(2 * EE + 255) / 256, 256, 0, stream>>>(ei, deg2);
    k_scan1<<<SCB, 512, 0, stream>>>(deg2, stmp, sbsum);
    k_scan2<<<1, 512, 0, stream>>>(sbsum, sboff, SCB);
    k_scan3<<<SCB, 512, 0, stream>>>(deg2, stmp, sboff, rowptr2, cursor2);
    k_csr_scatter3<<<(2 * EE + 255) / 256, 256, 0, stream>>>(ei, cursor2, ceid2, cs2, cdst2);

    // head (both t, one nf pass)
    k_prep_head2<<<256, 128, 0, stream>>>(nlW, nlb, aW1, ab1, neW, neb,
                                          WhT2, WUT2, WVT2, WET2, beff2);
    k_head2<<<NB_N, 256, 0, stream>>>(nf, WhT2, WUT2, WVT2, nlb, hbf2, U2, V2);

    // edge scores (CSR order, both t)
    k_edge5<<<2 * EE / EBLK, 256, 0, stream>>>(ef, ceid2, cs2, cdst2, WET2, U2, V2,
                                               beff2, aW2, ab2, ebuf2);
    // aggregation + relation tail (both t)
    k_tailA2b<<<2 * NB_N, 256, 0, stream>>>(rowptr2, cdst2, ebuf2, hbf2, twhi, twlo,
                                            ob, lng, lnb, eb1, eW2, eb2,
                                            emb0, emb1, scores, NB_N);

    k_tailB1<<<NB_N, 256, 0, stream>>>(emb0, emb1, scores,
                                       twhi + (size_t)4 * 16384, twlo + (size_t)4 * 16384,
                                       eob, elg, elb, fused2);
    k_fsum<<<256, 256, 0, stream>>>(fused2, lev, fsum);
    k_fin2<<<4, 128, 0, stream>>>(fsum, cnt4, hpW, hpb, hW1 + 16384, hb1, lmean, lmw);
    k_tailCD2<<<NB_N + 4, 256, 0, stream>>>(fused2, perm, cnt4, off4, boff5,
                                            QWhi, QWlo, qb, lmw, lmean, hW2,
                                            twhi + (size_t)5 * 16384, twlo + (size_t)5 * 16384,
                                            hob, hlg, hlb, out);
}